// Round 1
// baseline (1254.674 us; speedup 1.0000x reference)
//
#include <hip/hip_runtime.h>

#define NPTS 60000
#define NXG 256
#define NCELL 65536
#define MAXP 12000
#define MAXPP 32
#define NROWS (MAXP*MAXPP)

// ---------------- mask dtype probe ----------------
// misc[0]: 0 = int32, 1 = uint8, 2 = float32
__global__ void probe_mask(const unsigned* __restrict__ m, int* __restrict__ misc){
  __shared__ int cf32, cbig;
  if (threadIdx.x==0){ cf32=0; cbig=0; }
  __syncthreads();
  int lf=0, lb=0;
  for (int k=0;k<4;k++){
    unsigned x = m[threadIdx.x*4+k];
    if (x==0x3f800000u) lf++;
    else if (x>1u) lb++;
  }
  atomicAdd(&cf32, lf); atomicAdd(&cbig, lb);
  __syncthreads();
  if (threadIdx.x==0){
    int mode=0;
    if (cf32>64) mode=2; else if (cbig>0) mode=1;
    misc[0]=mode;
  }
}

// ---------------- pillarize ----------------
__global__ void compute_pid(const float* __restrict__ pts, const void* __restrict__ maskp,
                            const int* __restrict__ misc, int* __restrict__ pid,
                            int* __restrict__ ccnt){
  int i = blockIdx.x*blockDim.x + threadIdx.x;
  if (i>=NPTS) return;
  int b = blockIdx.y;
  int gi = b*NPTS+i;
  int mode = misc[0];
  bool m;
  if (mode==0)      m = ((const int*)maskp)[gi]!=0;
  else if (mode==1) m = ((const unsigned char*)maskp)[gi]!=0;
  else              m = ((const float*)maskp)[gi]!=0.f;
  int cell = -1;
  if (m){
    float x = pts[(size_t)gi*5+0], y = pts[(size_t)gi*5+1];
    int ix = (int)((x - (-32.0f)) / 0.25f);
    ix = ix<0?0:(ix>255?255:ix);
    int iy = (int)((y - (-32.0f)) / 0.25f);
    iy = iy<0?0:(iy>255?255:iy);
    cell = iy*NXG + ix;
    atomicAdd(&ccnt[b*NCELL+cell], 1);
  }
  pid[gi] = cell;
}

// one block per batch, 1024 threads, 64 cells/thread
__global__ __launch_bounds__(1024) void scan_cells(const int* __restrict__ ccnt,
    int* __restrict__ crank, int* __restrict__ cstart, int* __restrict__ pcell,
    int* __restrict__ misc, int* __restrict__ heavy){
  __shared__ int so_[1024], sc_[1024];
  int b = blockIdx.x, t = threadIdx.x;
  const int base = b*NCELL;
  const int cbeg = t*64;
  int occ=0, cnt=0;
  for (int j=0;j<64;j++){ int v=ccnt[base+cbeg+j]; occ += (v>0); cnt += v; }
  so_[t]=occ; sc_[t]=cnt; __syncthreads();
  for (int off=1; off<1024; off<<=1){
    int vo=0, vc=0;
    if (t>=off){ vo=so_[t-off]; vc=sc_[t-off]; }
    __syncthreads();
    if (t>=off){ so_[t]+=vo; sc_[t]+=vc; }
    __syncthreads();
  }
  int eo = so_[t]-occ, ec = sc_[t]-cnt;
  if (t==1023) misc[1+b] = (so_[1023] < MAXP) ? so_[1023] : MAXP; // npil
  int kept=0;
  for (int j=0;j<64;j++){
    int c = cbeg+j; int v = ccnt[base+c];
    if (v>0){
      crank[base+c]=eo; cstart[base+c]=ec;
      if (eo<MAXP){
        pcell[b*MAXP+eo]=c;
        kept += (v<MAXPP)? v : MAXPP;
        if (v>MAXPP){
          int hi = atomicAdd(&heavy[b],1);
          if (hi<64) heavy[2 + b*64 + hi] = c;
        }
      }
      eo++; ec+=v;
    } else {
      crank[base+c]=-1;
    }
  }
  atomicAdd(&misc[3+b], kept); // nk
}

__global__ void scatter_points(const int* __restrict__ pid, const int* __restrict__ ccnt,
    const int* __restrict__ crank, const int* __restrict__ cstart,
    int* __restrict__ ctmp, int* __restrict__ plist, int* __restrict__ pptr){
  int i = blockIdx.x*blockDim.x + threadIdx.x;
  if (i>=NPTS) return;
  int b = blockIdx.y;
  int gi = b*NPTS+i;
  int cell = pid[gi];
  if (cell<0) return;
  int bc = b*NCELL+cell;
  int pos = cstart[bc] + atomicAdd(&ctmp[bc],1);
  plist[b*NPTS+pos] = i;
  int r = crank[bc];
  if (r>=0 && r<MAXP && ccnt[bc]<=MAXPP) pptr[gi] = r;
}

__global__ void heavy_select(const int* __restrict__ ccnt, const int* __restrict__ crank,
    const int* __restrict__ cstart, const int* __restrict__ plist,
    const int* __restrict__ heavy, int* __restrict__ pptr){
  int b = blockIdx.y;
  int hn = heavy[b]; if (hn>64) hn=64;
  if ((int)blockIdx.x >= hn) return;
  int cell = heavy[2 + b*64 + blockIdx.x];
  int bc = b*NCELL+cell;
  int cnt = ccnt[bc], start = cstart[bc], pr = crank[bc];
  for (int e=threadIdx.x; e<cnt; e+=blockDim.x){
    int pe = plist[b*NPTS+start+e];
    int rank=0;
    for (int k=0;k<cnt;k++) rank += (plist[b*NPTS+start+k] < pe);
    if (rank<MAXPP) pptr[b*NPTS+pe] = pr;
  }
}

__global__ void centroid_acc(const float* __restrict__ pts, const int* __restrict__ pptr,
                             float* __restrict__ psum){
  int i = blockIdx.x*blockDim.x + threadIdx.x;
  if (i>=NPTS) return;
  int b = blockIdx.y;
  int gi = b*NPTS+i;
  int p = pptr[gi];
  if (p<0) return;
  const float* q = &pts[(size_t)gi*5];
  float* s = &psum[(size_t)(b*MAXP+p)*4];
  atomicAdd(s+0,q[0]); atomicAdd(s+1,q[1]); atomicAdd(s+2,q[2]); atomicAdd(s+3,1.0f);
}

__global__ void centroid_fin(float* __restrict__ psum){
  int i = blockIdx.x*blockDim.x + threadIdx.x;
  if (i>=2*MAXP) return;
  float* s = &psum[(size_t)i*4];
  float inv = 1.0f / fmaxf(s[3],1.0f);
  s[0]*=inv; s[1]*=inv; s[2]*=inv;
}

// pass1: build compact aug list + layer1 stats
__global__ __launch_bounds__(256) void mlp_pass1(const float* __restrict__ pts,
    const int* __restrict__ pid, const int* __restrict__ pptr, const float* __restrict__ psum,
    const float* __restrict__ w1, const float* __restrict__ b1,
    float* __restrict__ stats, int* __restrict__ misc, int* __restrict__ klist,
    float* __restrict__ augc){
  __shared__ float sw1[640], sb1v[64], ss[64], sq[64];
  int b = blockIdx.y, t = threadIdx.x;
  for (int e=t;e<640;e+=256) sw1[e]=w1[e];
  if (t<64){ sb1v[t]=b1[t]; ss[t]=0.f; sq[t]=0.f; }
  __syncthreads();
  int i = blockIdx.x*256+t;
  if (i<NPTS){
    int gi = b*NPTS+i;
    int p = pptr[gi];
    if (p>=0){
      const float* q = &pts[(size_t)gi*5];
      const float* mc = &psum[(size_t)(b*MAXP+p)*4];
      int cell = pid[gi];
      float aug[10];
      aug[0]=q[0];aug[1]=q[1];aug[2]=q[2];aug[3]=q[3];aug[4]=q[4];
      aug[5]=q[0]-mc[0]; aug[6]=q[1]-mc[1]; aug[7]=q[2]-mc[2];
      aug[8]=-32.0f+((float)(cell&255)+0.5f)*0.25f;
      aug[9]=-32.0f+((float)(cell>>8)+0.5f)*0.25f;
      int e2 = atomicAdd(&misc[5+b],1);
      klist[b*NPTS+e2]=i;
      float* A=&augc[(size_t)(b*NPTS+e2)*10];
      #pragma unroll
      for (int d=0;d<10;d++) A[d]=aug[d];
      for (int c=0;c<64;c++){
        float y=sb1v[c];
        #pragma unroll
        for (int d=0;d<10;d++) y += aug[d]*sw1[d*64+c];
        atomicAdd(&ss[c],y); atomicAdd(&sq[c],y*y);
      }
    }
  }
  __syncthreads();
  if (t<64){
    atomicAdd(&stats[(size_t)b*512+t],    ss[t]);
    atomicAdd(&stats[(size_t)b*512+64+t], sq[t]);
  }
}

__global__ void stats_fin1(const float* __restrict__ b1,const float* __restrict__ g1,
    const float* __restrict__ be1,const float* __restrict__ w2,const float* __restrict__ b2,
    float* __restrict__ stats, const int* __restrict__ misc){
  __shared__ float z0s[64];
  int b = blockIdx.x, c = threadIdx.x;
  float* S = &stats[(size_t)b*512];
  const float N = (float)NROWS;
  float pad = N - (float)misc[3+b];
  float s = S[c]    + pad*b1[c];
  float q = S[64+c] + pad*b1[c]*b1[c];
  float m = s/N;
  float v = fmaxf(q/N - m*m, 0.f);
  float sc = g1[c]*rsqrtf(v+1e-5f);
  float sh = be1[c]-m*sc;
  S[256+c]=sc; S[320+c]=sh;
  float z0 = fmaxf(b1[c]*sc+sh, 0.f);
  z0s[c]=z0;
  __syncthreads();
  float t0 = b2[c];
  for (int i2=0;i2<64;i2++) t0 += z0s[i2]*w2[(size_t)i2*64+c];
  S[128+c]=pad*t0; S[192+c]=pad*t0*t0;
}

// pass2: layer2 stats
__global__ __launch_bounds__(256) void mlp_pass2(const float* __restrict__ augc,
    const float* __restrict__ w1,const float* __restrict__ b1,
    const float* __restrict__ w2,const float* __restrict__ b2,
    float* __restrict__ stats, const int* __restrict__ misc){
  __shared__ __align__(16) float sw2[4096];
  __shared__ float sw1[640], sb1v[64], sb2v[64], sc1[64], sh1[64], ss[64], sq[64];
  int b = blockIdx.y, t = threadIdx.x;
  float* S = &stats[(size_t)b*512];
  for (int e=t;e<4096;e+=256) sw2[e]=w2[e];
  for (int e=t;e<640;e+=256) sw1[e]=w1[e];
  if (t<64){ sb1v[t]=b1[t]; sb2v[t]=b2[t]; sc1[t]=S[256+t]; sh1[t]=S[320+t]; ss[t]=0.f; sq[t]=0.f; }
  __syncthreads();
  int nk = misc[5+b];
  int e = blockIdx.x*256+t;
  if (e<nk){
    float aug[10];
    const float* A=&augc[(size_t)(b*NPTS+e)*10];
    #pragma unroll
    for (int d=0;d<10;d++) aug[d]=A[d];
    float tacc[64];
    #pragma unroll
    for (int o=0;o<64;o++) tacc[o]=sb2v[o];
    for (int c=0;c<64;c++){
      float y=sb1v[c];
      #pragma unroll
      for (int d=0;d<10;d++) y += aug[d]*sw1[d*64+c];
      float z = fmaxf(y*sc1[c]+sh1[c], 0.f);
      const float4* wr = (const float4*)&sw2[c*64];
      #pragma unroll
      for (int o4=0;o4<16;o4++){
        float4 wv = wr[o4];
        tacc[4*o4+0]+=z*wv.x; tacc[4*o4+1]+=z*wv.y;
        tacc[4*o4+2]+=z*wv.z; tacc[4*o4+3]+=z*wv.w;
      }
    }
    #pragma unroll
    for (int o=0;o<64;o++){ atomicAdd(&ss[o],tacc[o]); atomicAdd(&sq[o],tacc[o]*tacc[o]); }
  }
  __syncthreads();
  if (t<64){ atomicAdd(&S[128+t], ss[t]); atomicAdd(&S[192+t], sq[t]); }
}

__global__ void stats_fin2(const float* __restrict__ g2,const float* __restrict__ be2,
                           float* __restrict__ stats){
  int b = blockIdx.x, c = threadIdx.x;
  float* S = &stats[(size_t)b*512];
  const float N = (float)NROWS;
  float m = S[128+c]/N;
  float v = fmaxf(S[192+c]/N - m*m, 0.f);
  float sc = g2[c]*rsqrtf(v+1e-5f);
  S[384+c]=sc; S[448+c]=be2[c]-m*sc;
}

// pass3: per-pillar max via uint atomicMax (values are >= 0 post-relu)
__global__ __launch_bounds__(256) void mlp_pass3(const float* __restrict__ augc,
    const int* __restrict__ klist, const int* __restrict__ pptr,
    const float* __restrict__ w1,const float* __restrict__ b1,
    const float* __restrict__ w2,const float* __restrict__ b2,
    const float* __restrict__ stats, const int* __restrict__ misc,
    unsigned* __restrict__ feat){
  __shared__ __align__(16) float sw2[4096];
  __shared__ float sw1[640], sb1v[64], sb2v[64], sc1[64], sh1[64], sc2[64], sh2[64];
  int b = blockIdx.y, t = threadIdx.x;
  const float* S = &stats[(size_t)b*512];
  for (int e=t;e<4096;e+=256) sw2[e]=w2[e];
  for (int e=t;e<640;e+=256) sw1[e]=w1[e];
  if (t<64){ sb1v[t]=b1[t]; sb2v[t]=b2[t]; sc1[t]=S[256+t]; sh1[t]=S[320+t]; sc2[t]=S[384+t]; sh2[t]=S[448+t]; }
  __syncthreads();
  int nk = misc[5+b];
  int e = blockIdx.x*256+t;
  if (e>=nk) return;
  float aug[10];
  const float* A=&augc[(size_t)(b*NPTS+e)*10];
  #pragma unroll
  for (int d=0;d<10;d++) aug[d]=A[d];
  float tacc[64];
  #pragma unroll
  for (int o=0;o<64;o++) tacc[o]=sb2v[o];
  for (int c=0;c<64;c++){
    float y=sb1v[c];
    #pragma unroll
    for (int d=0;d<10;d++) y += aug[d]*sw1[d*64+c];
    float z = fmaxf(y*sc1[c]+sh1[c], 0.f);
    const float4* wr = (const float4*)&sw2[c*64];
    #pragma unroll
    for (int o4=0;o4<16;o4++){
      float4 wv = wr[o4];
      tacc[4*o4+0]+=z*wv.x; tacc[4*o4+1]+=z*wv.y;
      tacc[4*o4+2]+=z*wv.z; tacc[4*o4+3]+=z*wv.w;
    }
  }
  int li = klist[b*NPTS+e];
  int p = pptr[b*NPTS+li];
  unsigned* F = &feat[(size_t)(b*MAXP+p)*64];
  #pragma unroll
  for (int o=0;o<64;o++){
    float v = fmaxf(tacc[o]*sc2[o]+sh2[o], 0.f);
    atomicMax(&F[o], __float_as_uint(v));
  }
}

__global__ void scatter_bev(const unsigned* __restrict__ feat, const int* __restrict__ pcell,
                            const int* __restrict__ misc, float* __restrict__ bev){
  int tid = blockIdx.x*256+threadIdx.x;
  if (tid >= 2*64*MAXP) return;
  int b = tid/(64*MAXP); int r = tid - b*64*MAXP;
  int c = r/MAXP; int p = r - c*MAXP;
  if (p >= misc[1+b]) return;
  int cell = pcell[b*MAXP+p];
  bev[(((size_t)(b*64+c))<<16) + cell] = __uint_as_float(feat[(size_t)(b*MAXP+p)*64 + c]);
}

// ---------------- conv stack ----------------
// 16x16 pixel tile, all 64 oc; 256 thr; each thread: 8px(x) x 8oc register tile.
// Optional input transform (BN scale/shift + relu) applied while staging.
__global__ __launch_bounds__(256,2) void conv3x3(const float* __restrict__ in, float* __restrict__ out,
    const float* __restrict__ w, const float* __restrict__ bias,
    const float* __restrict__ bnsc, const float* __restrict__ bnsh){
  __shared__ __align__(16) float sIn[16][18][20];
  __shared__ __align__(16) float sW[16][9][64];
  const int tX = blockIdx.x*16, tY = blockIdx.y*16, b = blockIdx.z;
  const int t = threadIdx.x;
  const int ocg = t&7, pg = t>>3;
  const int py = pg>>1, x0 = (pg&1)*8, oc0 = ocg*8;
  float acc[8][8];
  #pragma unroll
  for (int k=0;k<8;k++)
    #pragma unroll
    for (int j=0;j<8;j++) acc[k][j]=0.f;

  for (int cc=0;cc<4;cc++){
    const int ic0 = cc*16;
    __syncthreads();
    for (int e=t;e<16*18*18;e+=256){
      int ic = e/324; int r = e-ic*324; int yy=r/18, xx=r-yy*18;
      int gy = tY+yy-1, gx = tX+xx-1;
      float v = 0.f;
      if ((unsigned)gy<256u && (unsigned)gx<256u){
        v = in[(((size_t)(b*64+ic0+ic))<<16) + (gy<<8) + gx];
        if (bnsc){ v = fmaxf(v*bnsc[ic0+ic]+bnsh[ic0+ic], 0.f); }
      }
      sIn[ic][yy][xx]=v;
    }
    for (int e=t;e<16*9*64;e+=256){
      int ic = e/576; int r = e-ic*576; int tap = r>>6; int oc = r&63;
      sW[ic][tap][oc] = w[((size_t)oc*64+(ic0+ic))*9 + tap];
    }
    __syncthreads();
    for (int ic=0;ic<16;ic++){
      #pragma unroll
      for (int dy=0;dy<3;dy++){
        const float* ip = &sIn[ic][py+dy][x0];
        float4 A0 = *(const float4*)ip;
        float4 A1 = *(const float4*)(ip+4);
        float4 A2 = *(const float4*)(ip+8);
        float v[12] = {A0.x,A0.y,A0.z,A0.w,A1.x,A1.y,A1.z,A1.w,A2.x,A2.y,A2.z,A2.w};
        #pragma unroll
        for (int dx=0;dx<3;dx++){
          const float4* wp = (const float4*)&sW[ic][dy*3+dx][oc0];
          float4 W0 = wp[0], W1 = wp[1];
          float wv[8] = {W0.x,W0.y,W0.z,W0.w,W1.x,W1.y,W1.z,W1.w};
          #pragma unroll
          for (int k=0;k<8;k++)
            #pragma unroll
            for (int j=0;j<8;j++) acc[k][j] += v[dx+k]*wv[j];
        }
      }
    }
  }
  #pragma unroll
  for (int j=0;j<8;j++){
    float bj = bias[oc0+j];
    float* dst = &out[(((size_t)(b*64+oc0+j))<<16) + ((tY+py)<<8) + tX + x0];
    float4 o0 = make_float4(acc[0][j]+bj, acc[1][j]+bj, acc[2][j]+bj, acc[3][j]+bj);
    float4 o1 = make_float4(acc[4][j]+bj, acc[5][j]+bj, acc[6][j]+bj, acc[7][j]+bj);
    *(float4*)dst = o0; *(float4*)(dst+4) = o1;
  }
}

__global__ __launch_bounds__(256) void bn_stats(const float* __restrict__ x, float* __restrict__ bnst){
  int c = blockIdx.x, part = blockIdx.y;
  float s=0.f, q=0.f;
  for (int b=0;b<2;b++){
    const float4* p = (const float4*)&x[(((size_t)(b*64+c))<<16) + (size_t)part*8192];
    for (int k=threadIdx.x;k<2048;k+=256){
      float4 v = p[k];
      s += v.x+v.y+v.z+v.w;
      q += v.x*v.x+v.y*v.y+v.z*v.z+v.w*v.w;
    }
  }
  __shared__ float rs[256], rq[256];
  rs[threadIdx.x]=s; rq[threadIdx.x]=q; __syncthreads();
  for (int o=128;o>0;o>>=1){
    if (threadIdx.x<o){ rs[threadIdx.x]+=rs[threadIdx.x+o]; rq[threadIdx.x]+=rq[threadIdx.x+o]; }
    __syncthreads();
  }
  if (threadIdx.x==0){ atomicAdd(&bnst[c], rs[0]); atomicAdd(&bnst[64+c], rq[0]); }
}

__global__ void bn_fin(float* __restrict__ bnst, const float* __restrict__ g, const float* __restrict__ be){
  int c = threadIdx.x;
  const float n = 131072.f;
  float m = bnst[c]/n;
  float v = fmaxf(bnst[64+c]/n - m*m, 0.f);
  float sc = g[c]*rsqrtf(v+1e-5f);
  bnst[128+c]=sc; bnst[192+c]=be[c]-m*sc;
}

__global__ __launch_bounds__(256) void bn_apply(float* __restrict__ x, const float* __restrict__ bnst){
  size_t idx = (size_t)blockIdx.x*256 + threadIdx.x;
  size_t stride = (size_t)gridDim.x*256;
  float4* p = (float4*)x;
  for (size_t k=idx; k<2097152ULL; k+=stride){
    int c = (int)((k>>14)&63);
    float sc = bnst[128+c], sh = bnst[192+c];
    float4 v = p[k];
    v.x=fmaxf(v.x*sc+sh,0.f); v.y=fmaxf(v.y*sc+sh,0.f);
    v.z=fmaxf(v.z*sc+sh,0.f); v.w=fmaxf(v.w*sc+sh,0.f);
    p[k]=v;
  }
}

// ---------------- launch ----------------
extern "C" void kernel_launch(void* const* d_in, const int* in_sizes, int n_in,
                              void* d_out, int out_size, void* d_ws, size_t ws_size,
                              hipStream_t stream){
  const float* pts  = (const float*)d_in[0];
  const void*  mask = d_in[1];
  const float* w1 = (const float*)d_in[2];
  const float* b1 = (const float*)d_in[3];
  const float* g1 = (const float*)d_in[4];
  const float* be1= (const float*)d_in[5];
  const float* w2 = (const float*)d_in[6];
  const float* b2 = (const float*)d_in[7];
  const float* g2 = (const float*)d_in[8];
  const float* be2= (const float*)d_in[9];
  const float* cw[3]  = {(const float*)d_in[10],(const float*)d_in[14],(const float*)d_in[18]};
  const float* cb[3]  = {(const float*)d_in[11],(const float*)d_in[15],(const float*)d_in[19]};
  const float* cg[3]  = {(const float*)d_in[12],(const float*)d_in[16],(const float*)d_in[20]};
  const float* cbe[3] = {(const float*)d_in[13],(const float*)d_in[17],(const float*)d_in[21]};
  float* out = (float*)d_out;

  char* W = (char*)d_ws;
  size_t off = 0;
  auto A = [&](size_t n){ size_t r = off; off = (off + n + 255) & ~(size_t)255; return r; };
  float*    BIG   = (float*)   (W + A(33554432));
  int*      PID   = (int*)     (W + A((size_t)2*NPTS*4));
  int*      CCNT  = (int*)     (W + A((size_t)2*NCELL*4));
  int*      CRANK = (int*)     (W + A((size_t)2*NCELL*4));
  int*      CSTART= (int*)     (W + A((size_t)2*NCELL*4));
  int*      CTMP  = (int*)     (W + A((size_t)2*NCELL*4));
  int*      PLIST = (int*)     (W + A((size_t)2*NPTS*4));
  int*      PPTR  = (int*)     (W + A((size_t)2*NPTS*4));
  int*      PCELL = (int*)     (W + A((size_t)2*MAXP*4));
  float*    PSUM  = (float*)   (W + A((size_t)2*MAXP*16));
  unsigned* FEAT  = (unsigned*)(W + A((size_t)2*MAXP*64*4));
  int*      KLIST = (int*)     (W + A((size_t)2*NPTS*4));
  float*    AUGC  = (float*)   (W + A((size_t)2*NPTS*10*4));
  float*    STATS = (float*)   (W + A((size_t)2*512*4));
  float*    BNST  = (float*)   (W + A((size_t)256*4));
  int*      HEAVY = (int*)     (W + A((size_t)(2+2*64)*4));
  int*      MISC  = (int*)     (W + A(256));

  hipMemsetAsync(BIG,  0, 33554432, stream);
  hipMemsetAsync(CCNT, 0, (size_t)2*NCELL*4, stream);
  hipMemsetAsync(CTMP, 0, (size_t)2*NCELL*4, stream);
  hipMemsetAsync(PPTR, 0xFF, (size_t)2*NPTS*4, stream);
  hipMemsetAsync(PSUM, 0, (size_t)2*MAXP*16, stream);
  hipMemsetAsync(FEAT, 0, (size_t)2*MAXP*64*4, stream);
  hipMemsetAsync(STATS,0, (size_t)2*512*4, stream);
  hipMemsetAsync(BNST, 0, (size_t)256*4, stream);
  hipMemsetAsync(HEAVY,0, (size_t)(2+2*64)*4, stream);
  hipMemsetAsync(MISC, 0, 256, stream);

  dim3 perPt((NPTS+255)/256, 2);

  probe_mask<<<1,256,0,stream>>>((const unsigned*)mask, MISC);
  compute_pid<<<perPt,256,0,stream>>>(pts, mask, MISC, PID, CCNT);
  scan_cells<<<2,1024,0,stream>>>(CCNT, CRANK, CSTART, PCELL, MISC, HEAVY);
  scatter_points<<<perPt,256,0,stream>>>(PID, CCNT, CRANK, CSTART, CTMP, PLIST, PPTR);
  heavy_select<<<dim3(64,2),64,0,stream>>>(CCNT, CRANK, CSTART, PLIST, HEAVY, PPTR);
  centroid_acc<<<perPt,256,0,stream>>>(pts, PPTR, PSUM);
  centroid_fin<<<(2*MAXP+255)/256,256,0,stream>>>(PSUM);
  mlp_pass1<<<perPt,256,0,stream>>>(pts, PID, PPTR, PSUM, w1, b1, STATS, MISC, KLIST, AUGC);
  stats_fin1<<<2,64,0,stream>>>(b1, g1, be1, w2, b2, STATS, MISC);
  mlp_pass2<<<perPt,256,0,stream>>>(AUGC, w1, b1, w2, b2, STATS, MISC);
  stats_fin2<<<2,64,0,stream>>>(g2, be2, STATS);
  mlp_pass3<<<perPt,256,0,stream>>>(AUGC, KLIST, PPTR, w1, b1, w2, b2, STATS, MISC, FEAT);
  scatter_bev<<<(2*64*MAXP+255)/256,256,0,stream>>>(FEAT, PCELL, MISC, BIG);

  // conv1: BIG(bev) -> d_out (raw + bias)
  conv3x3<<<dim3(16,16,2),256,0,stream>>>(BIG, out, cw[0], cb[0], nullptr, nullptr);
  bn_stats<<<dim3(64,8),256,0,stream>>>(out, BNST);
  bn_fin<<<1,64,0,stream>>>(BNST, cg[0], cbe[0]);
  // conv2: d_out (bn1+relu on stage) -> BIG
  conv3x3<<<dim3(16,16,2),256,0,stream>>>(out, BIG, cw[1], cb[1], BNST+128, BNST+192);
  hipMemsetAsync(BNST, 0, 512, stream);
  bn_stats<<<dim3(64,8),256,0,stream>>>(BIG, BNST);
  bn_fin<<<1,64,0,stream>>>(BNST, cg[1], cbe[1]);
  // conv3: BIG (bn2+relu on stage) -> d_out
  conv3x3<<<dim3(16,16,2),256,0,stream>>>(BIG, out, cw[2], cb[2], BNST+128, BNST+192);
  hipMemsetAsync(BNST, 0, 512, stream);
  bn_stats<<<dim3(64,8),256,0,stream>>>(out, BNST);
  bn_fin<<<1,64,0,stream>>>(BNST, cg[2], cbe[2]);
  bn_apply<<<2048,256,0,stream>>>(out, BNST);
}

// Round 2
// 1017.928 us; speedup vs baseline: 1.2326x; 1.2326x over previous
//
#include <hip/hip_runtime.h>

#define NPTS 60000
#define NXG 256
#define NCELL 65536
#define MAXP 12000
#define MAXPP 32
#define NROWS (MAXP*MAXPP)

// ---------------- mask dtype probe ----------------
// misc[0]: 0 = int32, 1 = uint8, 2 = float32
__global__ void probe_mask(const unsigned* __restrict__ m, int* __restrict__ misc){
  __shared__ int cf32, cbig;
  if (threadIdx.x==0){ cf32=0; cbig=0; }
  __syncthreads();
  int lf=0, lb=0;
  for (int k=0;k<4;k++){
    unsigned x = m[threadIdx.x*4+k];
    if (x==0x3f800000u) lf++;
    else if (x>1u) lb++;
  }
  atomicAdd(&cf32, lf); atomicAdd(&cbig, lb);
  __syncthreads();
  if (threadIdx.x==0){
    int mode=0;
    if (cf32>64) mode=2; else if (cbig>0) mode=1;
    misc[0]=mode;
  }
}

// ---------------- pillarize ----------------
__global__ void compute_pid(const float* __restrict__ pts, const void* __restrict__ maskp,
                            const int* __restrict__ misc, int* __restrict__ pid,
                            int* __restrict__ ccnt){
  int i = blockIdx.x*blockDim.x + threadIdx.x;
  if (i>=NPTS) return;
  int b = blockIdx.y;
  int gi = b*NPTS+i;
  int mode = misc[0];
  bool m;
  if (mode==0)      m = ((const int*)maskp)[gi]!=0;
  else if (mode==1) m = ((const unsigned char*)maskp)[gi]!=0;
  else              m = ((const float*)maskp)[gi]!=0.f;
  int cell = -1;
  if (m){
    float x = pts[(size_t)gi*5+0], y = pts[(size_t)gi*5+1];
    int ix = (int)((x - (-32.0f)) / 0.25f);
    ix = ix<0?0:(ix>255?255:ix);
    int iy = (int)((y - (-32.0f)) / 0.25f);
    iy = iy<0?0:(iy>255?255:iy);
    cell = iy*NXG + ix;
    atomicAdd(&ccnt[b*NCELL+cell], 1);
  }
  pid[gi] = cell;
}

// one block per batch, 1024 threads, 64 cells/thread
__global__ __launch_bounds__(1024) void scan_cells(const int* __restrict__ ccnt,
    int* __restrict__ crank, int* __restrict__ cstart, int* __restrict__ pcell,
    int* __restrict__ misc, int* __restrict__ heavy){
  __shared__ int so_[1024], sc_[1024];
  int b = blockIdx.x, t = threadIdx.x;
  const int base = b*NCELL;
  const int cbeg = t*64;
  int occ=0, cnt=0;
  for (int j=0;j<64;j++){ int v=ccnt[base+cbeg+j]; occ += (v>0); cnt += v; }
  so_[t]=occ; sc_[t]=cnt; __syncthreads();
  for (int off=1; off<1024; off<<=1){
    int vo=0, vc=0;
    if (t>=off){ vo=so_[t-off]; vc=sc_[t-off]; }
    __syncthreads();
    if (t>=off){ so_[t]+=vo; sc_[t]+=vc; }
    __syncthreads();
  }
  int eo = so_[t]-occ, ec = sc_[t]-cnt;
  if (t==1023) misc[1+b] = (so_[1023] < MAXP) ? so_[1023] : MAXP; // npil
  int kept=0;
  for (int j=0;j<64;j++){
    int c = cbeg+j; int v = ccnt[base+c];
    if (v>0){
      crank[base+c]=eo; cstart[base+c]=ec;
      if (eo<MAXP){
        pcell[b*MAXP+eo]=c;
        kept += (v<MAXPP)? v : MAXPP;
        if (v>MAXPP){
          int hi = atomicAdd(&heavy[b],1);
          if (hi<64) heavy[2 + b*64 + hi] = c;
        }
      }
      eo++; ec+=v;
    } else {
      crank[base+c]=-1;
    }
  }
  atomicAdd(&misc[3+b], kept); // nk
}

__global__ void scatter_points(const int* __restrict__ pid, const int* __restrict__ ccnt,
    const int* __restrict__ crank, const int* __restrict__ cstart,
    int* __restrict__ ctmp, int* __restrict__ plist, int* __restrict__ pptr){
  int i = blockIdx.x*blockDim.x + threadIdx.x;
  if (i>=NPTS) return;
  int b = blockIdx.y;
  int gi = b*NPTS+i;
  int cell = pid[gi];
  if (cell<0) return;
  int bc = b*NCELL+cell;
  int pos = cstart[bc] + atomicAdd(&ctmp[bc],1);
  plist[b*NPTS+pos] = i;
  int r = crank[bc];
  if (r>=0 && r<MAXP && ccnt[bc]<=MAXPP) pptr[gi] = r;
}

__global__ void heavy_select(const int* __restrict__ ccnt, const int* __restrict__ crank,
    const int* __restrict__ cstart, const int* __restrict__ plist,
    const int* __restrict__ heavy, int* __restrict__ pptr){
  int b = blockIdx.y;
  int hn = heavy[b]; if (hn>64) hn=64;
  if ((int)blockIdx.x >= hn) return;
  int cell = heavy[2 + b*64 + blockIdx.x];
  int bc = b*NCELL+cell;
  int cnt = ccnt[bc], start = cstart[bc], pr = crank[bc];
  for (int e=threadIdx.x; e<cnt; e+=blockDim.x){
    int pe = plist[b*NPTS+start+e];
    int rank=0;
    for (int k=0;k<cnt;k++) rank += (plist[b*NPTS+start+k] < pe);
    if (rank<MAXPP) pptr[b*NPTS+pe] = pr;
  }
}

__global__ void centroid_acc(const float* __restrict__ pts, const int* __restrict__ pptr,
                             float* __restrict__ psum){
  int i = blockIdx.x*blockDim.x + threadIdx.x;
  if (i>=NPTS) return;
  int b = blockIdx.y;
  int gi = b*NPTS+i;
  int p = pptr[gi];
  if (p<0) return;
  const float* q = &pts[(size_t)gi*5];
  float* s = &psum[(size_t)(b*MAXP+p)*4];
  atomicAdd(s+0,q[0]); atomicAdd(s+1,q[1]); atomicAdd(s+2,q[2]); atomicAdd(s+3,1.0f);
}

__global__ void centroid_fin(float* __restrict__ psum){
  int i = blockIdx.x*blockDim.x + threadIdx.x;
  if (i>=2*MAXP) return;
  float* s = &psum[(size_t)i*4];
  float inv = 1.0f / fmaxf(s[3],1.0f);
  s[0]*=inv; s[1]*=inv; s[2]*=inv;
}

// ---------------- moments: Sum(aug), Sum(aug x aug) over kept points ----------------
// stats[b*512 + k]: k in [0,55) pair moments (d<=e), [55,65) linear sums.
__global__ __launch_bounds__(256) void moments_k(const float* __restrict__ pts,
    const int* __restrict__ pid, const int* __restrict__ pptr,
    const float* __restrict__ psum, float* __restrict__ stats){
  int b = blockIdx.y;
  float acc[65];
  #pragma unroll
  for (int k=0;k<65;k++) acc[k]=0.f;
  for (int i = blockIdx.x*256+threadIdx.x; i<NPTS; i += gridDim.x*256){
    int gi = b*NPTS+i;
    int p = pptr[gi];
    if (p<0) continue;
    const float* q = &pts[(size_t)gi*5];
    const float* mc = &psum[(size_t)(b*MAXP+p)*4];
    int cell = pid[gi];
    float aug[10];
    aug[0]=q[0]; aug[1]=q[1]; aug[2]=q[2]; aug[3]=q[3]; aug[4]=q[4];
    aug[5]=q[0]-mc[0]; aug[6]=q[1]-mc[1]; aug[7]=q[2]-mc[2];
    aug[8]=-32.0f+((float)(cell&255)+0.5f)*0.25f;
    aug[9]=-32.0f+((float)(cell>>8)+0.5f)*0.25f;
    #pragma unroll
    for (int d=0; d<10; d++){
      #pragma unroll
      for (int e=d; e<10; e++){
        acc[d*10 - d*(d-1)/2 + (e-d)] += aug[d]*aug[e];
      }
      acc[55+d] += aug[d];
    }
  }
  int lane = threadIdx.x & 63;
  #pragma unroll
  for (int k=0;k<65;k++){
    float v = acc[k];
    #pragma unroll
    for (int off=32; off>0; off>>=1) v += __shfl_xor(v, off, 64);
    if (lane==0) atomicAdd(&stats[(size_t)b*512+k], v);
  }
}

// stats layout per batch (512 floats):
// [0,65)   moments
// [128,192) s2 (layer2 pre-BN sum)   [192,256) q2 (sum of squares)
// [256,320) sc1  [320,384) sh1  [384,448) sc2  [448,512) sh2
__global__ void stats_fin1(const float* __restrict__ w1, const float* __restrict__ b1,
    const float* __restrict__ g1, const float* __restrict__ be1,
    const float* __restrict__ w2, const float* __restrict__ b2,
    float* __restrict__ stats, const int* __restrict__ misc){
  __shared__ float z0s[64];
  int b = blockIdx.x, c = threadIdx.x;
  float* S = &stats[(size_t)b*512];
  float wcol[10];
  #pragma unroll
  for (int d=0;d<10;d++) wcol[d] = w1[d*64+c];
  float b1c = b1[c];
  float nk = (float)misc[3+b];
  const float N = (float)NROWS;
  float pad = N - nk;
  // S = sum over kept of y = L.w + nk*b1
  float s = nk*b1c;
  #pragma unroll
  for (int d=0;d<10;d++) s += S[55+d]*wcol[d];
  // Q = sum over kept of y^2 = w^T M w + 2 b1 (L.w) + nk b1^2
  float lw = s - nk*b1c;
  float qq = nk*b1c*b1c + 2.f*b1c*lw;
  #pragma unroll
  for (int d=0; d<10; d++){
    #pragma unroll
    for (int e=d; e<10; e++){
      float m = S[d*10 - d*(d-1)/2 + (e-d)];
      qq += ((d==e)?1.f:2.f)*m*wcol[d]*wcol[e];
    }
  }
  // pad rows contribute y = b1
  float St = s + pad*b1c;
  float Qt = qq + pad*b1c*b1c;
  float mu = St/N;
  float var = fmaxf(Qt/N - mu*mu, 0.f);
  float sc = g1[c]*rsqrtf(var+1e-5f);
  float sh = be1[c]-mu*sc;
  S[256+c]=sc; S[320+c]=sh;
  // seed layer2 stats with pad-row contribution
  float z0 = fmaxf(b1c*sc+sh, 0.f);
  z0s[c]=z0;
  __syncthreads();
  float t0 = b2[c];
  for (int i2=0;i2<64;i2++) t0 += z0s[i2]*w2[(size_t)i2*64+c];
  S[128+c]=pad*t0; S[192+c]=pad*t0*t0;
}

// ---------------- pillar-centric MLP + in-register max/min ----------------
// one wave per pillar; lane = channel. No spills, no LDS, no atomics in the hot loop.
__global__ __launch_bounds__(256) void pillar_mlp(const float* __restrict__ pts,
    const int* __restrict__ plist, const int* __restrict__ pcell,
    const int* __restrict__ cstart, const int* __restrict__ ccnt,
    const int* __restrict__ pptr, const float* __restrict__ psum,
    const int* __restrict__ misc,
    const float* __restrict__ w1, const float* __restrict__ b1,
    const float* __restrict__ w2, const float* __restrict__ b2,
    float* __restrict__ stats, float* __restrict__ fmx, float* __restrict__ fmn){
  const int lane = threadIdx.x & 63;
  float w1c[10];
  #pragma unroll
  for (int d=0;d<10;d++) w1c[d] = w1[d*64+lane];
  float w2c[64];
  #pragma unroll
  for (int c=0;c<64;c++) w2c[c] = w2[(size_t)c*64+lane];
  const float b1c = b1[lane], b2c = b2[lane];
  const float sc1_0 = stats[256+lane], sh1_0 = stats[320+lane];
  const float sc1_1 = stats[512+256+lane], sh1_1 = stats[512+320+lane];
  const int npil0 = misc[1], npil1 = misc[2];
  float s2_0=0.f, q2_0=0.f, s2_1=0.f, q2_1=0.f;

  const int wglobal = (blockIdx.x*256 + threadIdx.x) >> 6;
  const int nwaves = (gridDim.x*256) >> 6;
  for (int qq = wglobal; qq < 2*MAXP; qq += nwaves){
    int b = (qq >= MAXP) ? 1 : 0;
    int p = qq - b*MAXP;
    int npil = b ? npil1 : npil0;
    if (p >= npil) continue;
    int cell = pcell[b*MAXP+p];
    int bc = b*NCELL+cell;
    int cnt = ccnt[bc], start = cstart[bc];
    bool heavy = cnt > MAXPP;
    float gx = -32.0f + ((float)(cell&255)+0.5f)*0.25f;
    float gy = -32.0f + ((float)(cell>>8)+0.5f)*0.25f;
    const float* mc = &psum[(size_t)(b*MAXP+p)*4];
    float mx = mc[0], my = mc[1], mz = mc[2];
    float sc1 = b ? sc1_1 : sc1_0;
    float sh1 = b ? sh1_1 : sh1_0;
    float tmax = -1e30f, tmin = 1e30f;
    float s2 = 0.f, q2 = 0.f;
    for (int k=0; k<cnt; k++){
      int i = plist[b*NPTS+start+k];
      if (heavy && pptr[b*NPTS+i] != p) continue;
      const float* qp = &pts[(size_t)(b*NPTS+i)*5];
      float x=qp[0], y=qp[1], z=qp[2], i1=qp[3], i2=qp[4];
      float acc = b1c;
      acc = fmaf(x, w1c[0], acc);
      acc = fmaf(y, w1c[1], acc);
      acc = fmaf(z, w1c[2], acc);
      acc = fmaf(i1, w1c[3], acc);
      acc = fmaf(i2, w1c[4], acc);
      acc = fmaf(x-mx, w1c[5], acc);
      acc = fmaf(y-my, w1c[6], acc);
      acc = fmaf(z-mz, w1c[7], acc);
      acc = fmaf(gx, w1c[8], acc);
      acc = fmaf(gy, w1c[9], acc);
      float zz = fmaxf(acc*sc1+sh1, 0.f);
      float t = b2c;
      #pragma unroll
      for (int c=0;c<64;c++){
        float zc = __int_as_float(__builtin_amdgcn_readlane(__float_as_int(zz), c));
        t = fmaf(zc, w2c[c], t);
      }
      tmax = fmaxf(tmax, t);
      tmin = fminf(tmin, t);
      s2 += t; q2 += t*t;
    }
    fmx[(size_t)(b*MAXP+p)*64 + lane] = tmax;
    fmn[(size_t)(b*MAXP+p)*64 + lane] = tmin;
    if (b){ s2_1 += s2; q2_1 += q2; } else { s2_0 += s2; q2_0 += q2; }
  }
  atomicAdd(&stats[128+lane], s2_0);
  atomicAdd(&stats[192+lane], q2_0);
  atomicAdd(&stats[512+128+lane], s2_1);
  atomicAdd(&stats[512+192+lane], q2_1);
}

__global__ void stats_fin2(const float* __restrict__ g2,const float* __restrict__ be2,
                           float* __restrict__ stats){
  int b = blockIdx.x, c = threadIdx.x;
  float* S = &stats[(size_t)b*512];
  const float N = (float)NROWS;
  float m = S[128+c]/N;
  float v = fmaxf(S[192+c]/N - m*m, 0.f);
  float sc = g2[c]*rsqrtf(v+1e-5f);
  S[384+c]=sc; S[448+c]=be2[c]-m*sc;
}

// BN2+relu applied to the pillar max (or min when sc2<0 — monotone transform), scattered to BEV
__global__ void scatter_bev(const float* __restrict__ fmx, const float* __restrict__ fmn,
                            const int* __restrict__ pcell, const int* __restrict__ misc,
                            const float* __restrict__ stats, float* __restrict__ bev){
  int tid = blockIdx.x*256+threadIdx.x;
  if (tid >= 2*64*MAXP) return;
  int c = tid & 63;
  int bp = tid >> 6;
  int b = bp / MAXP;
  int p = bp - b*MAXP;
  if (p >= misc[1+b]) return;
  float sc2 = stats[(size_t)b*512+384+c], sh2 = stats[(size_t)b*512+448+c];
  float t = (sc2 >= 0.f) ? fmx[tid] : fmn[tid];
  float v = fmaxf(sc2*t+sh2, 0.f);
  bev[(((size_t)(b*64+c))<<16) + pcell[b*MAXP+p]] = v;
}

// ---------------- conv stack ----------------
__global__ __launch_bounds__(256,2) void conv3x3(const float* __restrict__ in, float* __restrict__ out,
    const float* __restrict__ w, const float* __restrict__ bias,
    const float* __restrict__ bnsc, const float* __restrict__ bnsh){
  __shared__ __align__(16) float sIn[16][18][20];
  __shared__ __align__(16) float sW[16][9][64];
  const int tX = blockIdx.x*16, tY = blockIdx.y*16, b = blockIdx.z;
  const int t = threadIdx.x;
  const int ocg = t&7, pg = t>>3;
  const int py = pg>>1, x0 = (pg&1)*8, oc0 = ocg*8;
  float acc[8][8];
  #pragma unroll
  for (int k=0;k<8;k++)
    #pragma unroll
    for (int j=0;j<8;j++) acc[k][j]=0.f;

  for (int cc=0;cc<4;cc++){
    const int ic0 = cc*16;
    __syncthreads();
    for (int e=t;e<16*18*18;e+=256){
      int ic = e/324; int r = e-ic*324; int yy=r/18, xx=r-yy*18;
      int gy = tY+yy-1, gx = tX+xx-1;
      float v = 0.f;
      if ((unsigned)gy<256u && (unsigned)gx<256u){
        v = in[(((size_t)(b*64+ic0+ic))<<16) + (gy<<8) + gx];
        if (bnsc){ v = fmaxf(v*bnsc[ic0+ic]+bnsh[ic0+ic], 0.f); }
      }
      sIn[ic][yy][xx]=v;
    }
    for (int e=t;e<16*9*64;e+=256){
      int ic = e/576; int r = e-ic*576; int tap = r>>6; int oc = r&63;
      sW[ic][tap][oc] = w[((size_t)oc*64+(ic0+ic))*9 + tap];
    }
    __syncthreads();
    for (int ic=0;ic<16;ic++){
      #pragma unroll
      for (int dy=0;dy<3;dy++){
        const float* ip = &sIn[ic][py+dy][x0];
        float4 A0 = *(const float4*)ip;
        float4 A1 = *(const float4*)(ip+4);
        float4 A2 = *(const float4*)(ip+8);
        float v[12] = {A0.x,A0.y,A0.z,A0.w,A1.x,A1.y,A1.z,A1.w,A2.x,A2.y,A2.z,A2.w};
        #pragma unroll
        for (int dx=0;dx<3;dx++){
          const float4* wp = (const float4*)&sW[ic][dy*3+dx][oc0];
          float4 W0 = wp[0], W1 = wp[1];
          float wv[8] = {W0.x,W0.y,W0.z,W0.w,W1.x,W1.y,W1.z,W1.w};
          #pragma unroll
          for (int k=0;k<8;k++)
            #pragma unroll
            for (int j=0;j<8;j++) acc[k][j] += v[dx+k]*wv[j];
        }
      }
    }
  }
  #pragma unroll
  for (int j=0;j<8;j++){
    float bj = bias[oc0+j];
    float* dst = &out[(((size_t)(b*64+oc0+j))<<16) + ((tY+py)<<8) + tX + x0];
    float4 o0 = make_float4(acc[0][j]+bj, acc[1][j]+bj, acc[2][j]+bj, acc[3][j]+bj);
    float4 o1 = make_float4(acc[4][j]+bj, acc[5][j]+bj, acc[6][j]+bj, acc[7][j]+bj);
    *(float4*)dst = o0; *(float4*)(dst+4) = o1;
  }
}

__global__ __launch_bounds__(256) void bn_stats(const float* __restrict__ x, float* __restrict__ bnst){
  int c = blockIdx.x, part = blockIdx.y;
  float s=0.f, q=0.f;
  for (int b=0;b<2;b++){
    const float4* p = (const float4*)&x[(((size_t)(b*64+c))<<16) + (size_t)part*8192];
    for (int k=threadIdx.x;k<2048;k+=256){
      float4 v = p[k];
      s += v.x+v.y+v.z+v.w;
      q += v.x*v.x+v.y*v.y+v.z*v.z+v.w*v.w;
    }
  }
  __shared__ float rs[256], rq[256];
  rs[threadIdx.x]=s; rq[threadIdx.x]=q; __syncthreads();
  for (int o=128;o>0;o>>=1){
    if (threadIdx.x<o){ rs[threadIdx.x]+=rs[threadIdx.x+o]; rq[threadIdx.x]+=rq[threadIdx.x+o]; }
    __syncthreads();
  }
  if (threadIdx.x==0){ atomicAdd(&bnst[c], rs[0]); atomicAdd(&bnst[64+c], rq[0]); }
}

__global__ void bn_fin(float* __restrict__ bnst, const float* __restrict__ g, const float* __restrict__ be){
  int c = threadIdx.x;
  const float n = 131072.f;
  float m = bnst[c]/n;
  float v = fmaxf(bnst[64+c]/n - m*m, 0.f);
  float sc = g[c]*rsqrtf(v+1e-5f);
  bnst[128+c]=sc; bnst[192+c]=be[c]-m*sc;
}

__global__ __launch_bounds__(256) void bn_apply(float* __restrict__ x, const float* __restrict__ bnst){
  size_t idx = (size_t)blockIdx.x*256 + threadIdx.x;
  size_t stride = (size_t)gridDim.x*256;
  float4* p = (float4*)x;
  for (size_t k=idx; k<2097152ULL; k+=stride){
    int c = (int)((k>>14)&63);
    float sc = bnst[128+c], sh = bnst[192+c];
    float4 v = p[k];
    v.x=fmaxf(v.x*sc+sh,0.f); v.y=fmaxf(v.y*sc+sh,0.f);
    v.z=fmaxf(v.z*sc+sh,0.f); v.w=fmaxf(v.w*sc+sh,0.f);
    p[k]=v;
  }
}

// ---------------- launch ----------------
extern "C" void kernel_launch(void* const* d_in, const int* in_sizes, int n_in,
                              void* d_out, int out_size, void* d_ws, size_t ws_size,
                              hipStream_t stream){
  const float* pts  = (const float*)d_in[0];
  const void*  mask = d_in[1];
  const float* w1 = (const float*)d_in[2];
  const float* b1 = (const float*)d_in[3];
  const float* g1 = (const float*)d_in[4];
  const float* be1= (const float*)d_in[5];
  const float* w2 = (const float*)d_in[6];
  const float* b2 = (const float*)d_in[7];
  const float* g2 = (const float*)d_in[8];
  const float* be2= (const float*)d_in[9];
  const float* cw[3]  = {(const float*)d_in[10],(const float*)d_in[14],(const float*)d_in[18]};
  const float* cb[3]  = {(const float*)d_in[11],(const float*)d_in[15],(const float*)d_in[19]};
  const float* cg[3]  = {(const float*)d_in[12],(const float*)d_in[16],(const float*)d_in[20]};
  const float* cbe[3] = {(const float*)d_in[13],(const float*)d_in[17],(const float*)d_in[21]};
  float* out = (float*)d_out;

  char* W = (char*)d_ws;
  size_t off = 0;
  auto A = [&](size_t n){ size_t r = off; off = (off + n + 255) & ~(size_t)255; return r; };
  float*    BIG   = (float*)   (W + A(33554432));
  int*      PID   = (int*)     (W + A((size_t)2*NPTS*4));
  int*      CCNT  = (int*)     (W + A((size_t)2*NCELL*4));
  int*      CRANK = (int*)     (W + A((size_t)2*NCELL*4));
  int*      CSTART= (int*)     (W + A((size_t)2*NCELL*4));
  int*      CTMP  = (int*)     (W + A((size_t)2*NCELL*4));
  int*      PLIST = (int*)     (W + A((size_t)2*NPTS*4));
  int*      PPTR  = (int*)     (W + A((size_t)2*NPTS*4));
  int*      PCELL = (int*)     (W + A((size_t)2*MAXP*4));
  float*    PSUM  = (float*)   (W + A((size_t)2*MAXP*16));
  float*    FMX   = (float*)   (W + A((size_t)2*MAXP*64*4));
  float*    FMN   = (float*)   (W + A((size_t)2*MAXP*64*4));
  float*    STATS = (float*)   (W + A((size_t)2*512*4));
  float*    BNST  = (float*)   (W + A((size_t)256*4));
  int*      HEAVY = (int*)     (W + A((size_t)(2+2*64)*4));
  int*      MISC  = (int*)     (W + A(256));

  hipMemsetAsync(BIG,  0, 33554432, stream);
  hipMemsetAsync(CCNT, 0, (size_t)2*NCELL*4, stream);
  hipMemsetAsync(CTMP, 0, (size_t)2*NCELL*4, stream);
  hipMemsetAsync(PPTR, 0xFF, (size_t)2*NPTS*4, stream);
  hipMemsetAsync(PSUM, 0, (size_t)2*MAXP*16, stream);
  hipMemsetAsync(STATS,0, (size_t)2*512*4, stream);
  hipMemsetAsync(BNST, 0, (size_t)256*4, stream);
  hipMemsetAsync(HEAVY,0, (size_t)(2+2*64)*4, stream);
  hipMemsetAsync(MISC, 0, 256, stream);

  dim3 perPt((NPTS+255)/256, 2);

  probe_mask<<<1,256,0,stream>>>((const unsigned*)mask, MISC);
  compute_pid<<<perPt,256,0,stream>>>(pts, mask, MISC, PID, CCNT);
  scan_cells<<<2,1024,0,stream>>>(CCNT, CRANK, CSTART, PCELL, MISC, HEAVY);
  scatter_points<<<perPt,256,0,stream>>>(PID, CCNT, CRANK, CSTART, CTMP, PLIST, PPTR);
  heavy_select<<<dim3(64,2),64,0,stream>>>(CCNT, CRANK, CSTART, PLIST, HEAVY, PPTR);
  centroid_acc<<<perPt,256,0,stream>>>(pts, PPTR, PSUM);
  centroid_fin<<<(2*MAXP+255)/256,256,0,stream>>>(PSUM);
  moments_k<<<dim3(120,2),256,0,stream>>>(pts, PID, PPTR, PSUM, STATS);
  stats_fin1<<<2,64,0,stream>>>(w1, b1, g1, be1, w2, b2, STATS, MISC);
  pillar_mlp<<<512,256,0,stream>>>(pts, PLIST, PCELL, CSTART, CCNT, PPTR, PSUM, MISC,
                                   w1, b1, w2, b2, STATS, FMX, FMN);
  stats_fin2<<<2,64,0,stream>>>(g2, be2, STATS);
  scatter_bev<<<(2*64*MAXP+255)/256,256,0,stream>>>(FMX, FMN, PCELL, MISC, STATS, BIG);

  // conv1: BIG(bev) -> d_out (raw + bias)
  conv3x3<<<dim3(16,16,2),256,0,stream>>>(BIG, out, cw[0], cb[0], nullptr, nullptr);
  bn_stats<<<dim3(64,8),256,0,stream>>>(out, BNST);
  bn_fin<<<1,64,0,stream>>>(BNST, cg[0], cbe[0]);
  // conv2: d_out (bn1+relu on stage) -> BIG
  conv3x3<<<dim3(16,16,2),256,0,stream>>>(out, BIG, cw[1], cb[1], BNST+128, BNST+192);
  hipMemsetAsync(BNST, 0, 512, stream);
  bn_stats<<<dim3(64,8),256,0,stream>>>(BIG, BNST);
  bn_fin<<<1,64,0,stream>>>(BNST, cg[1], cbe[1]);
  // conv3: BIG (bn2+relu on stage) -> d_out
  conv3x3<<<dim3(16,16,2),256,0,stream>>>(BIG, out, cw[2], cb[2], BNST+128, BNST+192);
  hipMemsetAsync(BNST, 0, 512, stream);
  bn_stats<<<dim3(64,8),256,0,stream>>>(out, BNST);
  bn_fin<<<1,64,0,stream>>>(BNST, cg[2], cbe[2]);
  bn_apply<<<2048,256,0,stream>>>(out, BNST);
}

// Round 3
// 787.775 us; speedup vs baseline: 1.5927x; 1.2922x over previous
//
#include <hip/hip_runtime.h>

#define NPTS 60000
#define NXG 256
#define NCELL 65536
#define MAXP 12000
#define MAXPP 32
#define NROWS (MAXP*MAXPP)

typedef float f32x32 __attribute__((ext_vector_type(32)));

// ---------------- mask dtype probe ----------------
// misc[0]: 0 = int32, 1 = uint8, 2 = float32
__global__ void probe_mask(const unsigned* __restrict__ m, int* __restrict__ misc){
  __shared__ int cf32, cbig;
  if (threadIdx.x==0){ cf32=0; cbig=0; }
  __syncthreads();
  int lf=0, lb=0;
  for (int k=0;k<4;k++){
    unsigned x = m[threadIdx.x*4+k];
    if (x==0x3f800000u) lf++;
    else if (x>1u) lb++;
  }
  atomicAdd(&cf32, lf); atomicAdd(&cbig, lb);
  __syncthreads();
  if (threadIdx.x==0){
    int mode=0;
    if (cf32>64) mode=2; else if (cbig>0) mode=1;
    misc[0]=mode;
  }
}

// ---------------- pillarize ----------------
__global__ void compute_pid(const float* __restrict__ pts, const void* __restrict__ maskp,
                            const int* __restrict__ misc, int* __restrict__ pid,
                            int* __restrict__ ccnt){
  int i = blockIdx.x*blockDim.x + threadIdx.x;
  if (i>=NPTS) return;
  int b = blockIdx.y;
  int gi = b*NPTS+i;
  int mode = misc[0];
  bool m;
  if (mode==0)      m = ((const int*)maskp)[gi]!=0;
  else if (mode==1) m = ((const unsigned char*)maskp)[gi]!=0;
  else              m = ((const float*)maskp)[gi]!=0.f;
  int cell = -1;
  if (m){
    float x = pts[(size_t)gi*5+0], y = pts[(size_t)gi*5+1];
    int ix = (int)((x - (-32.0f)) / 0.25f);
    ix = ix<0?0:(ix>255?255:ix);
    int iy = (int)((y - (-32.0f)) / 0.25f);
    iy = iy<0?0:(iy>255?255:iy);
    cell = iy*NXG + ix;
    atomicAdd(&ccnt[b*NCELL+cell], 1);
  }
  pid[gi] = cell;
}

// one block per batch, 1024 threads, 64 cells/thread
__global__ __launch_bounds__(1024) void scan_cells(const int* __restrict__ ccnt,
    int* __restrict__ crank, int* __restrict__ cstart, int* __restrict__ pcell,
    int* __restrict__ misc, int* __restrict__ heavy){
  __shared__ int so_[1024], sc_[1024];
  int b = blockIdx.x, t = threadIdx.x;
  const int base = b*NCELL;
  const int cbeg = t*64;
  int occ=0, cnt=0;
  for (int j=0;j<64;j++){ int v=ccnt[base+cbeg+j]; occ += (v>0); cnt += v; }
  so_[t]=occ; sc_[t]=cnt; __syncthreads();
  for (int off=1; off<1024; off<<=1){
    int vo=0, vc=0;
    if (t>=off){ vo=so_[t-off]; vc=sc_[t-off]; }
    __syncthreads();
    if (t>=off){ so_[t]+=vo; sc_[t]+=vc; }
    __syncthreads();
  }
  int eo = so_[t]-occ, ec = sc_[t]-cnt;
  if (t==1023) misc[1+b] = (so_[1023] < MAXP) ? so_[1023] : MAXP; // npil
  int kept=0;
  for (int j=0;j<64;j++){
    int c = cbeg+j; int v = ccnt[base+c];
    if (v>0){
      crank[base+c]=eo; cstart[base+c]=ec;
      if (eo<MAXP){
        pcell[b*MAXP+eo]=c;
        kept += (v<MAXPP)? v : MAXPP;
        if (v>MAXPP){
          int hi = atomicAdd(&heavy[b],1);
          if (hi<64) heavy[2 + b*64 + hi] = c;
        }
      }
      eo++; ec+=v;
    } else {
      crank[base+c]=-1;
    }
  }
  atomicAdd(&misc[3+b], kept); // nk
}

__global__ void scatter_points(const int* __restrict__ pid, const int* __restrict__ ccnt,
    const int* __restrict__ crank, const int* __restrict__ cstart,
    int* __restrict__ ctmp, int* __restrict__ plist, int* __restrict__ pptr){
  int i = blockIdx.x*blockDim.x + threadIdx.x;
  if (i>=NPTS) return;
  int b = blockIdx.y;
  int gi = b*NPTS+i;
  int cell = pid[gi];
  if (cell<0) return;
  int bc = b*NCELL+cell;
  int pos = cstart[bc] + atomicAdd(&ctmp[bc],1);
  plist[b*NPTS+pos] = i;
  int r = crank[bc];
  if (r>=0 && r<MAXP && ccnt[bc]<=MAXPP) pptr[gi] = r;
}

__global__ void heavy_select(const int* __restrict__ ccnt, const int* __restrict__ crank,
    const int* __restrict__ cstart, const int* __restrict__ plist,
    const int* __restrict__ heavy, int* __restrict__ pptr){
  int b = blockIdx.y;
  int hn = heavy[b]; if (hn>64) hn=64;
  if ((int)blockIdx.x >= hn) return;
  int cell = heavy[2 + b*64 + blockIdx.x];
  int bc = b*NCELL+cell;
  int cnt = ccnt[bc], start = cstart[bc], pr = crank[bc];
  for (int e=threadIdx.x; e<cnt; e+=blockDim.x){
    int pe = plist[b*NPTS+start+e];
    int rank=0;
    for (int k=0;k<cnt;k++) rank += (plist[b*NPTS+start+k] < pe);
    if (rank<MAXPP) pptr[b*NPTS+pe] = pr;
  }
}

// ---------------- layer-1 BN stats (pillar-centric, lane=channel) ----------------
// Also computes pillar centroids (psum) on the fly.
// lstat[rep][b][sq][64], 16 replicas.
__global__ __launch_bounds__(256) void l1_stats(const float* __restrict__ pts,
    const int* __restrict__ plist, const int* __restrict__ pcell,
    const int* __restrict__ cstart, const int* __restrict__ ccnt,
    const int* __restrict__ pptr, float* __restrict__ psum,
    const int* __restrict__ misc,
    const float* __restrict__ w1, const float* __restrict__ b1,
    float* __restrict__ lstat){
  const int lane = threadIdx.x & 63;
  float w1c[10];
  #pragma unroll
  for (int d=0;d<10;d++) w1c[d]=w1[d*64+lane];
  const float b1c = b1[lane];
  const int npil0 = misc[1], npil1 = misc[2];
  float s0=0.f,q0=0.f,s1=0.f,q1=0.f;
  const int wglobal = (blockIdx.x*256+threadIdx.x)>>6;
  const int nwaves = (gridDim.x*256)>>6;
  for (int qq=wglobal; qq<2*MAXP; qq+=nwaves){
    int b = (qq>=MAXP)?1:0;
    int p = qq-b*MAXP;
    if (p >= (b?npil1:npil0)) continue;
    int cell = pcell[b*MAXP+p];
    int bc = b*NCELL+cell;
    int cnt = ccnt[bc], start = cstart[bc];
    bool heavy = cnt>MAXPP;
    float sx=0.f,sy=0.f,sz=0.f,n=0.f;
    for (int k=0;k<cnt;k++){
      int i = plist[b*NPTS+start+k];
      if (heavy && pptr[b*NPTS+i]!=p) continue;
      const float* qp = &pts[(size_t)(b*NPTS+i)*5];
      sx+=qp[0]; sy+=qp[1]; sz+=qp[2]; n+=1.f;
    }
    float inv = 1.f/fmaxf(n,1.f);
    float mx=sx*inv, my=sy*inv, mz=sz*inv;
    if (lane==0){
      *(float4*)&psum[(size_t)(b*MAXP+p)*4] = make_float4(mx,my,mz,n);
    }
    float gx = -32.0f+((float)(cell&255)+0.5f)*0.25f;
    float gy = -32.0f+((float)(cell>>8)+0.5f)*0.25f;
    float s=0.f,q=0.f;
    for (int k=0;k<cnt;k++){
      int i = plist[b*NPTS+start+k];
      if (heavy && pptr[b*NPTS+i]!=p) continue;
      const float* qp = &pts[(size_t)(b*NPTS+i)*5];
      float x=qp[0], y=qp[1], z=qp[2], i1=qp[3], i2=qp[4];
      float acc=b1c;
      acc=fmaf(x,w1c[0],acc);  acc=fmaf(y,w1c[1],acc);  acc=fmaf(z,w1c[2],acc);
      acc=fmaf(i1,w1c[3],acc); acc=fmaf(i2,w1c[4],acc);
      acc=fmaf(x-mx,w1c[5],acc); acc=fmaf(y-my,w1c[6],acc); acc=fmaf(z-mz,w1c[7],acc);
      acc=fmaf(gx,w1c[8],acc);   acc=fmaf(gy,w1c[9],acc);
      s+=acc; q+=acc*acc;
    }
    if (b){ s1+=s; q1+=q; } else { s0+=s; q0+=q; }
  }
  int rep = wglobal & 15;
  atomicAdd(&lstat[((rep*2+0)*2+0)*64+lane], s0);
  atomicAdd(&lstat[((rep*2+0)*2+1)*64+lane], q0);
  atomicAdd(&lstat[((rep*2+1)*2+0)*64+lane], s1);
  atomicAdd(&lstat[((rep*2+1)*2+1)*64+lane], q1);
}

// stats layout per batch (512 floats):
// [128,192) s2 pad seed  [192,256) q2 pad seed
// [256,320) sc1 [320,384) sh1 [384,448) sc2 [448,512) sh2
__global__ void stats_fin1(const float* __restrict__ w1, const float* __restrict__ b1,
    const float* __restrict__ g1, const float* __restrict__ be1,
    const float* __restrict__ w2, const float* __restrict__ b2,
    const float* __restrict__ lstat, float* __restrict__ stats,
    const int* __restrict__ misc){
  __shared__ float z0s[64];
  int b = blockIdx.x, c = threadIdx.x;
  float* S = &stats[(size_t)b*512];
  float s=0.f, q=0.f;
  for (int r=0;r<16;r++){
    s += lstat[((r*2+b)*2+0)*64+c];
    q += lstat[((r*2+b)*2+1)*64+c];
  }
  float b1c = b1[c];
  float nk = (float)misc[3+b];
  const float N = (float)NROWS;
  float pad = N - nk;
  float St = s + pad*b1c;
  float Qt = q + pad*b1c*b1c;
  float mu = St/N;
  float var = fmaxf(Qt/N - mu*mu, 0.f);
  float sc = g1[c]*rsqrtf(var+1e-5f);
  float sh = be1[c]-mu*sc;
  S[256+c]=sc; S[320+c]=sh;
  float z0 = fmaxf(b1c*sc+sh, 0.f);
  z0s[c]=z0;
  __syncthreads();
  float t0 = b2[c];
  for (int i2=0;i2<64;i2++) t0 += z0s[i2]*w2[(size_t)i2*64+c];
  S[128+c]=pad*t0; S[192+c]=pad*t0*t0;
}

// ---------------- pillar-centric MLP + in-register max/min ----------------
__global__ __launch_bounds__(256) void pillar_mlp(const float* __restrict__ pts,
    const int* __restrict__ plist, const int* __restrict__ pcell,
    const int* __restrict__ cstart, const int* __restrict__ ccnt,
    const int* __restrict__ pptr, const float* __restrict__ psum,
    const int* __restrict__ misc,
    const float* __restrict__ w1, const float* __restrict__ b1,
    const float* __restrict__ w2, const float* __restrict__ b2,
    const float* __restrict__ stats, float* __restrict__ l2stat,
    float* __restrict__ fmx, float* __restrict__ fmn){
  const int lane = threadIdx.x & 63;
  float w1c[10];
  #pragma unroll
  for (int d=0;d<10;d++) w1c[d] = w1[d*64+lane];
  f32x32 w2lo, w2hi;
  #pragma unroll
  for (int c=0;c<32;c++) w2lo[c] = w2[(size_t)c*64+lane];
  #pragma unroll
  for (int c=0;c<32;c++) w2hi[c] = w2[(size_t)(c+32)*64+lane];
  const float b1c = b1[lane], b2c = b2[lane];
  const float sc1_0 = stats[256+lane], sh1_0 = stats[320+lane];
  const float sc1_1 = stats[512+256+lane], sh1_1 = stats[512+320+lane];
  const int npil0 = misc[1], npil1 = misc[2];
  float s2_0=0.f, q2_0=0.f, s2_1=0.f, q2_1=0.f;

  const int wglobal = (blockIdx.x*256 + threadIdx.x) >> 6;
  const int nwaves = (gridDim.x*256) >> 6;
  for (int qq = wglobal; qq < 2*MAXP; qq += nwaves){
    int b = (qq >= MAXP) ? 1 : 0;
    int p = qq - b*MAXP;
    int npil = b ? npil1 : npil0;
    if (p >= npil) continue;
    int cell = pcell[b*MAXP+p];
    int bc = b*NCELL+cell;
    int cnt = ccnt[bc], start = cstart[bc];
    bool heavy = cnt > MAXPP;
    float gx = -32.0f + ((float)(cell&255)+0.5f)*0.25f;
    float gy = -32.0f + ((float)(cell>>8)+0.5f)*0.25f;
    const float* mc = &psum[(size_t)(b*MAXP+p)*4];
    float mx = mc[0], my = mc[1], mz = mc[2];
    float sc1 = b ? sc1_1 : sc1_0;
    float sh1 = b ? sh1_1 : sh1_0;
    float tmax = -1e30f, tmin = 1e30f;
    float s2 = 0.f, q2 = 0.f;
    for (int k=0; k<cnt; k++){
      int i = plist[b*NPTS+start+k];
      if (heavy && pptr[b*NPTS+i] != p) continue;
      const float* qp = &pts[(size_t)(b*NPTS+i)*5];
      float x=qp[0], y=qp[1], z=qp[2], i1=qp[3], i2=qp[4];
      float acc = b1c;
      acc = fmaf(x, w1c[0], acc);
      acc = fmaf(y, w1c[1], acc);
      acc = fmaf(z, w1c[2], acc);
      acc = fmaf(i1, w1c[3], acc);
      acc = fmaf(i2, w1c[4], acc);
      acc = fmaf(x-mx, w1c[5], acc);
      acc = fmaf(y-my, w1c[6], acc);
      acc = fmaf(z-mz, w1c[7], acc);
      acc = fmaf(gx, w1c[8], acc);
      acc = fmaf(gy, w1c[9], acc);
      float zz = fmaxf(acc*sc1+sh1, 0.f);
      float t = b2c;
      #pragma unroll
      for (int c=0;c<32;c++){
        float zc = __int_as_float(__builtin_amdgcn_readlane(__float_as_int(zz), c));
        t = fmaf(zc, w2lo[c], t);
      }
      #pragma unroll
      for (int c=0;c<32;c++){
        float zc = __int_as_float(__builtin_amdgcn_readlane(__float_as_int(zz), c+32));
        t = fmaf(zc, w2hi[c], t);
      }
      tmax = fmaxf(tmax, t);
      tmin = fminf(tmin, t);
      s2 += t; q2 += t*t;
    }
    fmx[(size_t)(b*MAXP+p)*64 + lane] = tmax;
    fmn[(size_t)(b*MAXP+p)*64 + lane] = tmin;
    if (b){ s2_1 += s2; q2_1 += q2; } else { s2_0 += s2; q2_0 += q2; }
  }
  int rep = wglobal & 15;
  atomicAdd(&l2stat[((rep*2+0)*2+0)*64+lane], s2_0);
  atomicAdd(&l2stat[((rep*2+0)*2+1)*64+lane], q2_0);
  atomicAdd(&l2stat[((rep*2+1)*2+0)*64+lane], s2_1);
  atomicAdd(&l2stat[((rep*2+1)*2+1)*64+lane], q2_1);
}

__global__ void stats_fin2(const float* __restrict__ g2,const float* __restrict__ be2,
                           const float* __restrict__ l2stat, float* __restrict__ stats){
  int b = blockIdx.x, c = threadIdx.x;
  float* S = &stats[(size_t)b*512];
  float s = S[128+c], q = S[192+c];
  for (int r=0;r<16;r++){
    s += l2stat[((r*2+b)*2+0)*64+c];
    q += l2stat[((r*2+b)*2+1)*64+c];
  }
  const float N = (float)NROWS;
  float m = s/N;
  float v = fmaxf(q/N - m*m, 0.f);
  float sc = g2[c]*rsqrtf(v+1e-5f);
  S[384+c]=sc; S[448+c]=be2[c]-m*sc;
}

// BN2+relu applied to the pillar max (or min when sc2<0 — monotone transform), scattered to BEV
__global__ void scatter_bev(const float* __restrict__ fmx, const float* __restrict__ fmn,
                            const int* __restrict__ pcell, const int* __restrict__ misc,
                            const float* __restrict__ stats, float* __restrict__ bev){
  int tid = blockIdx.x*256+threadIdx.x;
  if (tid >= 2*64*MAXP) return;
  int c = tid & 63;
  int bp = tid >> 6;
  int b = bp / MAXP;
  int p = bp - b*MAXP;
  if (p >= misc[1+b]) return;
  float sc2 = stats[(size_t)b*512+384+c], sh2 = stats[(size_t)b*512+448+c];
  float t = (sc2 >= 0.f) ? fmx[tid] : fmn[tid];
  float v = fmaxf(sc2*t+sh2, 0.f);
  bev[(((size_t)(b*64+c))<<16) + pcell[b*MAXP+p]] = v;
}

// ---------------- conv stack ----------------
// 16x16 pixel tile, all 64 oc; 256 thr; per-thread 8px(x) x 8oc tile in two f32x32.
__global__ __launch_bounds__(256,2) void conv3x3(const float* __restrict__ in, float* __restrict__ out,
    const float* __restrict__ w, const float* __restrict__ bias,
    const float* __restrict__ bnsc, const float* __restrict__ bnsh){
  __shared__ __align__(16) float sIn[16][18][20];
  __shared__ __align__(16) float sW[16][9][64];
  const int tX = blockIdx.x*16, tY = blockIdx.y*16, b = blockIdx.z;
  const int t = threadIdx.x;
  const int ocg = t&7, pg = t>>3;
  const int py = pg>>1, x0 = (pg&1)*8, oc0 = ocg*8;
  f32x32 accA, accB;   // accA[k*8+j] k=0..3, accB[(k-4)*8+j] k=4..7; j=oc
  #pragma unroll
  for (int j=0;j<32;j++){ accA[j]=0.f; accB[j]=0.f; }

  for (int cc=0;cc<4;cc++){
    const int ic0 = cc*16;
    __syncthreads();
    for (int e=t;e<16*18*18;e+=256){
      int ic = e/324; int r = e-ic*324; int yy=r/18, xx=r-yy*18;
      int gy = tY+yy-1, gx = tX+xx-1;
      float v = 0.f;
      if ((unsigned)gy<256u && (unsigned)gx<256u){
        v = in[(((size_t)(b*64+ic0+ic))<<16) + (gy<<8) + gx];
        if (bnsc){ v = fmaxf(v*bnsc[ic0+ic]+bnsh[ic0+ic], 0.f); }
      }
      sIn[ic][yy][xx]=v;
    }
    for (int e=t;e<16*9*64;e+=256){
      int ic = e/576; int r = e-ic*576; int tap = r>>6; int oc = r&63;
      sW[ic][tap][oc] = w[((size_t)oc*64+(ic0+ic))*9 + tap];
    }
    __syncthreads();
    for (int ic=0;ic<16;ic++){
      #pragma unroll
      for (int dy=0;dy<3;dy++){
        const float* ip = &sIn[ic][py+dy][x0];
        float4 A0 = *(const float4*)ip;
        float4 A1 = *(const float4*)(ip+4);
        float4 A2 = *(const float4*)(ip+8);
        float v[12] = {A0.x,A0.y,A0.z,A0.w,A1.x,A1.y,A1.z,A1.w,A2.x,A2.y,A2.z,A2.w};
        #pragma unroll
        for (int dx=0;dx<3;dx++){
          const float4* wp = (const float4*)&sW[ic][dy*3+dx][oc0];
          float4 W0 = wp[0], W1 = wp[1];
          float wv[8] = {W0.x,W0.y,W0.z,W0.w,W1.x,W1.y,W1.z,W1.w};
          #pragma unroll
          for (int k=0;k<8;k++){
            float pv = v[dx+k];
            #pragma unroll
            for (int j=0;j<8;j++){
              if (k<4) accA[k*8+j]     = fmaf(pv, wv[j], accA[k*8+j]);
              else     accB[(k-4)*8+j] = fmaf(pv, wv[j], accB[(k-4)*8+j]);
            }
          }
        }
      }
    }
  }
  #pragma unroll
  for (int j=0;j<8;j++){
    float bj = bias[oc0+j];
    float* dst = &out[(((size_t)(b*64+oc0+j))<<16) + ((tY+py)<<8) + tX + x0];
    float4 o0 = make_float4(accA[0*8+j]+bj, accA[1*8+j]+bj, accA[2*8+j]+bj, accA[3*8+j]+bj);
    float4 o1 = make_float4(accB[0*8+j]+bj, accB[1*8+j]+bj, accB[2*8+j]+bj, accB[3*8+j]+bj);
    *(float4*)dst = o0; *(float4*)(dst+4) = o1;
  }
}

__global__ __launch_bounds__(256) void bn_stats(const float* __restrict__ x, float* __restrict__ bnst){
  int c = blockIdx.x, part = blockIdx.y;
  float s=0.f, q=0.f;
  for (int b=0;b<2;b++){
    const float4* p = (const float4*)&x[(((size_t)(b*64+c))<<16) + (size_t)part*8192];
    for (int k=threadIdx.x;k<2048;k+=256){
      float4 v = p[k];
      s += v.x+v.y+v.z+v.w;
      q += v.x*v.x+v.y*v.y+v.z*v.z+v.w*v.w;
    }
  }
  __shared__ float rs[256], rq[256];
  rs[threadIdx.x]=s; rq[threadIdx.x]=q; __syncthreads();
  for (int o=128;o>0;o>>=1){
    if (threadIdx.x<o){ rs[threadIdx.x]+=rs[threadIdx.x+o]; rq[threadIdx.x]+=rq[threadIdx.x+o]; }
    __syncthreads();
  }
  if (threadIdx.x==0){ atomicAdd(&bnst[c], rs[0]); atomicAdd(&bnst[64+c], rq[0]); }
}

__global__ void bn_fin(float* __restrict__ bnst, const float* __restrict__ g, const float* __restrict__ be){
  int c = threadIdx.x;
  const float n = 131072.f;
  float m = bnst[c]/n;
  float v = fmaxf(bnst[64+c]/n - m*m, 0.f);
  float sc = g[c]*rsqrtf(v+1e-5f);
  bnst[128+c]=sc; bnst[192+c]=be[c]-m*sc;
}

__global__ __launch_bounds__(256) void bn_apply(float* __restrict__ x, const float* __restrict__ bnst){
  size_t idx = (size_t)blockIdx.x*256 + threadIdx.x;
  size_t stride = (size_t)gridDim.x*256;
  float4* p = (float4*)x;
  for (size_t k=idx; k<2097152ULL; k+=stride){
    int c = (int)((k>>14)&63);
    float sc = bnst[128+c], sh = bnst[192+c];
    float4 v = p[k];
    v.x=fmaxf(v.x*sc+sh,0.f); v.y=fmaxf(v.y*sc+sh,0.f);
    v.z=fmaxf(v.z*sc+sh,0.f); v.w=fmaxf(v.w*sc+sh,0.f);
    p[k]=v;
  }
}

// ---------------- launch ----------------
extern "C" void kernel_launch(void* const* d_in, const int* in_sizes, int n_in,
                              void* d_out, int out_size, void* d_ws, size_t ws_size,
                              hipStream_t stream){
  const float* pts  = (const float*)d_in[0];
  const void*  mask = d_in[1];
  const float* w1 = (const float*)d_in[2];
  const float* b1 = (const float*)d_in[3];
  const float* g1 = (const float*)d_in[4];
  const float* be1= (const float*)d_in[5];
  const float* w2 = (const float*)d_in[6];
  const float* b2 = (const float*)d_in[7];
  const float* g2 = (const float*)d_in[8];
  const float* be2= (const float*)d_in[9];
  const float* cw[3]  = {(const float*)d_in[10],(const float*)d_in[14],(const float*)d_in[18]};
  const float* cb[3]  = {(const float*)d_in[11],(const float*)d_in[15],(const float*)d_in[19]};
  const float* cg[3]  = {(const float*)d_in[12],(const float*)d_in[16],(const float*)d_in[20]};
  const float* cbe[3] = {(const float*)d_in[13],(const float*)d_in[17],(const float*)d_in[21]};
  float* out = (float*)d_out;

  char* W = (char*)d_ws;
  size_t off = 0;
  auto A = [&](size_t n){ size_t r = off; off = (off + n + 255) & ~(size_t)255; return r; };
  float*    BIG   = (float*)   (W + A(33554432));
  int*      PID   = (int*)     (W + A((size_t)2*NPTS*4));
  int*      CCNT  = (int*)     (W + A((size_t)2*NCELL*4));
  int*      CRANK = (int*)     (W + A((size_t)2*NCELL*4));
  int*      CSTART= (int*)     (W + A((size_t)2*NCELL*4));
  int*      CTMP  = (int*)     (W + A((size_t)2*NCELL*4));
  int*      PLIST = (int*)     (W + A((size_t)2*NPTS*4));
  int*      PPTR  = (int*)     (W + A((size_t)2*NPTS*4));
  int*      PCELL = (int*)     (W + A((size_t)2*MAXP*4));
  float*    PSUM  = (float*)   (W + A((size_t)2*MAXP*16));
  float*    FMX   = (float*)   (W + A((size_t)2*MAXP*64*4));
  float*    FMN   = (float*)   (W + A((size_t)2*MAXP*64*4));
  float*    STATS = (float*)   (W + A((size_t)2*512*4));
  float*    LSTAT = (float*)   (W + A((size_t)16*2*2*64*4));
  float*    L2STAT= (float*)   (W + A((size_t)16*2*2*64*4));
  float*    BNST  = (float*)   (W + A((size_t)256*4));
  int*      HEAVY = (int*)     (W + A((size_t)(2+2*64)*4));
  int*      MISC  = (int*)     (W + A(256));

  hipMemsetAsync(BIG,  0, 33554432, stream);
  hipMemsetAsync(CCNT, 0, (size_t)2*NCELL*4, stream);
  hipMemsetAsync(CTMP, 0, (size_t)2*NCELL*4, stream);
  hipMemsetAsync(PPTR, 0xFF, (size_t)2*NPTS*4, stream);
  hipMemsetAsync(STATS,0, (size_t)2*512*4, stream);
  hipMemsetAsync(LSTAT,0, (size_t)16*2*2*64*4, stream);
  hipMemsetAsync(L2STAT,0,(size_t)16*2*2*64*4, stream);
  hipMemsetAsync(BNST, 0, (size_t)256*4, stream);
  hipMemsetAsync(HEAVY,0, (size_t)(2+2*64)*4, stream);
  hipMemsetAsync(MISC, 0, 256, stream);

  dim3 perPt((NPTS+255)/256, 2);

  probe_mask<<<1,256,0,stream>>>((const unsigned*)mask, MISC);
  compute_pid<<<perPt,256,0,stream>>>(pts, mask, MISC, PID, CCNT);
  scan_cells<<<2,1024,0,stream>>>(CCNT, CRANK, CSTART, PCELL, MISC, HEAVY);
  scatter_points<<<perPt,256,0,stream>>>(PID, CCNT, CRANK, CSTART, CTMP, PLIST, PPTR);
  heavy_select<<<dim3(64,2),64,0,stream>>>(CCNT, CRANK, CSTART, PLIST, HEAVY, PPTR);
  l1_stats<<<512,256,0,stream>>>(pts, PLIST, PCELL, CSTART, CCNT, PPTR, PSUM, MISC, w1, b1, LSTAT);
  stats_fin1<<<2,64,0,stream>>>(w1, b1, g1, be1, w2, b2, LSTAT, STATS, MISC);
  pillar_mlp<<<512,256,0,stream>>>(pts, PLIST, PCELL, CSTART, CCNT, PPTR, PSUM, MISC,
                                   w1, b1, w2, b2, STATS, L2STAT, FMX, FMN);
  stats_fin2<<<2,64,0,stream>>>(g2, be2, L2STAT, STATS);
  scatter_bev<<<(2*64*MAXP+255)/256,256,0,stream>>>(FMX, FMN, PCELL, MISC, STATS, BIG);

  // conv1: BIG(bev) -> d_out (raw + bias)
  conv3x3<<<dim3(16,16,2),256,0,stream>>>(BIG, out, cw[0], cb[0], nullptr, nullptr);
  bn_stats<<<dim3(64,8),256,0,stream>>>(out, BNST);
  bn_fin<<<1,64,0,stream>>>(BNST, cg[0], cbe[0]);
  // conv2: d_out (bn1+relu on stage) -> BIG
  conv3x3<<<dim3(16,16,2),256,0,stream>>>(out, BIG, cw[1], cb[1], BNST+128, BNST+192);
  hipMemsetAsync(BNST, 0, 512, stream);
  bn_stats<<<dim3(64,8),256,0,stream>>>(BIG, BNST);
  bn_fin<<<1,64,0,stream>>>(BNST, cg[1], cbe[1]);
  // conv3: BIG (bn2+relu on stage) -> d_out
  conv3x3<<<dim3(16,16,2),256,0,stream>>>(BIG, out, cw[2], cb[2], BNST+128, BNST+192);
  hipMemsetAsync(BNST, 0, 512, stream);
  bn_stats<<<dim3(64,8),256,0,stream>>>(out, BNST);
  bn_fin<<<1,64,0,stream>>>(BNST, cg[2], cbe[2]);
  bn_apply<<<2048,256,0,stream>>>(out, BNST);
}

// Round 4
// 431.097 us; speedup vs baseline: 2.9104x; 1.8274x over previous
//
#include <hip/hip_runtime.h>

#define NPTS 60000
#define NXG 256
#define NCELL 65536
#define MAXP 12000
#define MAXPP 32
#define NROWS (MAXP*MAXPP)

typedef float f32x32 __attribute__((ext_vector_type(32)));
typedef float f32x4  __attribute__((ext_vector_type(4)));
typedef short s16x8  __attribute__((ext_vector_type(8)));

__device__ __forceinline__ short to_bf16(float f){
  unsigned u = __float_as_uint(f);
  unsigned r = (u + 0x7FFFu + ((u>>16)&1u)) >> 16;
  return (short)r;
}

// ---------------- mask dtype probe ----------------
__global__ void probe_mask(const unsigned* __restrict__ m, int* __restrict__ misc){
  __shared__ int cf32, cbig;
  if (threadIdx.x==0){ cf32=0; cbig=0; }
  __syncthreads();
  int lf=0, lb=0;
  for (int k=0;k<4;k++){
    unsigned x = m[threadIdx.x*4+k];
    if (x==0x3f800000u) lf++;
    else if (x>1u) lb++;
  }
  atomicAdd(&cf32, lf); atomicAdd(&cbig, lb);
  __syncthreads();
  if (threadIdx.x==0){
    int mode=0;
    if (cf32>64) mode=2; else if (cbig>0) mode=1;
    misc[0]=mode;
  }
}

// ---------------- pillarize ----------------
__global__ void compute_pid(const float* __restrict__ pts, const void* __restrict__ maskp,
                            const int* __restrict__ misc, int* __restrict__ pid,
                            int* __restrict__ ccnt){
  int i = blockIdx.x*blockDim.x + threadIdx.x;
  if (i>=NPTS) return;
  int b = blockIdx.y;
  int gi = b*NPTS+i;
  int mode = misc[0];
  bool m;
  if (mode==0)      m = ((const int*)maskp)[gi]!=0;
  else if (mode==1) m = ((const unsigned char*)maskp)[gi]!=0;
  else              m = ((const float*)maskp)[gi]!=0.f;
  int cell = -1;
  if (m){
    float x = pts[(size_t)gi*5+0], y = pts[(size_t)gi*5+1];
    int ix = (int)((x - (-32.0f)) / 0.25f);
    ix = ix<0?0:(ix>255?255:ix);
    int iy = (int)((y - (-32.0f)) / 0.25f);
    iy = iy<0?0:(iy>255?255:iy);
    cell = iy*NXG + ix;
    atomicAdd(&ccnt[b*NCELL+cell], 1);
  }
  pid[gi] = cell;
}

__global__ __launch_bounds__(1024) void scan_cells(const int* __restrict__ ccnt,
    int* __restrict__ crank, int* __restrict__ cstart, int* __restrict__ pcell,
    int* __restrict__ misc, int* __restrict__ heavy){
  __shared__ int so_[1024], sc_[1024];
  int b = blockIdx.x, t = threadIdx.x;
  const int base = b*NCELL;
  const int cbeg = t*64;
  int occ=0, cnt=0;
  for (int j=0;j<64;j++){ int v=ccnt[base+cbeg+j]; occ += (v>0); cnt += v; }
  so_[t]=occ; sc_[t]=cnt; __syncthreads();
  for (int off=1; off<1024; off<<=1){
    int vo=0, vc=0;
    if (t>=off){ vo=so_[t-off]; vc=sc_[t-off]; }
    __syncthreads();
    if (t>=off){ so_[t]+=vo; sc_[t]+=vc; }
    __syncthreads();
  }
  int eo = so_[t]-occ, ec = sc_[t]-cnt;
  if (t==1023) misc[1+b] = (so_[1023] < MAXP) ? so_[1023] : MAXP; // npil
  int kept=0;
  for (int j=0;j<64;j++){
    int c = cbeg+j; int v = ccnt[base+c];
    if (v>0){
      crank[base+c]=eo; cstart[base+c]=ec;
      if (eo<MAXP){
        pcell[b*MAXP+eo]=c;
        kept += (v<MAXPP)? v : MAXPP;
        if (v>MAXPP){
          int hi = atomicAdd(&heavy[b],1);
          if (hi<64) heavy[2 + b*64 + hi] = c;
        }
      }
      eo++; ec+=v;
    } else {
      crank[base+c]=-1;
    }
  }
  atomicAdd(&misc[3+b], kept); // nk
}

__global__ void scatter_points(const int* __restrict__ pid, const int* __restrict__ ccnt,
    const int* __restrict__ crank, const int* __restrict__ cstart,
    int* __restrict__ ctmp, int* __restrict__ plist, int* __restrict__ pptr){
  int i = blockIdx.x*blockDim.x + threadIdx.x;
  if (i>=NPTS) return;
  int b = blockIdx.y;
  int gi = b*NPTS+i;
  int cell = pid[gi];
  if (cell<0) return;
  int bc = b*NCELL+cell;
  int pos = cstart[bc] + atomicAdd(&ctmp[bc],1);
  plist[b*NPTS+pos] = i;
  int r = crank[bc];
  if (r>=0 && r<MAXP && ccnt[bc]<=MAXPP) pptr[gi] = r;
}

__global__ void heavy_select(const int* __restrict__ ccnt, const int* __restrict__ crank,
    const int* __restrict__ cstart, const int* __restrict__ plist,
    const int* __restrict__ heavy, int* __restrict__ pptr){
  int b = blockIdx.y;
  int hn = heavy[b]; if (hn>64) hn=64;
  if ((int)blockIdx.x >= hn) return;
  int cell = heavy[2 + b*64 + blockIdx.x];
  int bc = b*NCELL+cell;
  int cnt = ccnt[bc], start = cstart[bc], pr = crank[bc];
  for (int e=threadIdx.x; e<cnt; e+=blockDim.x){
    int pe = plist[b*NPTS+start+e];
    int rank=0;
    for (int k=0;k<cnt;k++) rank += (plist[b*NPTS+start+k] < pe);
    if (rank<MAXPP) pptr[b*NPTS+pe] = pr;
  }
}

// ---------------- layer-1 BN stats (pillar-centric, lane=channel) ----------------
__global__ __launch_bounds__(256) void l1_stats(const float* __restrict__ pts,
    const int* __restrict__ plist, const int* __restrict__ pcell,
    const int* __restrict__ cstart, const int* __restrict__ ccnt,
    const int* __restrict__ pptr, float* __restrict__ psum,
    const int* __restrict__ misc,
    const float* __restrict__ w1, const float* __restrict__ b1,
    float* __restrict__ lstat){
  const int lane = threadIdx.x & 63;
  float w1c[10];
  #pragma unroll
  for (int d=0;d<10;d++) w1c[d]=w1[d*64+lane];
  const float b1c = b1[lane];
  const int npil0 = misc[1], npil1 = misc[2];
  float s0=0.f,q0=0.f,s1=0.f,q1=0.f;
  const int wglobal = (blockIdx.x*256+threadIdx.x)>>6;
  const int nwaves = (gridDim.x*256)>>6;
  for (int qq=wglobal; qq<2*MAXP; qq+=nwaves){
    int b = (qq>=MAXP)?1:0;
    int p = qq-b*MAXP;
    if (p >= (b?npil1:npil0)) continue;
    int cell = pcell[b*MAXP+p];
    int bc = b*NCELL+cell;
    int cnt = ccnt[bc], start = cstart[bc];
    bool heavy = cnt>MAXPP;
    float sx=0.f,sy=0.f,sz=0.f,n=0.f;
    for (int k=0;k<cnt;k++){
      int i = plist[b*NPTS+start+k];
      if (heavy && pptr[b*NPTS+i]!=p) continue;
      const float* qp = &pts[(size_t)(b*NPTS+i)*5];
      sx+=qp[0]; sy+=qp[1]; sz+=qp[2]; n+=1.f;
    }
    float inv = 1.f/fmaxf(n,1.f);
    float mx=sx*inv, my=sy*inv, mz=sz*inv;
    if (lane==0){
      *(float4*)&psum[(size_t)(b*MAXP+p)*4] = make_float4(mx,my,mz,n);
    }
    float gx = -32.0f+((float)(cell&255)+0.5f)*0.25f;
    float gy = -32.0f+((float)(cell>>8)+0.5f)*0.25f;
    float s=0.f,q=0.f;
    for (int k=0;k<cnt;k++){
      int i = plist[b*NPTS+start+k];
      if (heavy && pptr[b*NPTS+i]!=p) continue;
      const float* qp = &pts[(size_t)(b*NPTS+i)*5];
      float x=qp[0], y=qp[1], z=qp[2], i1=qp[3], i2=qp[4];
      float acc=b1c;
      acc=fmaf(x,w1c[0],acc);  acc=fmaf(y,w1c[1],acc);  acc=fmaf(z,w1c[2],acc);
      acc=fmaf(i1,w1c[3],acc); acc=fmaf(i2,w1c[4],acc);
      acc=fmaf(x-mx,w1c[5],acc); acc=fmaf(y-my,w1c[6],acc); acc=fmaf(z-mz,w1c[7],acc);
      acc=fmaf(gx,w1c[8],acc);   acc=fmaf(gy,w1c[9],acc);
      s+=acc; q+=acc*acc;
    }
    if (b){ s1+=s; q1+=q; } else { s0+=s; q0+=q; }
  }
  int rep = wglobal & 15;
  atomicAdd(&lstat[((rep*2+0)*2+0)*64+lane], s0);
  atomicAdd(&lstat[((rep*2+0)*2+1)*64+lane], q0);
  atomicAdd(&lstat[((rep*2+1)*2+0)*64+lane], s1);
  atomicAdd(&lstat[((rep*2+1)*2+1)*64+lane], q1);
}

__global__ void stats_fin1(const float* __restrict__ w1, const float* __restrict__ b1,
    const float* __restrict__ g1, const float* __restrict__ be1,
    const float* __restrict__ w2, const float* __restrict__ b2,
    const float* __restrict__ lstat, float* __restrict__ stats,
    const int* __restrict__ misc){
  __shared__ float z0s[64];
  int b = blockIdx.x, c = threadIdx.x;
  float* S = &stats[(size_t)b*512];
  float s=0.f, q=0.f;
  for (int r=0;r<16;r++){
    s += lstat[((r*2+b)*2+0)*64+c];
    q += lstat[((r*2+b)*2+1)*64+c];
  }
  float b1c = b1[c];
  float nk = (float)misc[3+b];
  const float N = (float)NROWS;
  float pad = N - nk;
  float St = s + pad*b1c;
  float Qt = q + pad*b1c*b1c;
  float mu = St/N;
  float var = fmaxf(Qt/N - mu*mu, 0.f);
  float sc = g1[c]*rsqrtf(var+1e-5f);
  float sh = be1[c]-mu*sc;
  S[256+c]=sc; S[320+c]=sh;
  float z0 = fmaxf(b1c*sc+sh, 0.f);
  z0s[c]=z0;
  __syncthreads();
  float t0 = b2[c];
  for (int i2=0;i2<64;i2++) t0 += z0s[i2]*w2[(size_t)i2*64+c];
  S[128+c]=pad*t0; S[192+c]=pad*t0*t0;
}

// ---------------- pillar-centric MLP + in-register max/min ----------------
__global__ __launch_bounds__(256) void pillar_mlp(const float* __restrict__ pts,
    const int* __restrict__ plist, const int* __restrict__ pcell,
    const int* __restrict__ cstart, const int* __restrict__ ccnt,
    const int* __restrict__ pptr, const float* __restrict__ psum,
    const int* __restrict__ misc,
    const float* __restrict__ w1, const float* __restrict__ b1,
    const float* __restrict__ w2, const float* __restrict__ b2,
    const float* __restrict__ stats, float* __restrict__ l2stat,
    float* __restrict__ fmx, float* __restrict__ fmn){
  const int lane = threadIdx.x & 63;
  float w1c[10];
  #pragma unroll
  for (int d=0;d<10;d++) w1c[d] = w1[d*64+lane];
  f32x32 w2lo, w2hi;
  #pragma unroll
  for (int c=0;c<32;c++) w2lo[c] = w2[(size_t)c*64+lane];
  #pragma unroll
  for (int c=0;c<32;c++) w2hi[c] = w2[(size_t)(c+32)*64+lane];
  const float b1c = b1[lane], b2c = b2[lane];
  const float sc1_0 = stats[256+lane], sh1_0 = stats[320+lane];
  const float sc1_1 = stats[512+256+lane], sh1_1 = stats[512+320+lane];
  const int npil0 = misc[1], npil1 = misc[2];
  float s2_0=0.f, q2_0=0.f, s2_1=0.f, q2_1=0.f;

  const int wglobal = (blockIdx.x*256 + threadIdx.x) >> 6;
  const int nwaves = (gridDim.x*256) >> 6;
  for (int qq = wglobal; qq < 2*MAXP; qq += nwaves){
    int b = (qq >= MAXP) ? 1 : 0;
    int p = qq - b*MAXP;
    int npil = b ? npil1 : npil0;
    if (p >= npil) continue;
    int cell = pcell[b*MAXP+p];
    int bc = b*NCELL+cell;
    int cnt = ccnt[bc], start = cstart[bc];
    bool heavy = cnt > MAXPP;
    float gx = -32.0f + ((float)(cell&255)+0.5f)*0.25f;
    float gy = -32.0f + ((float)(cell>>8)+0.5f)*0.25f;
    const float* mc = &psum[(size_t)(b*MAXP+p)*4];
    float mx = mc[0], my = mc[1], mz = mc[2];
    float sc1 = b ? sc1_1 : sc1_0;
    float sh1 = b ? sh1_1 : sh1_0;
    float tmax = -1e30f, tmin = 1e30f;
    float s2 = 0.f, q2 = 0.f;
    for (int k=0; k<cnt; k++){
      int i = plist[b*NPTS+start+k];
      if (heavy && pptr[b*NPTS+i] != p) continue;
      const float* qp = &pts[(size_t)(b*NPTS+i)*5];
      float x=qp[0], y=qp[1], z=qp[2], i1=qp[3], i2=qp[4];
      float acc = b1c;
      acc = fmaf(x, w1c[0], acc);
      acc = fmaf(y, w1c[1], acc);
      acc = fmaf(z, w1c[2], acc);
      acc = fmaf(i1, w1c[3], acc);
      acc = fmaf(i2, w1c[4], acc);
      acc = fmaf(x-mx, w1c[5], acc);
      acc = fmaf(y-my, w1c[6], acc);
      acc = fmaf(z-mz, w1c[7], acc);
      acc = fmaf(gx, w1c[8], acc);
      acc = fmaf(gy, w1c[9], acc);
      float zz = fmaxf(acc*sc1+sh1, 0.f);
      float t = b2c;
      #pragma unroll
      for (int c=0;c<32;c++){
        float zc = __int_as_float(__builtin_amdgcn_readlane(__float_as_int(zz), c));
        t = fmaf(zc, w2lo[c], t);
      }
      #pragma unroll
      for (int c=0;c<32;c++){
        float zc = __int_as_float(__builtin_amdgcn_readlane(__float_as_int(zz), c+32));
        t = fmaf(zc, w2hi[c], t);
      }
      tmax = fmaxf(tmax, t);
      tmin = fminf(tmin, t);
      s2 += t; q2 += t*t;
    }
    fmx[(size_t)(b*MAXP+p)*64 + lane] = tmax;
    fmn[(size_t)(b*MAXP+p)*64 + lane] = tmin;
    if (b){ s2_1 += s2; q2_1 += q2; } else { s2_0 += s2; q2_0 += q2; }
  }
  int rep = wglobal & 15;
  atomicAdd(&l2stat[((rep*2+0)*2+0)*64+lane], s2_0);
  atomicAdd(&l2stat[((rep*2+0)*2+1)*64+lane], q2_0);
  atomicAdd(&l2stat[((rep*2+1)*2+0)*64+lane], s2_1);
  atomicAdd(&l2stat[((rep*2+1)*2+1)*64+lane], q2_1);
}

__global__ void stats_fin2(const float* __restrict__ g2,const float* __restrict__ be2,
                           const float* __restrict__ l2stat, float* __restrict__ stats){
  int b = blockIdx.x, c = threadIdx.x;
  float* S = &stats[(size_t)b*512];
  float s = S[128+c], q = S[192+c];
  for (int r=0;r<16;r++){
    s += l2stat[((r*2+b)*2+0)*64+c];
    q += l2stat[((r*2+b)*2+1)*64+c];
  }
  const float N = (float)NROWS;
  float m = s/N;
  float v = fmaxf(q/N - m*m, 0.f);
  float sc = g2[c]*rsqrtf(v+1e-5f);
  S[384+c]=sc; S[448+c]=be2[c]-m*sc;
}

// BN2+relu on pillar max/min, scatter to bf16 pixel-major BEV [y][x][ch]
__global__ void scatter_bev(const float* __restrict__ fmx, const float* __restrict__ fmn,
                            const int* __restrict__ pcell, const int* __restrict__ misc,
                            const float* __restrict__ stats, short* __restrict__ bevh){
  int tid = blockIdx.x*256+threadIdx.x;
  if (tid >= 2*64*MAXP) return;
  int c = tid & 63;
  int bp = tid >> 6;
  int b = bp / MAXP;
  int p = bp - b*MAXP;
  if (p >= misc[1+b]) return;
  float sc2 = stats[(size_t)b*512+384+c], sh2 = stats[(size_t)b*512+448+c];
  float t = (sc2 >= 0.f) ? fmx[tid] : fmn[tid];
  float v = fmaxf(sc2*t+sh2, 0.f);
  int cell = pcell[b*MAXP+p];
  bevh[((size_t)((b<<16) + cell))*64 + c] = to_bf16(v);
}

// ---------------- weights fp32 [oc][ic][tap] -> bf16 [tap][oc][ic] ----------------
__global__ void wcvt(const float* __restrict__ w, short* __restrict__ wh){
  int t = blockIdx.x*256 + threadIdx.x;
  if (t >= 36864) return;
  int ic = t & 63, oc = (t>>6)&63, tap = t>>12;
  wh[t] = to_bf16(w[(oc*64+ic)*9 + tap]);
}

// ---------------- BN+relu + fp32->bf16 px-major transpose ----------------
// in fp32 [b*64+ch][y][x] -> out bf16 [(b,y,x)][ch]
__global__ __launch_bounds__(256) void cvt_px(const float* __restrict__ in,
    const float* __restrict__ bnst, short* __restrict__ outh){
  __shared__ short sT[64*66];
  const int x0 = blockIdx.x*64, y = blockIdx.y, b = blockIdx.z;
  const int t = threadIdx.x;
  for (int e=t; e<4096; e+=256){
    int ch = e>>6, px = e&63;
    float v = in[(((size_t)(b*64+ch))<<16) + (y<<8) + x0 + px];
    v = fmaxf(v*bnst[128+ch]+bnst[192+ch], 0.f);
    sT[px*66+ch] = to_bf16(v);
  }
  __syncthreads();
  for (int e=t; e<2048; e+=256){
    int px = e>>5, c2 = (e&31)*2;
    *(unsigned*)&outh[(((size_t)(b<<16)) + (y<<8) + x0 + px)*64 + c2] =
        *(const unsigned*)&sT[px*66+c2];
  }
}

// ---------------- MFMA conv3x3: bf16 px-major in, fp32 [oc][y][x] out ----------------
#define MFMA16(A,B,C) __builtin_amdgcn_mfma_f32_16x16x32_bf16(A,B,C,0,0,0)

__global__ __launch_bounds__(256,2) void conv_mfma(const short* __restrict__ xh,
    const short* __restrict__ wh, const float* __restrict__ bias,
    float* __restrict__ out){
  __shared__ short sX[18*18*40];   // [yy][xx][ic32 pad40]
  __shared__ short sW[576*40];     // [tap*64+oc][ic32 pad40]
  const int tX = blockIdx.x*16, tY = blockIdx.y*16, b = blockIdx.z;
  const int t = threadIdx.x;
  const int lane = t & 63, wv = t >> 6;
  const int colx = lane & 15;
  const int kb = (lane >> 4) * 8;

  f32x4 a00={0.f,0.f,0.f,0.f}, a01=a00, a02=a00, a03=a00;
  f32x4 a10=a00, a11=a00, a12=a00, a13=a00;
  f32x4 a20=a00, a21=a00, a22=a00, a23=a00;
  f32x4 a30=a00, a31=a00, a32=a00, a33=a00;

  for (int h=0; h<2; ++h){
    __syncthreads();
    for (int e=t; e<1296; e+=256){
      int px = e>>2, j = e&3;
      int yy = px/18, xx = px - yy*18;
      int gy = tY+yy-1, gx = tX+xx-1;
      uint4 v = make_uint4(0,0,0,0);
      if ((unsigned)gy<256u && (unsigned)gx<256u)
        v = *(const uint4*)&xh[((size_t)((b<<16) + (gy<<8) + gx))*64 + h*32 + j*8];
      *(uint4*)&sX[px*40 + j*8] = v;
    }
    for (int e=t; e<2304; e+=256){
      int row = e>>2, j = e&3;
      uint4 v = *(const uint4*)&wh[(size_t)row*64 + h*32 + j*8];
      *(uint4*)&sW[row*40 + j*8] = v;
    }
    __syncthreads();
    #pragma unroll
    for (int tap=0; tap<9; ++tap){
      const int dy = tap/3, dx = tap - dy*3;
      s16x8 wA = *(const s16x8*)&sW[(tap*64 +  0 + colx)*40 + kb];
      s16x8 wB = *(const s16x8*)&sW[(tap*64 + 16 + colx)*40 + kb];
      s16x8 wC = *(const s16x8*)&sW[(tap*64 + 32 + colx)*40 + kb];
      s16x8 wD = *(const s16x8*)&sW[(tap*64 + 48 + colx)*40 + kb];
      s16x8 x0 = *(const s16x8*)&sX[((wv*4+0+dy)*18 + colx+dx)*40 + kb];
      s16x8 x1 = *(const s16x8*)&sX[((wv*4+1+dy)*18 + colx+dx)*40 + kb];
      s16x8 x2 = *(const s16x8*)&sX[((wv*4+2+dy)*18 + colx+dx)*40 + kb];
      s16x8 x3 = *(const s16x8*)&sX[((wv*4+3+dy)*18 + colx+dx)*40 + kb];
      a00 = MFMA16(wA,x0,a00); a01 = MFMA16(wA,x1,a01);
      a02 = MFMA16(wA,x2,a02); a03 = MFMA16(wA,x3,a03);
      a10 = MFMA16(wB,x0,a10); a11 = MFMA16(wB,x1,a11);
      a12 = MFMA16(wB,x2,a12); a13 = MFMA16(wB,x3,a13);
      a20 = MFMA16(wC,x0,a20); a21 = MFMA16(wC,x1,a21);
      a22 = MFMA16(wC,x2,a22); a23 = MFMA16(wC,x3,a23);
      a30 = MFMA16(wD,x0,a30); a31 = MFMA16(wD,x1,a31);
      a32 = MFMA16(wD,x2,a32); a33 = MFMA16(wD,x3,a33);
    }
  }
  const int ocl = (lane>>4)*4;
  #define EPI(G,R,ACC) { \
    const int y = tY + wv*4 + R; \
    _Pragma("unroll") \
    for (int m=0;m<4;m++){ \
      int oc = G*16 + ocl + m; \
      out[(((size_t)(b*64+oc))<<16) + (y<<8) + tX + colx] = ACC[m] + bias[oc]; \
    } }
  EPI(0,0,a00) EPI(0,1,a01) EPI(0,2,a02) EPI(0,3,a03)
  EPI(1,0,a10) EPI(1,1,a11) EPI(1,2,a12) EPI(1,3,a13)
  EPI(2,0,a20) EPI(2,1,a21) EPI(2,2,a22) EPI(2,3,a23)
  EPI(3,0,a30) EPI(3,1,a31) EPI(3,2,a32) EPI(3,3,a33)
  #undef EPI
}

__global__ __launch_bounds__(256) void bn_stats(const float* __restrict__ x, float* __restrict__ bnst){
  int c = blockIdx.x, part = blockIdx.y;
  float s=0.f, q=0.f;
  for (int b=0;b<2;b++){
    const float4* p = (const float4*)&x[(((size_t)(b*64+c))<<16) + (size_t)part*8192];
    for (int k=threadIdx.x;k<2048;k+=256){
      float4 v = p[k];
      s += v.x+v.y+v.z+v.w;
      q += v.x*v.x+v.y*v.y+v.z*v.z+v.w*v.w;
    }
  }
  __shared__ float rs[256], rq[256];
  rs[threadIdx.x]=s; rq[threadIdx.x]=q; __syncthreads();
  for (int o=128;o>0;o>>=1){
    if (threadIdx.x<o){ rs[threadIdx.x]+=rs[threadIdx.x+o]; rq[threadIdx.x]+=rq[threadIdx.x+o]; }
    __syncthreads();
  }
  if (threadIdx.x==0){ atomicAdd(&bnst[c], rs[0]); atomicAdd(&bnst[64+c], rq[0]); }
}

__global__ void bn_fin(float* __restrict__ bnst, const float* __restrict__ g, const float* __restrict__ be){
  int c = threadIdx.x;
  const float n = 131072.f;
  float m = bnst[c]/n;
  float v = fmaxf(bnst[64+c]/n - m*m, 0.f);
  float sc = g[c]*rsqrtf(v+1e-5f);
  bnst[128+c]=sc; bnst[192+c]=be[c]-m*sc;
}

__global__ __launch_bounds__(256) void bn_apply(float* __restrict__ x, const float* __restrict__ bnst){
  size_t idx = (size_t)blockIdx.x*256 + threadIdx.x;
  size_t stride = (size_t)gridDim.x*256;
  float4* p = (float4*)x;
  for (size_t k=idx; k<2097152ULL; k+=stride){
    int c = (int)((k>>14)&63);
    float sc = bnst[128+c], sh = bnst[192+c];
    float4 v = p[k];
    v.x=fmaxf(v.x*sc+sh,0.f); v.y=fmaxf(v.y*sc+sh,0.f);
    v.z=fmaxf(v.z*sc+sh,0.f); v.w=fmaxf(v.w*sc+sh,0.f);
    p[k]=v;
  }
}

// ---------------- launch ----------------
extern "C" void kernel_launch(void* const* d_in, const int* in_sizes, int n_in,
                              void* d_out, int out_size, void* d_ws, size_t ws_size,
                              hipStream_t stream){
  const float* pts  = (const float*)d_in[0];
  const void*  mask = d_in[1];
  const float* w1 = (const float*)d_in[2];
  const float* b1 = (const float*)d_in[3];
  const float* g1 = (const float*)d_in[4];
  const float* be1= (const float*)d_in[5];
  const float* w2 = (const float*)d_in[6];
  const float* b2 = (const float*)d_in[7];
  const float* g2 = (const float*)d_in[8];
  const float* be2= (const float*)d_in[9];
  const float* cw[3]  = {(const float*)d_in[10],(const float*)d_in[14],(const float*)d_in[18]};
  const float* cb[3]  = {(const float*)d_in[11],(const float*)d_in[15],(const float*)d_in[19]};
  const float* cg[3]  = {(const float*)d_in[12],(const float*)d_in[16],(const float*)d_in[20]};
  const float* cbe[3] = {(const float*)d_in[13],(const float*)d_in[17],(const float*)d_in[21]};
  float* out = (float*)d_out;

  char* W = (char*)d_ws;
  size_t off = 0;
  auto A = [&](size_t n){ size_t r = off; off = (off + n + 255) & ~(size_t)255; return r; };
  short*    BIGH  = (short*)   (W + A((size_t)2*NCELL*64*2));
  int*      PID   = (int*)     (W + A((size_t)2*NPTS*4));
  int*      CCNT  = (int*)     (W + A((size_t)2*NCELL*4));
  int*      CRANK = (int*)     (W + A((size_t)2*NCELL*4));
  int*      CSTART= (int*)     (W + A((size_t)2*NCELL*4));
  int*      CTMP  = (int*)     (W + A((size_t)2*NCELL*4));
  int*      PLIST = (int*)     (W + A((size_t)2*NPTS*4));
  int*      PPTR  = (int*)     (W + A((size_t)2*NPTS*4));
  int*      PCELL = (int*)     (W + A((size_t)2*MAXP*4));
  float*    PSUM  = (float*)   (W + A((size_t)2*MAXP*16));
  float*    FMX   = (float*)   (W + A((size_t)2*MAXP*64*4));
  float*    FMN   = (float*)   (W + A((size_t)2*MAXP*64*4));
  float*    STATS = (float*)   (W + A((size_t)2*512*4));
  float*    LSTAT = (float*)   (W + A((size_t)16*2*2*64*4));
  float*    L2STAT= (float*)   (W + A((size_t)16*2*2*64*4));
  float*    BNST  = (float*)   (W + A((size_t)256*4));
  short*    WH0   = (short*)   (W + A((size_t)36864*2));
  short*    WH1   = (short*)   (W + A((size_t)36864*2));
  short*    WH2   = (short*)   (W + A((size_t)36864*2));
  int*      HEAVY = (int*)     (W + A((size_t)(2+2*64)*4));
  int*      MISC  = (int*)     (W + A(256));

  hipMemsetAsync(BIGH, 0, (size_t)2*NCELL*64*2, stream);
  hipMemsetAsync(CCNT, 0, (size_t)2*NCELL*4, stream);
  hipMemsetAsync(CTMP, 0, (size_t)2*NCELL*4, stream);
  hipMemsetAsync(PPTR, 0xFF, (size_t)2*NPTS*4, stream);
  hipMemsetAsync(STATS,0, (size_t)2*512*4, stream);
  hipMemsetAsync(LSTAT,0, (size_t)16*2*2*64*4, stream);
  hipMemsetAsync(L2STAT,0,(size_t)16*2*2*64*4, stream);
  hipMemsetAsync(BNST, 0, (size_t)256*4, stream);
  hipMemsetAsync(HEAVY,0, (size_t)(2+2*64)*4, stream);
  hipMemsetAsync(MISC, 0, 256, stream);

  dim3 perPt((NPTS+255)/256, 2);

  probe_mask<<<1,256,0,stream>>>((const unsigned*)mask, MISC);
  compute_pid<<<perPt,256,0,stream>>>(pts, mask, MISC, PID, CCNT);
  wcvt<<<144,256,0,stream>>>(cw[0], WH0);
  wcvt<<<144,256,0,stream>>>(cw[1], WH1);
  wcvt<<<144,256,0,stream>>>(cw[2], WH2);
  scan_cells<<<2,1024,0,stream>>>(CCNT, CRANK, CSTART, PCELL, MISC, HEAVY);
  scatter_points<<<perPt,256,0,stream>>>(PID, CCNT, CRANK, CSTART, CTMP, PLIST, PPTR);
  heavy_select<<<dim3(64,2),64,0,stream>>>(CCNT, CRANK, CSTART, PLIST, HEAVY, PPTR);
  l1_stats<<<512,256,0,stream>>>(pts, PLIST, PCELL, CSTART, CCNT, PPTR, PSUM, MISC, w1, b1, LSTAT);
  stats_fin1<<<2,64,0,stream>>>(w1, b1, g1, be1, w2, b2, LSTAT, STATS, MISC);
  pillar_mlp<<<512,256,0,stream>>>(pts, PLIST, PCELL, CSTART, CCNT, PPTR, PSUM, MISC,
                                   w1, b1, w2, b2, STATS, L2STAT, FMX, FMN);
  stats_fin2<<<2,64,0,stream>>>(g2, be2, L2STAT, STATS);
  scatter_bev<<<(2*64*MAXP+255)/256,256,0,stream>>>(FMX, FMN, PCELL, MISC, STATS, BIGH);

  // conv1: BIGH -> d_out
  conv_mfma<<<dim3(16,16,2),256,0,stream>>>(BIGH, WH0, cb[0], out);
  bn_stats<<<dim3(64,8),256,0,stream>>>(out, BNST);
  bn_fin<<<1,64,0,stream>>>(BNST, cg[0], cbe[0]);
  // bn1+relu -> BIGH ; conv2: BIGH -> d_out
  cvt_px<<<dim3(4,256,2),256,0,stream>>>(out, BNST, BIGH);
  hipMemsetAsync(BNST, 0, 512, stream);
  conv_mfma<<<dim3(16,16,2),256,0,stream>>>(BIGH, WH1, cb[1], out);
  bn_stats<<<dim3(64,8),256,0,stream>>>(out, BNST);
  bn_fin<<<1,64,0,stream>>>(BNST, cg[1], cbe[1]);
  // bn2+relu -> BIGH ; conv3: BIGH -> d_out
  cvt_px<<<dim3(4,256,2),256,0,stream>>>(out, BNST, BIGH);
  hipMemsetAsync(BNST, 0, 512, stream);
  conv_mfma<<<dim3(16,16,2),256,0,stream>>>(BIGH, WH2, cb[2], out);
  bn_stats<<<dim3(64,8),256,0,stream>>>(out, BNST);
  bn_fin<<<1,64,0,stream>>>(BNST, cg[2], cbe[2]);
  bn_apply<<<2048,256,0,stream>>>(out, BNST);
}

// Round 5
// 318.336 us; speedup vs baseline: 3.9413x; 1.3542x over previous
//
#include <hip/hip_runtime.h>

#define NPTS 60000
#define NXG 256
#define NCELL 65536
#define MAXP 12000
#define MAXPP 32
#define NROWS (MAXP*MAXPP)

typedef float f32x32 __attribute__((ext_vector_type(32)));
typedef float f32x4  __attribute__((ext_vector_type(4)));
typedef short s16x8  __attribute__((ext_vector_type(8)));

__device__ __forceinline__ short to_bf16(float f){
  unsigned u = __float_as_uint(f);
  unsigned r = (u + 0x7FFFu + ((u>>16)&1u)) >> 16;
  return (short)r;
}

// ---------------- mask dtype probe ----------------
__global__ void probe_mask(const unsigned* __restrict__ m, int* __restrict__ misc){
  __shared__ int cf32, cbig;
  if (threadIdx.x==0){ cf32=0; cbig=0; }
  __syncthreads();
  int lf=0, lb=0;
  for (int k=0;k<4;k++){
    unsigned x = m[threadIdx.x*4+k];
    if (x==0x3f800000u) lf++;
    else if (x>1u) lb++;
  }
  atomicAdd(&cf32, lf); atomicAdd(&cbig, lb);
  __syncthreads();
  if (threadIdx.x==0){
    int mode=0;
    if (cf32>64) mode=2; else if (cbig>0) mode=1;
    misc[0]=mode;
  }
}

// ---------------- pillarize ----------------
__global__ void compute_pid(const float* __restrict__ pts, const void* __restrict__ maskp,
                            const int* __restrict__ misc, int* __restrict__ pid,
                            int* __restrict__ ccnt){
  int i = blockIdx.x*blockDim.x + threadIdx.x;
  if (i>=NPTS) return;
  int b = blockIdx.y;
  int gi = b*NPTS+i;
  int mode = misc[0];
  bool m;
  if (mode==0)      m = ((const int*)maskp)[gi]!=0;
  else if (mode==1) m = ((const unsigned char*)maskp)[gi]!=0;
  else              m = ((const float*)maskp)[gi]!=0.f;
  int cell = -1;
  if (m){
    float x = pts[(size_t)gi*5+0], y = pts[(size_t)gi*5+1];
    int ix = (int)((x - (-32.0f)) / 0.25f);
    ix = ix<0?0:(ix>255?255:ix);
    int iy = (int)((y - (-32.0f)) / 0.25f);
    iy = iy<0?0:(iy>255?255:iy);
    cell = iy*NXG + ix;
    atomicAdd(&ccnt[b*NCELL+cell], 1);
  }
  pid[gi] = cell;
}

// ---------------- parallel occupancy scan: 2 phases ----------------
// phase A: per-block occ/cnt totals. grid(64,2) x 256 thr, 4 cells/thread (int4).
__global__ __launch_bounds__(256) void scan_a(const int* __restrict__ ccnt,
                                              int2* __restrict__ bpart){
  int b = blockIdx.y, blk = blockIdx.x, t = threadIdx.x;
  int4 v = *(const int4*)&ccnt[b*NCELL + blk*1024 + t*4];
  int occ = (v.x>0)+(v.y>0)+(v.z>0)+(v.w>0);
  int cnt = v.x+v.y+v.z+v.w;
  #pragma unroll
  for (int off=32; off>0; off>>=1){
    occ += __shfl_xor(occ, off, 64);
    cnt += __shfl_xor(cnt, off, 64);
  }
  __shared__ int so[4], sc[4];
  int wv = t>>6, lane = t&63;
  if (lane==0){ so[wv]=occ; sc[wv]=cnt; }
  __syncthreads();
  if (t==0) bpart[b*64+blk] = make_int2(so[0]+so[1]+so[2]+so[3], sc[0]+sc[1]+sc[2]+sc[3]);
}

// phase B: block offset = masked wave-sum of partials; in-wave scan; emit outputs.
__global__ __launch_bounds__(256) void scan_b(const int* __restrict__ ccnt,
    const int2* __restrict__ bpart,
    int* __restrict__ crank, int* __restrict__ cstart, int* __restrict__ pcell,
    int* __restrict__ misc, int* __restrict__ heavy){
  __shared__ int swo[4], swc[4], sk[4];
  __shared__ int bo_, bc_;
  int b = blockIdx.y, blk = blockIdx.x, t = threadIdx.x;
  int wv = t>>6, lane = t&63;
  if (t < 64){
    int2 p = bpart[b*64+t];
    int po = (t<blk)? p.x : 0;
    int pc = (t<blk)? p.y : 0;
    int to = p.x;
    #pragma unroll
    for (int off=32; off>0; off>>=1){
      po += __shfl_xor(po, off, 64);
      pc += __shfl_xor(pc, off, 64);
      to += __shfl_xor(to, off, 64);
    }
    if (t==0){
      bo_ = po; bc_ = pc;
      if (blk==0) misc[1+b] = (to < MAXP) ? to : MAXP;
    }
  }
  int4 v = *(const int4*)&ccnt[b*NCELL + blk*1024 + t*4];
  int occ = (v.x>0)+(v.y>0)+(v.z>0)+(v.w>0);
  int cnt = v.x+v.y+v.z+v.w;
  int io = occ, ic = cnt;
  #pragma unroll
  for (int off=1; off<64; off<<=1){
    int ao = __shfl_up(io, off, 64);
    int ac = __shfl_up(ic, off, 64);
    if (lane >= off){ io += ao; ic += ac; }
  }
  if (lane==63){ swo[wv]=io; swc[wv]=ic; }
  __syncthreads();
  int wvo=0, wvc=0;
  #pragma unroll
  for (int w2=0; w2<4; w2++){
    if (w2<wv){ wvo += swo[w2]; wvc += swc[w2]; }
  }
  int eo = bo_ + wvo + io - occ;   // exclusive prefix (occupied rank)
  int ec = bc_ + wvc + ic - cnt;   // exclusive prefix (point start)
  int kept = 0;
  int cellb = blk*1024 + t*4;
  int vv[4] = {v.x,v.y,v.z,v.w};
  #pragma unroll
  for (int j=0;j<4;j++){
    int c = cellb+j; int val = vv[j];
    if (val>0){
      crank[b*NCELL+c]=eo; cstart[b*NCELL+c]=ec;
      if (eo<MAXP){
        pcell[b*MAXP+eo]=c;
        kept += (val<MAXPP)? val : MAXPP;
        if (val>MAXPP){
          int hi = atomicAdd(&heavy[b],1);
          if (hi<64) heavy[2 + b*64 + hi] = c;
        }
      }
      eo++; ec+=val;
    }
  }
  #pragma unroll
  for (int off=32; off>0; off>>=1) kept += __shfl_xor(kept, off, 64);
  if (lane==0) sk[wv]=kept;
  __syncthreads();
  if (t==0) atomicAdd(&misc[3+b], sk[0]+sk[1]+sk[2]+sk[3]);
}

__global__ void scatter_points(const int* __restrict__ pid, const int* __restrict__ ccnt,
    const int* __restrict__ crank, const int* __restrict__ cstart,
    int* __restrict__ ctmp, int* __restrict__ plist, int* __restrict__ pptr){
  int i = blockIdx.x*blockDim.x + threadIdx.x;
  if (i>=NPTS) return;
  int b = blockIdx.y;
  int gi = b*NPTS+i;
  int cell = pid[gi];
  if (cell<0) return;
  int bc = b*NCELL+cell;
  int pos = cstart[bc] + atomicAdd(&ctmp[bc],1);
  plist[b*NPTS+pos] = i;
  int r = crank[bc];
  if (r>=0 && r<MAXP && ccnt[bc]<=MAXPP) pptr[gi] = r;
}

__global__ void heavy_select(const int* __restrict__ ccnt, const int* __restrict__ crank,
    const int* __restrict__ cstart, const int* __restrict__ plist,
    const int* __restrict__ heavy, int* __restrict__ pptr){
  int b = blockIdx.y;
  int hn = heavy[b]; if (hn>64) hn=64;
  if ((int)blockIdx.x >= hn) return;
  int cell = heavy[2 + b*64 + blockIdx.x];
  int bc = b*NCELL+cell;
  int cnt = ccnt[bc], start = cstart[bc], pr = crank[bc];
  for (int e=threadIdx.x; e<cnt; e+=blockDim.x){
    int pe = plist[b*NPTS+start+e];
    int rank=0;
    for (int k=0;k<cnt;k++) rank += (plist[b*NPTS+start+k] < pe);
    if (rank<MAXPP) pptr[b*NPTS+pe] = pr;
  }
}

// ---------------- layer-1 BN stats (pillar-centric, lane=channel) ----------------
__global__ __launch_bounds__(256) void l1_stats(const float* __restrict__ pts,
    const int* __restrict__ plist, const int* __restrict__ pcell,
    const int* __restrict__ cstart, const int* __restrict__ ccnt,
    const int* __restrict__ pptr, float* __restrict__ psum,
    const int* __restrict__ misc,
    const float* __restrict__ w1, const float* __restrict__ b1,
    float* __restrict__ lstat){
  const int lane = threadIdx.x & 63;
  float w1c[10];
  #pragma unroll
  for (int d=0;d<10;d++) w1c[d]=w1[d*64+lane];
  const float b1c = b1[lane];
  const int npil0 = misc[1], npil1 = misc[2];
  float s0=0.f,q0=0.f,s1=0.f,q1=0.f;
  const int wglobal = (blockIdx.x*256+threadIdx.x)>>6;
  const int nwaves = (gridDim.x*256)>>6;
  for (int qq=wglobal; qq<2*MAXP; qq+=nwaves){
    int b = (qq>=MAXP)?1:0;
    int p = qq-b*MAXP;
    if (p >= (b?npil1:npil0)) continue;
    int cell = pcell[b*MAXP+p];
    int bc = b*NCELL+cell;
    int cnt = ccnt[bc], start = cstart[bc];
    bool heavy = cnt>MAXPP;
    float sx=0.f,sy=0.f,sz=0.f,n=0.f;
    for (int k=0;k<cnt;k++){
      int i = plist[b*NPTS+start+k];
      if (heavy && pptr[b*NPTS+i]!=p) continue;
      const float* qp = &pts[(size_t)(b*NPTS+i)*5];
      sx+=qp[0]; sy+=qp[1]; sz+=qp[2]; n+=1.f;
    }
    float inv = 1.f/fmaxf(n,1.f);
    float mx=sx*inv, my=sy*inv, mz=sz*inv;
    if (lane==0){
      *(float4*)&psum[(size_t)(b*MAXP+p)*4] = make_float4(mx,my,mz,n);
    }
    float gx = -32.0f+((float)(cell&255)+0.5f)*0.25f;
    float gy = -32.0f+((float)(cell>>8)+0.5f)*0.25f;
    float s=0.f,q=0.f;
    for (int k=0;k<cnt;k++){
      int i = plist[b*NPTS+start+k];
      if (heavy && pptr[b*NPTS+i]!=p) continue;
      const float* qp = &pts[(size_t)(b*NPTS+i)*5];
      float x=qp[0], y=qp[1], z=qp[2], i1=qp[3], i2=qp[4];
      float acc=b1c;
      acc=fmaf(x,w1c[0],acc);  acc=fmaf(y,w1c[1],acc);  acc=fmaf(z,w1c[2],acc);
      acc=fmaf(i1,w1c[3],acc); acc=fmaf(i2,w1c[4],acc);
      acc=fmaf(x-mx,w1c[5],acc); acc=fmaf(y-my,w1c[6],acc); acc=fmaf(z-mz,w1c[7],acc);
      acc=fmaf(gx,w1c[8],acc);   acc=fmaf(gy,w1c[9],acc);
      s+=acc; q+=acc*acc;
    }
    if (b){ s1+=s; q1+=q; } else { s0+=s; q0+=q; }
  }
  int rep = wglobal & 15;
  atomicAdd(&lstat[((rep*2+0)*2+0)*64+lane], s0);
  atomicAdd(&lstat[((rep*2+0)*2+1)*64+lane], q0);
  atomicAdd(&lstat[((rep*2+1)*2+0)*64+lane], s1);
  atomicAdd(&lstat[((rep*2+1)*2+1)*64+lane], q1);
}

__global__ void stats_fin1(const float* __restrict__ w1, const float* __restrict__ b1,
    const float* __restrict__ g1, const float* __restrict__ be1,
    const float* __restrict__ w2, const float* __restrict__ b2,
    const float* __restrict__ lstat, float* __restrict__ stats,
    const int* __restrict__ misc){
  __shared__ float z0s[64];
  int b = blockIdx.x, c = threadIdx.x;
  float* S = &stats[(size_t)b*512];
  float s=0.f, q=0.f;
  for (int r=0;r<16;r++){
    s += lstat[((r*2+b)*2+0)*64+c];
    q += lstat[((r*2+b)*2+1)*64+c];
  }
  float b1c = b1[c];
  float nk = (float)misc[3+b];
  const float N = (float)NROWS;
  float pad = N - nk;
  float St = s + pad*b1c;
  float Qt = q + pad*b1c*b1c;
  float mu = St/N;
  float var = fmaxf(Qt/N - mu*mu, 0.f);
  float sc = g1[c]*rsqrtf(var+1e-5f);
  float sh = be1[c]-mu*sc;
  S[256+c]=sc; S[320+c]=sh;
  float z0 = fmaxf(b1c*sc+sh, 0.f);
  z0s[c]=z0;
  __syncthreads();
  float t0 = b2[c];
  for (int i2=0;i2<64;i2++) t0 += z0s[i2]*w2[(size_t)i2*64+c];
  S[128+c]=pad*t0; S[192+c]=pad*t0*t0;
}

// ---------------- pillar-centric MLP + in-register max/min ----------------
__global__ __launch_bounds__(256) void pillar_mlp(const float* __restrict__ pts,
    const int* __restrict__ plist, const int* __restrict__ pcell,
    const int* __restrict__ cstart, const int* __restrict__ ccnt,
    const int* __restrict__ pptr, const float* __restrict__ psum,
    const int* __restrict__ misc,
    const float* __restrict__ w1, const float* __restrict__ b1,
    const float* __restrict__ w2, const float* __restrict__ b2,
    const float* __restrict__ stats, float* __restrict__ l2stat,
    float* __restrict__ fmx, float* __restrict__ fmn){
  const int lane = threadIdx.x & 63;
  float w1c[10];
  #pragma unroll
  for (int d=0;d<10;d++) w1c[d] = w1[d*64+lane];
  f32x32 w2lo, w2hi;
  #pragma unroll
  for (int c=0;c<32;c++) w2lo[c] = w2[(size_t)c*64+lane];
  #pragma unroll
  for (int c=0;c<32;c++) w2hi[c] = w2[(size_t)(c+32)*64+lane];
  const float b1c = b1[lane], b2c = b2[lane];
  const float sc1_0 = stats[256+lane], sh1_0 = stats[320+lane];
  const float sc1_1 = stats[512+256+lane], sh1_1 = stats[512+320+lane];
  const int npil0 = misc[1], npil1 = misc[2];
  float s2_0=0.f, q2_0=0.f, s2_1=0.f, q2_1=0.f;

  const int wglobal = (blockIdx.x*256 + threadIdx.x) >> 6;
  const int nwaves = (gridDim.x*256) >> 6;
  for (int qq = wglobal; qq < 2*MAXP; qq += nwaves){
    int b = (qq >= MAXP) ? 1 : 0;
    int p = qq - b*MAXP;
    int npil = b ? npil1 : npil0;
    if (p >= npil) continue;
    int cell = pcell[b*MAXP+p];
    int bc = b*NCELL+cell;
    int cnt = ccnt[bc], start = cstart[bc];
    bool heavy = cnt > MAXPP;
    float gx = -32.0f + ((float)(cell&255)+0.5f)*0.25f;
    float gy = -32.0f + ((float)(cell>>8)+0.5f)*0.25f;
    const float* mc = &psum[(size_t)(b*MAXP+p)*4];
    float mx = mc[0], my = mc[1], mz = mc[2];
    float sc1 = b ? sc1_1 : sc1_0;
    float sh1 = b ? sh1_1 : sh1_0;
    float tmax = -1e30f, tmin = 1e30f;
    float s2 = 0.f, q2 = 0.f;
    for (int k=0; k<cnt; k++){
      int i = plist[b*NPTS+start+k];
      if (heavy && pptr[b*NPTS+i] != p) continue;
      const float* qp = &pts[(size_t)(b*NPTS+i)*5];
      float x=qp[0], y=qp[1], z=qp[2], i1=qp[3], i2=qp[4];
      float acc = b1c;
      acc = fmaf(x, w1c[0], acc);
      acc = fmaf(y, w1c[1], acc);
      acc = fmaf(z, w1c[2], acc);
      acc = fmaf(i1, w1c[3], acc);
      acc = fmaf(i2, w1c[4], acc);
      acc = fmaf(x-mx, w1c[5], acc);
      acc = fmaf(y-my, w1c[6], acc);
      acc = fmaf(z-mz, w1c[7], acc);
      acc = fmaf(gx, w1c[8], acc);
      acc = fmaf(gy, w1c[9], acc);
      float zz = fmaxf(acc*sc1+sh1, 0.f);
      float t = b2c;
      #pragma unroll
      for (int c=0;c<32;c++){
        float zc = __int_as_float(__builtin_amdgcn_readlane(__float_as_int(zz), c));
        t = fmaf(zc, w2lo[c], t);
      }
      #pragma unroll
      for (int c=0;c<32;c++){
        float zc = __int_as_float(__builtin_amdgcn_readlane(__float_as_int(zz), c+32));
        t = fmaf(zc, w2hi[c], t);
      }
      tmax = fmaxf(tmax, t);
      tmin = fminf(tmin, t);
      s2 += t; q2 += t*t;
    }
    fmx[(size_t)(b*MAXP+p)*64 + lane] = tmax;
    fmn[(size_t)(b*MAXP+p)*64 + lane] = tmin;
    if (b){ s2_1 += s2; q2_1 += q2; } else { s2_0 += s2; q2_0 += q2; }
  }
  int rep = wglobal & 15;
  atomicAdd(&l2stat[((rep*2+0)*2+0)*64+lane], s2_0);
  atomicAdd(&l2stat[((rep*2+0)*2+1)*64+lane], q2_0);
  atomicAdd(&l2stat[((rep*2+1)*2+0)*64+lane], s2_1);
  atomicAdd(&l2stat[((rep*2+1)*2+1)*64+lane], q2_1);
}

__global__ void stats_fin2(const float* __restrict__ g2,const float* __restrict__ be2,
                           const float* __restrict__ l2stat, float* __restrict__ stats){
  int b = blockIdx.x, c = threadIdx.x;
  float* S = &stats[(size_t)b*512];
  float s = S[128+c], q = S[192+c];
  for (int r=0;r<16;r++){
    s += l2stat[((r*2+b)*2+0)*64+c];
    q += l2stat[((r*2+b)*2+1)*64+c];
  }
  const float N = (float)NROWS;
  float m = s/N;
  float v = fmaxf(q/N - m*m, 0.f);
  float sc = g2[c]*rsqrtf(v+1e-5f);
  S[384+c]=sc; S[448+c]=be2[c]-m*sc;
}

// BN2+relu on pillar max/min, scatter to bf16 pixel-major BEV [y][x][ch]
__global__ void scatter_bev(const float* __restrict__ fmx, const float* __restrict__ fmn,
                            const int* __restrict__ pcell, const int* __restrict__ misc,
                            const float* __restrict__ stats, short* __restrict__ bevh){
  int tid = blockIdx.x*256+threadIdx.x;
  if (tid >= 2*64*MAXP) return;
  int c = tid & 63;
  int bp = tid >> 6;
  int b = bp / MAXP;
  int p = bp - b*MAXP;
  if (p >= misc[1+b]) return;
  float sc2 = stats[(size_t)b*512+384+c], sh2 = stats[(size_t)b*512+448+c];
  float t = (sc2 >= 0.f) ? fmx[tid] : fmn[tid];
  float v = fmaxf(sc2*t+sh2, 0.f);
  int cell = pcell[b*MAXP+p];
  bevh[((size_t)((b<<16) + cell))*64 + c] = to_bf16(v);
}

// ---------------- weights fp32 [oc][ic][tap] -> bf16 [tap][oc][ic] ----------------
__global__ void wcvt(const float* __restrict__ w, short* __restrict__ wh){
  int t = blockIdx.x*256 + threadIdx.x;
  if (t >= 36864) return;
  int ic = t & 63, oc = (t>>6)&63, tap = t>>12;
  wh[t] = to_bf16(w[(oc*64+ic)*9 + tap]);
}

// ---------------- BN+relu + fp32->bf16 px-major transpose ----------------
__global__ __launch_bounds__(256) void cvt_px(const float* __restrict__ in,
    const float* __restrict__ bnst, short* __restrict__ outh){
  __shared__ short sT[64*66];
  const int x0 = blockIdx.x*64, y = blockIdx.y, b = blockIdx.z;
  const int t = threadIdx.x;
  for (int e=t; e<4096; e+=256){
    int ch = e>>6, px = e&63;
    float v = in[(((size_t)(b*64+ch))<<16) + (y<<8) + x0 + px];
    v = fmaxf(v*bnst[128+ch]+bnst[192+ch], 0.f);
    sT[px*66+ch] = to_bf16(v);
  }
  __syncthreads();
  for (int e=t; e<2048; e+=256){
    int px = e>>5, c2 = (e&31)*2;
    *(unsigned*)&outh[(((size_t)(b<<16)) + (y<<8) + x0 + px)*64 + c2] =
        *(const unsigned*)&sT[px*66+c2];
  }
}

// ---------------- MFMA conv3x3: bf16 px-major in, fp32 [oc][y][x] out ----------------
#define MFMA16(A,B,C) __builtin_amdgcn_mfma_f32_16x16x32_bf16(A,B,C,0,0,0)

__global__ __launch_bounds__(256,2) void conv_mfma(const short* __restrict__ xh,
    const short* __restrict__ wh, const float* __restrict__ bias,
    float* __restrict__ out){
  __shared__ short sX[18*18*40];   // [yy][xx][ic32 pad40]
  __shared__ short sW[576*40];     // [tap*64+oc][ic32 pad40]
  const int tX = blockIdx.x*16, tY = blockIdx.y*16, b = blockIdx.z;
  const int t = threadIdx.x;
  const int lane = t & 63, wv = t >> 6;
  const int colx = lane & 15;
  const int kb = (lane >> 4) * 8;

  f32x4 a00={0.f,0.f,0.f,0.f}, a01=a00, a02=a00, a03=a00;
  f32x4 a10=a00, a11=a00, a12=a00, a13=a00;
  f32x4 a20=a00, a21=a00, a22=a00, a23=a00;
  f32x4 a30=a00, a31=a00, a32=a00, a33=a00;

  for (int h=0; h<2; ++h){
    __syncthreads();
    for (int e=t; e<1296; e+=256){
      int px = e>>2, j = e&3;
      int yy = px/18, xx = px - yy*18;
      int gy = tY+yy-1, gx = tX+xx-1;
      uint4 v = make_uint4(0,0,0,0);
      if ((unsigned)gy<256u && (unsigned)gx<256u)
        v = *(const uint4*)&xh[((size_t)((b<<16) + (gy<<8) + gx))*64 + h*32 + j*8];
      *(uint4*)&sX[px*40 + j*8] = v;
    }
    for (int e=t; e<2304; e+=256){
      int row = e>>2, j = e&3;
      uint4 v = *(const uint4*)&wh[(size_t)row*64 + h*32 + j*8];
      *(uint4*)&sW[row*40 + j*8] = v;
    }
    __syncthreads();
    #pragma unroll
    for (int tap=0; tap<9; ++tap){
      const int dy = tap/3, dx = tap - dy*3;
      s16x8 wA = *(const s16x8*)&sW[(tap*64 +  0 + colx)*40 + kb];
      s16x8 wB = *(const s16x8*)&sW[(tap*64 + 16 + colx)*40 + kb];
      s16x8 wC = *(const s16x8*)&sW[(tap*64 + 32 + colx)*40 + kb];
      s16x8 wD = *(const s16x8*)&sW[(tap*64 + 48 + colx)*40 + kb];
      s16x8 x0 = *(const s16x8*)&sX[((wv*4+0+dy)*18 + colx+dx)*40 + kb];
      s16x8 x1 = *(const s16x8*)&sX[((wv*4+1+dy)*18 + colx+dx)*40 + kb];
      s16x8 x2 = *(const s16x8*)&sX[((wv*4+2+dy)*18 + colx+dx)*40 + kb];
      s16x8 x3 = *(const s16x8*)&sX[((wv*4+3+dy)*18 + colx+dx)*40 + kb];
      a00 = MFMA16(wA,x0,a00); a01 = MFMA16(wA,x1,a01);
      a02 = MFMA16(wA,x2,a02); a03 = MFMA16(wA,x3,a03);
      a10 = MFMA16(wB,x0,a10); a11 = MFMA16(wB,x1,a11);
      a12 = MFMA16(wB,x2,a12); a13 = MFMA16(wB,x3,a13);
      a20 = MFMA16(wC,x0,a20); a21 = MFMA16(wC,x1,a21);
      a22 = MFMA16(wC,x2,a22); a23 = MFMA16(wC,x3,a23);
      a30 = MFMA16(wD,x0,a30); a31 = MFMA16(wD,x1,a31);
      a32 = MFMA16(wD,x2,a32); a33 = MFMA16(wD,x3,a33);
    }
  }
  const int ocl = (lane>>4)*4;
  #define EPI(G,R,ACC) { \
    const int y = tY + wv*4 + R; \
    _Pragma("unroll") \
    for (int m=0;m<4;m++){ \
      int oc = G*16 + ocl + m; \
      out[(((size_t)(b*64+oc))<<16) + (y<<8) + tX + colx] = ACC[m] + bias[oc]; \
    } }
  EPI(0,0,a00) EPI(0,1,a01) EPI(0,2,a02) EPI(0,3,a03)
  EPI(1,0,a10) EPI(1,1,a11) EPI(1,2,a12) EPI(1,3,a13)
  EPI(2,0,a20) EPI(2,1,a21) EPI(2,2,a22) EPI(2,3,a23)
  EPI(3,0,a30) EPI(3,1,a31) EPI(3,2,a32) EPI(3,3,a33)
  #undef EPI
}

__global__ __launch_bounds__(256) void bn_stats(const float* __restrict__ x, float* __restrict__ bnst){
  int c = blockIdx.x, part = blockIdx.y;
  float s=0.f, q=0.f;
  for (int b=0;b<2;b++){
    const float4* p = (const float4*)&x[(((size_t)(b*64+c))<<16) + (size_t)part*8192];
    for (int k=threadIdx.x;k<2048;k+=256){
      float4 v = p[k];
      s += v.x+v.y+v.z+v.w;
      q += v.x*v.x+v.y*v.y+v.z*v.z+v.w*v.w;
    }
  }
  __shared__ float rs[256], rq[256];
  rs[threadIdx.x]=s; rq[threadIdx.x]=q; __syncthreads();
  for (int o=128;o>0;o>>=1){
    if (threadIdx.x<o){ rs[threadIdx.x]+=rs[threadIdx.x+o]; rq[threadIdx.x]+=rq[threadIdx.x+o]; }
    __syncthreads();
  }
  if (threadIdx.x==0){ atomicAdd(&bnst[c], rs[0]); atomicAdd(&bnst[64+c], rq[0]); }
}

__global__ void bn_fin(float* __restrict__ bnst, const float* __restrict__ g, const float* __restrict__ be){
  int c = threadIdx.x;
  const float n = 131072.f;
  float m = bnst[c]/n;
  float v = fmaxf(bnst[64+c]/n - m*m, 0.f);
  float sc = g[c]*rsqrtf(v+1e-5f);
  bnst[128+c]=sc; bnst[192+c]=be[c]-m*sc;
}

__global__ __launch_bounds__(256) void bn_apply(float* __restrict__ x, const float* __restrict__ bnst){
  size_t idx = (size_t)blockIdx.x*256 + threadIdx.x;
  size_t stride = (size_t)gridDim.x*256;
  float4* p = (float4*)x;
  for (size_t k=idx; k<2097152ULL; k+=stride){
    int c = (int)((k>>14)&63);
    float sc = bnst[128+c], sh = bnst[192+c];
    float4 v = p[k];
    v.x=fmaxf(v.x*sc+sh,0.f); v.y=fmaxf(v.y*sc+sh,0.f);
    v.z=fmaxf(v.z*sc+sh,0.f); v.w=fmaxf(v.w*sc+sh,0.f);
    p[k]=v;
  }
}

// ---------------- launch ----------------
extern "C" void kernel_launch(void* const* d_in, const int* in_sizes, int n_in,
                              void* d_out, int out_size, void* d_ws, size_t ws_size,
                              hipStream_t stream){
  const float* pts  = (const float*)d_in[0];
  const void*  mask = d_in[1];
  const float* w1 = (const float*)d_in[2];
  const float* b1 = (const float*)d_in[3];
  const float* g1 = (const float*)d_in[4];
  const float* be1= (const float*)d_in[5];
  const float* w2 = (const float*)d_in[6];
  const float* b2 = (const float*)d_in[7];
  const float* g2 = (const float*)d_in[8];
  const float* be2= (const float*)d_in[9];
  const float* cw[3]  = {(const float*)d_in[10],(const float*)d_in[14],(const float*)d_in[18]};
  const float* cb[3]  = {(const float*)d_in[11],(const float*)d_in[15],(const float*)d_in[19]};
  const float* cg[3]  = {(const float*)d_in[12],(const float*)d_in[16],(const float*)d_in[20]};
  const float* cbe[3] = {(const float*)d_in[13],(const float*)d_in[17],(const float*)d_in[21]};
  float* out = (float*)d_out;

  char* W = (char*)d_ws;
  size_t off = 0;
  auto A = [&](size_t n){ size_t r = off; off = (off + n + 255) & ~(size_t)255; return r; };
  short*    BIGH  = (short*)   (W + A((size_t)2*NCELL*64*2));
  int*      PID   = (int*)     (W + A((size_t)2*NPTS*4));
  int*      CCNT  = (int*)     (W + A((size_t)2*NCELL*4));
  int*      CRANK = (int*)     (W + A((size_t)2*NCELL*4));
  int*      CSTART= (int*)     (W + A((size_t)2*NCELL*4));
  int*      CTMP  = (int*)     (W + A((size_t)2*NCELL*4));
  int*      PLIST = (int*)     (W + A((size_t)2*NPTS*4));
  int*      PPTR  = (int*)     (W + A((size_t)2*NPTS*4));
  int*      PCELL = (int*)     (W + A((size_t)2*MAXP*4));
  float*    PSUM  = (float*)   (W + A((size_t)2*MAXP*16));
  float*    FMX   = (float*)   (W + A((size_t)2*MAXP*64*4));
  float*    FMN   = (float*)   (W + A((size_t)2*MAXP*64*4));
  float*    STATS = (float*)   (W + A((size_t)2*512*4));
  float*    LSTAT = (float*)   (W + A((size_t)16*2*2*64*4));
  float*    L2STAT= (float*)   (W + A((size_t)16*2*2*64*4));
  float*    BNST  = (float*)   (W + A((size_t)256*4));
  short*    WH0   = (short*)   (W + A((size_t)36864*2));
  short*    WH1   = (short*)   (W + A((size_t)36864*2));
  short*    WH2   = (short*)   (W + A((size_t)36864*2));
  int2*     BPART = (int2*)    (W + A((size_t)2*64*8));
  int*      HEAVY = (int*)     (W + A((size_t)(2+2*64)*4));
  int*      MISC  = (int*)     (W + A(256));

  hipMemsetAsync(BIGH, 0, (size_t)2*NCELL*64*2, stream);
  hipMemsetAsync(CCNT, 0, (size_t)2*NCELL*4, stream);
  hipMemsetAsync(CTMP, 0, (size_t)2*NCELL*4, stream);
  hipMemsetAsync(PPTR, 0xFF, (size_t)2*NPTS*4, stream);
  hipMemsetAsync(STATS,0, (size_t)2*512*4, stream);
  hipMemsetAsync(LSTAT,0, (size_t)16*2*2*64*4, stream);
  hipMemsetAsync(L2STAT,0,(size_t)16*2*2*64*4, stream);
  hipMemsetAsync(BNST, 0, (size_t)256*4, stream);
  hipMemsetAsync(HEAVY,0, (size_t)(2+2*64)*4, stream);
  hipMemsetAsync(MISC, 0, 256, stream);

  dim3 perPt((NPTS+255)/256, 2);

  probe_mask<<<1,256,0,stream>>>((const unsigned*)mask, MISC);
  compute_pid<<<perPt,256,0,stream>>>(pts, mask, MISC, PID, CCNT);
  wcvt<<<144,256,0,stream>>>(cw[0], WH0);
  wcvt<<<144,256,0,stream>>>(cw[1], WH1);
  wcvt<<<144,256,0,stream>>>(cw[2], WH2);
  scan_a<<<dim3(64,2),256,0,stream>>>(CCNT, BPART);
  scan_b<<<dim3(64,2),256,0,stream>>>(CCNT, BPART, CRANK, CSTART, PCELL, MISC, HEAVY);
  scatter_points<<<perPt,256,0,stream>>>(PID, CCNT, CRANK, CSTART, CTMP, PLIST, PPTR);
  heavy_select<<<dim3(64,2),64,0,stream>>>(CCNT, CRANK, CSTART, PLIST, HEAVY, PPTR);
  l1_stats<<<512,256,0,stream>>>(pts, PLIST, PCELL, CSTART, CCNT, PPTR, PSUM, MISC, w1, b1, LSTAT);
  stats_fin1<<<2,64,0,stream>>>(w1, b1, g1, be1, w2, b2, LSTAT, STATS, MISC);
  pillar_mlp<<<512,256,0,stream>>>(pts, PLIST, PCELL, CSTART, CCNT, PPTR, PSUM, MISC,
                                   w1, b1, w2, b2, STATS, L2STAT, FMX, FMN);
  stats_fin2<<<2,64,0,stream>>>(g2, be2, L2STAT, STATS);
  scatter_bev<<<(2*64*MAXP+255)/256,256,0,stream>>>(FMX, FMN, PCELL, MISC, STATS, BIGH);

  // conv1: BIGH -> d_out
  conv_mfma<<<dim3(16,16,2),256,0,stream>>>(BIGH, WH0, cb[0], out);
  bn_stats<<<dim3(64,8),256,0,stream>>>(out, BNST);
  bn_fin<<<1,64,0,stream>>>(BNST, cg[0], cbe[0]);
  // bn1+relu -> BIGH ; conv2: BIGH -> d_out
  cvt_px<<<dim3(4,256,2),256,0,stream>>>(out, BNST, BIGH);
  hipMemsetAsync(BNST, 0, 512, stream);
  conv_mfma<<<dim3(16,16,2),256,0,stream>>>(BIGH, WH1, cb[1], out);
  bn_stats<<<dim3(64,8),256,0,stream>>>(out, BNST);
  bn_fin<<<1,64,0,stream>>>(BNST, cg[1], cbe[1]);
  // bn2+relu -> BIGH ; conv3: BIGH -> d_out
  cvt_px<<<dim3(4,256,2),256,0,stream>>>(out, BNST, BIGH);
  hipMemsetAsync(BNST, 0, 512, stream);
  conv_mfma<<<dim3(16,16,2),256,0,stream>>>(BIGH, WH2, cb[2], out);
  bn_stats<<<dim3(64,8),256,0,stream>>>(out, BNST);
  bn_fin<<<1,64,0,stream>>>(BNST, cg[2], cbe[2]);
  bn_apply<<<2048,256,0,stream>>>(out, BNST);
}

// Round 6
// 281.239 us; speedup vs baseline: 4.4612x; 1.1319x over previous
//
#include <hip/hip_runtime.h>

#define NPTS 60000
#define NXG 256
#define NCELL 65536
#define MAXP 12000
#define MAXPP 32
#define NROWS (MAXP*MAXPP)

typedef float f32x32 __attribute__((ext_vector_type(32)));
typedef float f32x4  __attribute__((ext_vector_type(4)));
typedef short s16x8  __attribute__((ext_vector_type(8)));

__device__ __forceinline__ short to_bf16(float f){
  unsigned u = __float_as_uint(f);
  unsigned r = (u + 0x7FFFu + ((u>>16)&1u)) >> 16;
  return (short)r;
}

// ---------------- mask dtype probe ----------------
__global__ void probe_mask(const unsigned* __restrict__ m, int* __restrict__ misc){
  __shared__ int cf32, cbig;
  if (threadIdx.x==0){ cf32=0; cbig=0; }
  __syncthreads();
  int lf=0, lb=0;
  for (int k=0;k<4;k++){
    unsigned x = m[threadIdx.x*4+k];
    if (x==0x3f800000u) lf++;
    else if (x>1u) lb++;
  }
  atomicAdd(&cf32, lf); atomicAdd(&cbig, lb);
  __syncthreads();
  if (threadIdx.x==0){
    int mode=0;
    if (cf32>64) mode=2; else if (cbig>0) mode=1;
    misc[0]=mode;
  }
}

// ---------------- pillarize ----------------
__global__ void compute_pid(const float* __restrict__ pts, const void* __restrict__ maskp,
                            const int* __restrict__ misc, int* __restrict__ pid,
                            int* __restrict__ ccnt){
  int i = blockIdx.x*blockDim.x + threadIdx.x;
  if (i>=NPTS) return;
  int b = blockIdx.y;
  int gi = b*NPTS+i;
  int mode = misc[0];
  bool m;
  if (mode==0)      m = ((const int*)maskp)[gi]!=0;
  else if (mode==1) m = ((const unsigned char*)maskp)[gi]!=0;
  else              m = ((const float*)maskp)[gi]!=0.f;
  int cell = -1;
  if (m){
    float x = pts[(size_t)gi*5+0], y = pts[(size_t)gi*5+1];
    int ix = (int)((x - (-32.0f)) / 0.25f);
    ix = ix<0?0:(ix>255?255:ix);
    int iy = (int)((y - (-32.0f)) / 0.25f);
    iy = iy<0?0:(iy>255?255:iy);
    cell = iy*NXG + ix;
    atomicAdd(&ccnt[b*NCELL+cell], 1);
  }
  pid[gi] = cell;
}

// ---------------- parallel occupancy scan: 2 phases ----------------
__global__ __launch_bounds__(256) void scan_a(const int* __restrict__ ccnt,
                                              int2* __restrict__ bpart){
  int b = blockIdx.y, blk = blockIdx.x, t = threadIdx.x;
  int4 v = *(const int4*)&ccnt[b*NCELL + blk*1024 + t*4];
  int occ = (v.x>0)+(v.y>0)+(v.z>0)+(v.w>0);
  int cnt = v.x+v.y+v.z+v.w;
  #pragma unroll
  for (int off=32; off>0; off>>=1){
    occ += __shfl_xor(occ, off, 64);
    cnt += __shfl_xor(cnt, off, 64);
  }
  __shared__ int so[4], sc[4];
  int wv = t>>6, lane = t&63;
  if (lane==0){ so[wv]=occ; sc[wv]=cnt; }
  __syncthreads();
  if (t==0) bpart[b*64+blk] = make_int2(so[0]+so[1]+so[2]+so[3], sc[0]+sc[1]+sc[2]+sc[3]);
}

__global__ __launch_bounds__(256) void scan_b(const int* __restrict__ ccnt,
    const int2* __restrict__ bpart,
    int* __restrict__ crank, int* __restrict__ cstart, int* __restrict__ pcell,
    int* __restrict__ misc, int* __restrict__ heavy){
  __shared__ int swo[4], swc[4], sk[4];
  __shared__ int bo_, bc_;
  int b = blockIdx.y, blk = blockIdx.x, t = threadIdx.x;
  int wv = t>>6, lane = t&63;
  if (t < 64){
    int2 p = bpart[b*64+t];
    int po = (t<blk)? p.x : 0;
    int pc = (t<blk)? p.y : 0;
    int to = p.x;
    int tc = p.y;
    #pragma unroll
    for (int off=32; off>0; off>>=1){
      po += __shfl_xor(po, off, 64);
      pc += __shfl_xor(pc, off, 64);
      to += __shfl_xor(to, off, 64);
      tc += __shfl_xor(tc, off, 64);
    }
    if (t==0){
      bo_ = po; bc_ = pc;
      if (blk==0){
        misc[1+b] = (to < MAXP) ? to : MAXP;
        misc[5+b] = tc;               // total masked points
      }
    }
  }
  int4 v = *(const int4*)&ccnt[b*NCELL + blk*1024 + t*4];
  int occ = (v.x>0)+(v.y>0)+(v.z>0)+(v.w>0);
  int cnt = v.x+v.y+v.z+v.w;
  int io = occ, ic = cnt;
  #pragma unroll
  for (int off=1; off<64; off<<=1){
    int ao = __shfl_up(io, off, 64);
    int ac = __shfl_up(ic, off, 64);
    if (lane >= off){ io += ao; ic += ac; }
  }
  if (lane==63){ swo[wv]=io; swc[wv]=ic; }
  __syncthreads();
  int wvo=0, wvc=0;
  #pragma unroll
  for (int w2=0; w2<4; w2++){
    if (w2<wv){ wvo += swo[w2]; wvc += swc[w2]; }
  }
  int eo = bo_ + wvo + io - occ;
  int ec = bc_ + wvc + ic - cnt;
  int kept = 0;
  int cellb = blk*1024 + t*4;
  int vv[4] = {v.x,v.y,v.z,v.w};
  #pragma unroll
  for (int j=0;j<4;j++){
    int c = cellb+j; int val = vv[j];
    if (val>0){
      crank[b*NCELL+c]=eo; cstart[b*NCELL+c]=ec;
      if (eo<MAXP){
        pcell[b*MAXP+eo]=c;
        kept += (val<MAXPP)? val : MAXPP;
        if (val>MAXPP){
          int hi = atomicAdd(&heavy[b],1);
          if (hi<64) heavy[2 + b*64 + hi] = c;
        }
      }
      eo++; ec+=val;
    }
  }
  #pragma unroll
  for (int off=32; off>0; off>>=1) kept += __shfl_xor(kept, off, 64);
  if (lane==0) sk[wv]=kept;
  __syncthreads();
  if (t==0) atomicAdd(&misc[3+b], sk[0]+sk[1]+sk[2]+sk[3]);
}

__global__ void scatter_points(const int* __restrict__ pid, const int* __restrict__ ccnt,
    const int* __restrict__ crank, const int* __restrict__ cstart,
    int* __restrict__ ctmp, int* __restrict__ plist, int* __restrict__ pptr){
  int i = blockIdx.x*blockDim.x + threadIdx.x;
  if (i>=NPTS) return;
  int b = blockIdx.y;
  int gi = b*NPTS+i;
  int cell = pid[gi];
  if (cell<0) return;
  int bc = b*NCELL+cell;
  int pos = cstart[bc] + atomicAdd(&ctmp[bc],1);
  plist[b*NPTS+pos] = i;
  int r = crank[bc];
  if (r>=0 && r<MAXP && ccnt[bc]<=MAXPP) pptr[gi] = r;
}

__global__ void heavy_select(const int* __restrict__ ccnt, const int* __restrict__ crank,
    const int* __restrict__ cstart, const int* __restrict__ plist,
    const int* __restrict__ heavy, int* __restrict__ pptr){
  int b = blockIdx.y;
  int hn = heavy[b]; if (hn>64) hn=64;
  if ((int)blockIdx.x >= hn) return;
  int cell = heavy[2 + b*64 + blockIdx.x];
  int bc = b*NCELL+cell;
  int cnt = ccnt[bc], start = cstart[bc], pr = crank[bc];
  for (int e=threadIdx.x; e<cnt; e+=blockDim.x){
    int pe = plist[b*NPTS+start+e];
    int rank=0;
    for (int k=0;k<cnt;k++) rank += (plist[b*NPTS+start+k] < pe);
    if (rank<MAXPP) pptr[b*NPTS+pe] = pr;
  }
}

// ---------------- compact pillar-ordered point tensor + centroid atomics ----------------
// CPTS[pos]: {x,y,z,i1} {i2,gx,gy,rid_bits}
__global__ __launch_bounds__(256) void gather_cpts(const float* __restrict__ pts,
    const int* __restrict__ pid, const int* __restrict__ pptr,
    const int* __restrict__ plist, const int* __restrict__ misc,
    float* __restrict__ cpts, float* __restrict__ psum){
  int pos = blockIdx.x*256 + threadIdx.x;
  int b = blockIdx.y;
  if (pos >= misc[5+b]) return;
  int i = plist[b*NPTS+pos];
  int gi = b*NPTS+i;
  const float* qp = &pts[(size_t)gi*5];
  float x=qp[0], y=qp[1], z=qp[2], i1=qp[3], i2=qp[4];
  int cell = pid[gi];
  int rid = pptr[gi];
  float gx = -32.0f + ((float)(cell&255)+0.5f)*0.25f;
  float gy = -32.0f + ((float)(cell>>8)+0.5f)*0.25f;
  float4* cp = (float4*)&cpts[(size_t)(b*NPTS+pos)*8];
  cp[0] = make_float4(x,y,z,i1);
  cp[1] = make_float4(i2,gx,gy,__int_as_float(rid));
  if (rid>=0){
    float* s = &psum[(size_t)(b*MAXP+rid)*4];
    atomicAdd(s+0,x); atomicAdd(s+1,y); atomicAdd(s+2,z); atomicAdd(s+3,1.f);
  }
}

__global__ void centroid_fin(float* __restrict__ psum){
  int i = blockIdx.x*blockDim.x + threadIdx.x;
  if (i>=2*MAXP) return;
  float* s = &psum[(size_t)i*4];
  float inv = 1.0f / fmaxf(s[3],1.0f);
  s[0]*=inv; s[1]*=inv; s[2]*=inv;
}

// ---------------- global aug moments (65 accumulators, register-resident) ----------------
// lstat[rep][b][65]: k in [0,55) pair moments (d<=e), [55,65) linear sums.
#define MM_ACC(K,V) { if ((K)<32) m0[(K)&31]+=(V); else if ((K)<64) m1[((K)-32)&31]+=(V); else m2+=(V); }
__global__ __launch_bounds__(256) void moments(const float* __restrict__ cpts,
    const float* __restrict__ psum, const int* __restrict__ misc,
    float* __restrict__ lstat){
  int b = blockIdx.y;
  int n = misc[5+b];
  f32x32 m0, m1; float m2 = 0.f;
  #pragma unroll
  for (int j=0;j<32;j++){ m0[j]=0.f; m1[j]=0.f; }
  for (int pos = blockIdx.x*256+threadIdx.x; pos<n; pos += gridDim.x*256){
    const float4* cp = (const float4*)&cpts[(size_t)(b*NPTS+pos)*8];
    float4 f1 = cp[0], f2 = cp[1];
    int rid = __float_as_int(f2.w);
    if (rid<0) continue;
    float4 mc = *(const float4*)&psum[(size_t)(b*MAXP+rid)*4];
    float aug[10] = {f1.x,f1.y,f1.z,f1.w,f2.x,
                     f1.x-mc.x, f1.y-mc.y, f1.z-mc.z, f2.y, f2.z};
    #pragma unroll
    for (int d=0; d<10; d++){
      #pragma unroll
      for (int e=d; e<10; e++){
        const int k = d*10 - d*(d-1)/2 + (e-d);
        MM_ACC(k, aug[d]*aug[e]);
      }
      const int kl = 55+d;
      MM_ACC(kl, aug[d]);
    }
  }
  int lane = threadIdx.x & 63;
  int rep = ((blockIdx.x*256+threadIdx.x)>>6) & 15;
  float* dst = &lstat[(size_t)(rep*2+b)*65];
  #pragma unroll
  for (int j=0;j<32;j++){
    float v = m0[j];
    #pragma unroll
    for (int off=32; off>0; off>>=1) v += __shfl_xor(v, off, 64);
    if (lane==0) atomicAdd(&dst[j], v);
  }
  #pragma unroll
  for (int j=0;j<32;j++){
    float v = m1[j];
    #pragma unroll
    for (int off=32; off>0; off>>=1) v += __shfl_xor(v, off, 64);
    if (lane==0) atomicAdd(&dst[32+j], v);
  }
  {
    float v = m2;
    #pragma unroll
    for (int off=32; off>0; off>>=1) v += __shfl_xor(v, off, 64);
    if (lane==0) atomicAdd(&dst[64], v);
  }
}

// stats layout per batch (512 floats):
// [128,192) s2 pad seed  [192,256) q2 pad seed
// [256,320) sc1 [320,384) sh1 [384,448) sc2 [448,512) sh2
__global__ void stats_fin1(const float* __restrict__ w1, const float* __restrict__ b1,
    const float* __restrict__ g1, const float* __restrict__ be1,
    const float* __restrict__ w2, const float* __restrict__ b2,
    const float* __restrict__ lstat, float* __restrict__ stats,
    const int* __restrict__ misc){
  __shared__ float M[65];
  __shared__ float z0s[64];
  int b = blockIdx.x, c = threadIdx.x;
  for (int e=c; e<65; e+=64){
    float s=0.f;
    for (int r=0;r<16;r++) s += lstat[(size_t)(r*2+b)*65+e];
    M[e]=s;
  }
  __syncthreads();
  float* S = &stats[(size_t)b*512];
  float wcol[10];
  #pragma unroll
  for (int d=0;d<10;d++) wcol[d] = w1[d*64+c];
  float b1c = b1[c];
  float nk = (float)misc[3+b];
  const float N = (float)NROWS;
  float pad = N - nk;
  float lw = 0.f;
  #pragma unroll
  for (int d=0;d<10;d++) lw += M[55+d]*wcol[d];
  float s = nk*b1c + lw;
  float qq = nk*b1c*b1c + 2.f*b1c*lw;
  #pragma unroll
  for (int d=0; d<10; d++){
    #pragma unroll
    for (int e=d; e<10; e++){
      float m = M[d*10 - d*(d-1)/2 + (e-d)];
      qq += ((d==e)?1.f:2.f)*m*wcol[d]*wcol[e];
    }
  }
  float St = s + pad*b1c;
  float Qt = qq + pad*b1c*b1c;
  float mu = St/N;
  float var = fmaxf(Qt/N - mu*mu, 0.f);
  float sc = g1[c]*rsqrtf(var+1e-5f);
  float sh = be1[c]-mu*sc;
  S[256+c]=sc; S[320+c]=sh;
  float z0 = fmaxf(b1c*sc+sh, 0.f);
  z0s[c]=z0;
  __syncthreads();
  float t0 = b2[c];
  for (int i2=0;i2<64;i2++) t0 += z0s[i2]*w2[(size_t)i2*64+c];
  S[128+c]=pad*t0; S[192+c]=pad*t0*t0;
}

// ---------------- pillar-centric MLP + in-register max/min (CPTS input) ----------------
__global__ __launch_bounds__(256) void pillar_mlp(const float* __restrict__ cpts,
    const int* __restrict__ pcell, const int* __restrict__ cstart,
    const int* __restrict__ ccnt, const float* __restrict__ psum,
    const int* __restrict__ misc,
    const float* __restrict__ w1, const float* __restrict__ b1,
    const float* __restrict__ w2, const float* __restrict__ b2,
    const float* __restrict__ stats, float* __restrict__ l2stat,
    float* __restrict__ fmx, float* __restrict__ fmn){
  const int lane = threadIdx.x & 63;
  float w1c[10];
  #pragma unroll
  for (int d=0;d<10;d++) w1c[d] = w1[d*64+lane];
  f32x32 w2lo, w2hi;
  #pragma unroll
  for (int c=0;c<32;c++) w2lo[c] = w2[(size_t)c*64+lane];
  #pragma unroll
  for (int c=0;c<32;c++) w2hi[c] = w2[(size_t)(c+32)*64+lane];
  const float b1c = b1[lane], b2c = b2[lane];
  const float sc1_0 = stats[256+lane], sh1_0 = stats[320+lane];
  const float sc1_1 = stats[512+256+lane], sh1_1 = stats[512+320+lane];
  const int npil0 = misc[1], npil1 = misc[2];
  float s2_0=0.f, q2_0=0.f, s2_1=0.f, q2_1=0.f;

  const int wglobal = (blockIdx.x*256 + threadIdx.x) >> 6;
  const int nwaves = (gridDim.x*256) >> 6;
  for (int qq = wglobal; qq < 2*MAXP; qq += nwaves){
    int b = (qq >= MAXP) ? 1 : 0;
    int p = qq - b*MAXP;
    int npil = b ? npil1 : npil0;
    if (p >= npil) continue;
    int cell = pcell[b*MAXP+p];
    int bc = b*NCELL+cell;
    int cnt = ccnt[bc], start = cstart[bc];
    const float* mc = &psum[(size_t)(b*MAXP+p)*4];
    float mx = mc[0], my = mc[1], mz = mc[2];
    float gx = -32.0f + ((float)(cell&255)+0.5f)*0.25f;
    float gy = -32.0f + ((float)(cell>>8)+0.5f)*0.25f;
    float sc1 = b ? sc1_1 : sc1_0;
    float sh1 = b ? sh1_1 : sh1_0;
    float tmax = -1e30f, tmin = 1e30f;
    float s2 = 0.f, q2 = 0.f;
    for (int k=0; k<cnt; k++){
      const float4* cp = (const float4*)&cpts[(size_t)(b*NPTS+start+k)*8];
      float4 f1 = cp[0], f2 = cp[1];
      int rid = __float_as_int(f2.w);
      if (rid != p) continue;
      float x=f1.x, y=f1.y, z=f1.z, i1=f1.w, i2=f2.x;
      float acc = b1c;
      acc = fmaf(x, w1c[0], acc);
      acc = fmaf(y, w1c[1], acc);
      acc = fmaf(z, w1c[2], acc);
      acc = fmaf(i1, w1c[3], acc);
      acc = fmaf(i2, w1c[4], acc);
      acc = fmaf(x-mx, w1c[5], acc);
      acc = fmaf(y-my, w1c[6], acc);
      acc = fmaf(z-mz, w1c[7], acc);
      acc = fmaf(gx, w1c[8], acc);
      acc = fmaf(gy, w1c[9], acc);
      float zz = fmaxf(acc*sc1+sh1, 0.f);
      float t = b2c;
      #pragma unroll
      for (int c=0;c<32;c++){
        float zc = __int_as_float(__builtin_amdgcn_readlane(__float_as_int(zz), c));
        t = fmaf(zc, w2lo[c], t);
      }
      #pragma unroll
      for (int c=0;c<32;c++){
        float zc = __int_as_float(__builtin_amdgcn_readlane(__float_as_int(zz), c+32));
        t = fmaf(zc, w2hi[c], t);
      }
      tmax = fmaxf(tmax, t);
      tmin = fminf(tmin, t);
      s2 += t; q2 += t*t;
    }
    fmx[(size_t)(b*MAXP+p)*64 + lane] = tmax;
    fmn[(size_t)(b*MAXP+p)*64 + lane] = tmin;
    if (b){ s2_1 += s2; q2_1 += q2; } else { s2_0 += s2; q2_0 += q2; }
  }
  int rep = wglobal & 15;
  atomicAdd(&l2stat[((rep*2+0)*2+0)*64+lane], s2_0);
  atomicAdd(&l2stat[((rep*2+0)*2+1)*64+lane], q2_0);
  atomicAdd(&l2stat[((rep*2+1)*2+0)*64+lane], s2_1);
  atomicAdd(&l2stat[((rep*2+1)*2+1)*64+lane], q2_1);
}

__global__ void stats_fin2(const float* __restrict__ g2,const float* __restrict__ be2,
                           const float* __restrict__ l2stat, float* __restrict__ stats){
  int b = blockIdx.x, c = threadIdx.x;
  float* S = &stats[(size_t)b*512];
  float s = S[128+c], q = S[192+c];
  for (int r=0;r<16;r++){
    s += l2stat[((r*2+b)*2+0)*64+c];
    q += l2stat[((r*2+b)*2+1)*64+c];
  }
  const float N = (float)NROWS;
  float m = s/N;
  float v = fmaxf(q/N - m*m, 0.f);
  float sc = g2[c]*rsqrtf(v+1e-5f);
  S[384+c]=sc; S[448+c]=be2[c]-m*sc;
}

// BN2+relu on pillar max/min, scatter to bf16 pixel-major BEV [y][x][ch]
__global__ void scatter_bev(const float* __restrict__ fmx, const float* __restrict__ fmn,
                            const int* __restrict__ pcell, const int* __restrict__ misc,
                            const float* __restrict__ stats, short* __restrict__ bevh){
  int tid = blockIdx.x*256+threadIdx.x;
  if (tid >= 2*64*MAXP) return;
  int c = tid & 63;
  int bp = tid >> 6;
  int b = bp / MAXP;
  int p = bp - b*MAXP;
  if (p >= misc[1+b]) return;
  float sc2 = stats[(size_t)b*512+384+c], sh2 = stats[(size_t)b*512+448+c];
  float t = (sc2 >= 0.f) ? fmx[tid] : fmn[tid];
  float v = fmaxf(sc2*t+sh2, 0.f);
  int cell = pcell[b*MAXP+p];
  bevh[((size_t)((b<<16) + cell))*64 + c] = to_bf16(v);
}

// ---------------- weights fp32 [oc][ic][tap] -> bf16 [tap][oc][ic] ----------------
__global__ void wcvt(const float* __restrict__ w, short* __restrict__ wh){
  int t = blockIdx.x*256 + threadIdx.x;
  if (t >= 36864) return;
  int ic = t & 63, oc = (t>>6)&63, tap = t>>12;
  wh[t] = to_bf16(w[(oc*64+ic)*9 + tap]);
}

// ---------------- BN+relu + fp32->bf16 px-major transpose ----------------
__global__ __launch_bounds__(256) void cvt_px(const float* __restrict__ in,
    const float* __restrict__ bnst, short* __restrict__ outh){
  __shared__ short sT[64*66];
  const int x0 = blockIdx.x*64, y = blockIdx.y, b = blockIdx.z;
  const int t = threadIdx.x;
  for (int e=t; e<4096; e+=256){
    int ch = e>>6, px = e&63;
    float v = in[(((size_t)(b*64+ch))<<16) + (y<<8) + x0 + px];
    v = fmaxf(v*bnst[128+ch]+bnst[192+ch], 0.f);
    sT[px*66+ch] = to_bf16(v);
  }
  __syncthreads();
  for (int e=t; e<2048; e+=256){
    int px = e>>5, c2 = (e&31)*2;
    *(unsigned*)&outh[(((size_t)(b<<16)) + (y<<8) + x0 + px)*64 + c2] =
        *(const unsigned*)&sT[px*66+c2];
  }
}

// ---------------- MFMA conv3x3: bf16 px-major in, fp32 [oc][y][x] out ----------------
#define MFMA16(A,B,C) __builtin_amdgcn_mfma_f32_16x16x32_bf16(A,B,C,0,0,0)

__global__ __launch_bounds__(256,2) void conv_mfma(const short* __restrict__ xh,
    const short* __restrict__ wh, const float* __restrict__ bias,
    float* __restrict__ out){
  __shared__ short sX[18*18*40];   // [yy][xx][ic32 pad40]
  __shared__ short sW[576*40];     // [tap*64+oc][ic32 pad40]
  const int tX = blockIdx.x*16, tY = blockIdx.y*16, b = blockIdx.z;
  const int t = threadIdx.x;
  const int lane = t & 63, wv = t >> 6;
  const int colx = lane & 15;
  const int kb = (lane >> 4) * 8;

  f32x4 a00={0.f,0.f,0.f,0.f}, a01=a00, a02=a00, a03=a00;
  f32x4 a10=a00, a11=a00, a12=a00, a13=a00;
  f32x4 a20=a00, a21=a00, a22=a00, a23=a00;
  f32x4 a30=a00, a31=a00, a32=a00, a33=a00;

  for (int h=0; h<2; ++h){
    __syncthreads();
    for (int e=t; e<1296; e+=256){
      int px = e>>2, j = e&3;
      int yy = px/18, xx = px - yy*18;
      int gy = tY+yy-1, gx = tX+xx-1;
      uint4 v = make_uint4(0,0,0,0);
      if ((unsigned)gy<256u && (unsigned)gx<256u)
        v = *(const uint4*)&xh[((size_t)((b<<16) + (gy<<8) + gx))*64 + h*32 + j*8];
      *(uint4*)&sX[px*40 + j*8] = v;
    }
    for (int e=t; e<2304; e+=256){
      int row = e>>2, j = e&3;
      uint4 v = *(const uint4*)&wh[(size_t)row*64 + h*32 + j*8];
      *(uint4*)&sW[row*40 + j*8] = v;
    }
    __syncthreads();
    #pragma unroll
    for (int tap=0; tap<9; ++tap){
      const int dy = tap/3, dx = tap - dy*3;
      s16x8 wA = *(const s16x8*)&sW[(tap*64 +  0 + colx)*40 + kb];
      s16x8 wB = *(const s16x8*)&sW[(tap*64 + 16 + colx)*40 + kb];
      s16x8 wC = *(const s16x8*)&sW[(tap*64 + 32 + colx)*40 + kb];
      s16x8 wD = *(const s16x8*)&sW[(tap*64 + 48 + colx)*40 + kb];
      s16x8 x0 = *(const s16x8*)&sX[((wv*4+0+dy)*18 + colx+dx)*40 + kb];
      s16x8 x1 = *(const s16x8*)&sX[((wv*4+1+dy)*18 + colx+dx)*40 + kb];
      s16x8 x2 = *(const s16x8*)&sX[((wv*4+2+dy)*18 + colx+dx)*40 + kb];
      s16x8 x3 = *(const s16x8*)&sX[((wv*4+3+dy)*18 + colx+dx)*40 + kb];
      a00 = MFMA16(wA,x0,a00); a01 = MFMA16(wA,x1,a01);
      a02 = MFMA16(wA,x2,a02); a03 = MFMA16(wA,x3,a03);
      a10 = MFMA16(wB,x0,a10); a11 = MFMA16(wB,x1,a11);
      a12 = MFMA16(wB,x2,a12); a13 = MFMA16(wB,x3,a13);
      a20 = MFMA16(wC,x0,a20); a21 = MFMA16(wC,x1,a21);
      a22 = MFMA16(wC,x2,a22); a23 = MFMA16(wC,x3,a23);
      a30 = MFMA16(wD,x0,a30); a31 = MFMA16(wD,x1,a31);
      a32 = MFMA16(wD,x2,a32); a33 = MFMA16(wD,x3,a33);
    }
  }
  const int ocl = (lane>>4)*4;
  #define EPI(G,R,ACC) { \
    const int y = tY + wv*4 + R; \
    _Pragma("unroll") \
    for (int m=0;m<4;m++){ \
      int oc = G*16 + ocl + m; \
      out[(((size_t)(b*64+oc))<<16) + (y<<8) + tX + colx] = ACC[m] + bias[oc]; \
    } }
  EPI(0,0,a00) EPI(0,1,a01) EPI(0,2,a02) EPI(0,3,a03)
  EPI(1,0,a10) EPI(1,1,a11) EPI(1,2,a12) EPI(1,3,a13)
  EPI(2,0,a20) EPI(2,1,a21) EPI(2,2,a22) EPI(2,3,a23)
  EPI(3,0,a30) EPI(3,1,a31) EPI(3,2,a32) EPI(3,3,a33)
  #undef EPI
}

__global__ __launch_bounds__(256) void bn_stats(const float* __restrict__ x, float* __restrict__ bnst){
  int c = blockIdx.x, part = blockIdx.y;
  float s=0.f, q=0.f;
  for (int b=0;b<2;b++){
    const float4* p = (const float4*)&x[(((size_t)(b*64+c))<<16) + (size_t)part*8192];
    for (int k=threadIdx.x;k<2048;k+=256){
      float4 v = p[k];
      s += v.x+v.y+v.z+v.w;
      q += v.x*v.x+v.y*v.y+v.z*v.z+v.w*v.w;
    }
  }
  __shared__ float rs[256], rq[256];
  rs[threadIdx.x]=s; rq[threadIdx.x]=q; __syncthreads();
  for (int o=128;o>0;o>>=1){
    if (threadIdx.x<o){ rs[threadIdx.x]+=rs[threadIdx.x+o]; rq[threadIdx.x]+=rq[threadIdx.x+o]; }
    __syncthreads();
  }
  if (threadIdx.x==0){ atomicAdd(&bnst[c], rs[0]); atomicAdd(&bnst[64+c], rq[0]); }
}

__global__ void bn_fin(float* __restrict__ bnst, const float* __restrict__ g, const float* __restrict__ be){
  int c = threadIdx.x;
  const float n = 131072.f;
  float m = bnst[c]/n;
  float v = fmaxf(bnst[64+c]/n - m*m, 0.f);
  float sc = g[c]*rsqrtf(v+1e-5f);
  bnst[128+c]=sc; bnst[192+c]=be[c]-m*sc;
}

__global__ __launch_bounds__(256) void bn_apply(float* __restrict__ x, const float* __restrict__ bnst){
  size_t idx = (size_t)blockIdx.x*256 + threadIdx.x;
  size_t stride = (size_t)gridDim.x*256;
  float4* p = (float4*)x;
  for (size_t k=idx; k<2097152ULL; k+=stride){
    int c = (int)((k>>14)&63);
    float sc = bnst[128+c], sh = bnst[192+c];
    float4 v = p[k];
    v.x=fmaxf(v.x*sc+sh,0.f); v.y=fmaxf(v.y*sc+sh,0.f);
    v.z=fmaxf(v.z*sc+sh,0.f); v.w=fmaxf(v.w*sc+sh,0.f);
    p[k]=v;
  }
}

// ---------------- launch ----------------
extern "C" void kernel_launch(void* const* d_in, const int* in_sizes, int n_in,
                              void* d_out, int out_size, void* d_ws, size_t ws_size,
                              hipStream_t stream){
  const float* pts  = (const float*)d_in[0];
  const void*  mask = d_in[1];
  const float* w1 = (const float*)d_in[2];
  const float* b1 = (const float*)d_in[3];
  const float* g1 = (const float*)d_in[4];
  const float* be1= (const float*)d_in[5];
  const float* w2 = (const float*)d_in[6];
  const float* b2 = (const float*)d_in[7];
  const float* g2 = (const float*)d_in[8];
  const float* be2= (const float*)d_in[9];
  const float* cw[3]  = {(const float*)d_in[10],(const float*)d_in[14],(const float*)d_in[18]};
  const float* cb[3]  = {(const float*)d_in[11],(const float*)d_in[15],(const float*)d_in[19]};
  const float* cg[3]  = {(const float*)d_in[12],(const float*)d_in[16],(const float*)d_in[20]};
  const float* cbe[3] = {(const float*)d_in[13],(const float*)d_in[17],(const float*)d_in[21]};
  float* out = (float*)d_out;

  char* W = (char*)d_ws;
  size_t off = 0;
  auto A = [&](size_t n){ size_t r = off; off = (off + n + 255) & ~(size_t)255; return r; };
  short*    BIGH  = (short*)   (W + A((size_t)2*NCELL*64*2));
  int*      PID   = (int*)     (W + A((size_t)2*NPTS*4));
  int*      CCNT  = (int*)     (W + A((size_t)2*NCELL*4));
  int*      CRANK = (int*)     (W + A((size_t)2*NCELL*4));
  int*      CSTART= (int*)     (W + A((size_t)2*NCELL*4));
  int*      CTMP  = (int*)     (W + A((size_t)2*NCELL*4));
  int*      PLIST = (int*)     (W + A((size_t)2*NPTS*4));
  int*      PPTR  = (int*)     (W + A((size_t)2*NPTS*4));
  int*      PCELL = (int*)     (W + A((size_t)2*MAXP*4));
  float*    PSUM  = (float*)   (W + A((size_t)2*MAXP*16));
  float*    CPTS  = (float*)   (W + A((size_t)2*NPTS*8*4));
  float*    FMX   = (float*)   (W + A((size_t)2*MAXP*64*4));
  float*    FMN   = (float*)   (W + A((size_t)2*MAXP*64*4));
  float*    STATS = (float*)   (W + A((size_t)2*512*4));
  float*    LSTAT = (float*)   (W + A((size_t)16*2*65*4));
  float*    L2STAT= (float*)   (W + A((size_t)16*2*2*64*4));
  float*    BNST  = (float*)   (W + A((size_t)256*4));
  short*    WH0   = (short*)   (W + A((size_t)36864*2));
  short*    WH1   = (short*)   (W + A((size_t)36864*2));
  short*    WH2   = (short*)   (W + A((size_t)36864*2));
  int2*     BPART = (int2*)    (W + A((size_t)2*64*8));
  int*      HEAVY = (int*)     (W + A((size_t)(2+2*64)*4));
  int*      MISC  = (int*)     (W + A(256));

  hipMemsetAsync(BIGH, 0, (size_t)2*NCELL*64*2, stream);
  hipMemsetAsync(CCNT, 0, (size_t)2*NCELL*4, stream);
  hipMemsetAsync(CTMP, 0, (size_t)2*NCELL*4, stream);
  hipMemsetAsync(PPTR, 0xFF, (size_t)2*NPTS*4, stream);
  hipMemsetAsync(PSUM, 0, (size_t)2*MAXP*16, stream);
  hipMemsetAsync(STATS,0, (size_t)2*512*4, stream);
  hipMemsetAsync(LSTAT,0, (size_t)16*2*65*4, stream);
  hipMemsetAsync(L2STAT,0,(size_t)16*2*2*64*4, stream);
  hipMemsetAsync(BNST, 0, (size_t)256*4, stream);
  hipMemsetAsync(HEAVY,0, (size_t)(2+2*64)*4, stream);
  hipMemsetAsync(MISC, 0, 256, stream);

  dim3 perPt((NPTS+255)/256, 2);

  probe_mask<<<1,256,0,stream>>>((const unsigned*)mask, MISC);
  compute_pid<<<perPt,256,0,stream>>>(pts, mask, MISC, PID, CCNT);
  wcvt<<<144,256,0,stream>>>(cw[0], WH0);
  wcvt<<<144,256,0,stream>>>(cw[1], WH1);
  wcvt<<<144,256,0,stream>>>(cw[2], WH2);
  scan_a<<<dim3(64,2),256,0,stream>>>(CCNT, BPART);
  scan_b<<<dim3(64,2),256,0,stream>>>(CCNT, BPART, CRANK, CSTART, PCELL, MISC, HEAVY);
  scatter_points<<<perPt,256,0,stream>>>(PID, CCNT, CRANK, CSTART, CTMP, PLIST, PPTR);
  heavy_select<<<dim3(64,2),64,0,stream>>>(CCNT, CRANK, CSTART, PLIST, HEAVY, PPTR);
  gather_cpts<<<perPt,256,0,stream>>>(pts, PID, PPTR, PLIST, MISC, CPTS, PSUM);
  centroid_fin<<<(2*MAXP+255)/256,256,0,stream>>>(PSUM);
  moments<<<dim3(120,2),256,0,stream>>>(CPTS, PSUM, MISC, LSTAT);
  stats_fin1<<<2,64,0,stream>>>(w1, b1, g1, be1, w2, b2, LSTAT, STATS, MISC);
  pillar_mlp<<<2048,256,0,stream>>>(CPTS, PCELL, CSTART, CCNT, PSUM, MISC,
                                    w1, b1, w2, b2, STATS, L2STAT, FMX, FMN);
  stats_fin2<<<2,64,0,stream>>>(g2, be2, L2STAT, STATS);
  scatter_bev<<<(2*64*MAXP+255)/256,256,0,stream>>>(FMX, FMN, PCELL, MISC, STATS, BIGH);

  // conv1: BIGH -> d_out
  conv_mfma<<<dim3(16,16,2),256,0,stream>>>(BIGH, WH0, cb[0], out);
  bn_stats<<<dim3(64,8),256,0,stream>>>(out, BNST);
  bn_fin<<<1,64,0,stream>>>(BNST, cg[0], cbe[0]);
  // bn1+relu -> BIGH ; conv2: BIGH -> d_out
  cvt_px<<<dim3(4,256,2),256,0,stream>>>(out, BNST, BIGH);
  hipMemsetAsync(BNST, 0, 512, stream);
  conv_mfma<<<dim3(16,16,2),256,0,stream>>>(BIGH, WH1, cb[1], out);
  bn_stats<<<dim3(64,8),256,0,stream>>>(out, BNST);
  bn_fin<<<1,64,0,stream>>>(BNST, cg[1], cbe[1]);
  // bn2+relu -> BIGH ; conv3: BIGH -> d_out
  cvt_px<<<dim3(4,256,2),256,0,stream>>>(out, BNST, BIGH);
  hipMemsetAsync(BNST, 0, 512, stream);
  conv_mfma<<<dim3(16,16,2),256,0,stream>>>(BIGH, WH2, cb[2], out);
  bn_stats<<<dim3(64,8),256,0,stream>>>(out, BNST);
  bn_fin<<<1,64,0,stream>>>(BNST, cg[2], cbe[2]);
  bn_apply<<<2048,256,0,stream>>>(out, BNST);
}

// Round 7
// 251.292 us; speedup vs baseline: 4.9929x; 1.1192x over previous
//
#include <hip/hip_runtime.h>

#define NPTS 60000
#define NXG 256
#define NCELL 65536
#define MAXP 12000
#define MAXPP 32
#define NROWS (MAXP*MAXPP)

typedef float f32x32 __attribute__((ext_vector_type(32)));
typedef float f32x4  __attribute__((ext_vector_type(4)));
typedef short s16x8  __attribute__((ext_vector_type(8)));

__device__ __forceinline__ short to_bf16(float f){
  unsigned u = __float_as_uint(f);
  unsigned r = (u + 0x7FFFu + ((u>>16)&1u)) >> 16;
  return (short)r;
}

// ---------------- mask dtype probe ----------------
__global__ void probe_mask(const unsigned* __restrict__ m, int* __restrict__ misc){
  __shared__ int cf32, cbig;
  if (threadIdx.x==0){ cf32=0; cbig=0; }
  __syncthreads();
  int lf=0, lb=0;
  for (int k=0;k<4;k++){
    unsigned x = m[threadIdx.x*4+k];
    if (x==0x3f800000u) lf++;
    else if (x>1u) lb++;
  }
  atomicAdd(&cf32, lf); atomicAdd(&cbig, lb);
  __syncthreads();
  if (threadIdx.x==0){
    int mode=0;
    if (cf32>64) mode=2; else if (cbig>0) mode=1;
    misc[0]=mode;
  }
}

// ---------------- pillarize ----------------
__global__ void compute_pid(const float* __restrict__ pts, const void* __restrict__ maskp,
                            const int* __restrict__ misc, int* __restrict__ pid,
                            int* __restrict__ ccnt){
  int i = blockIdx.x*blockDim.x + threadIdx.x;
  if (i>=NPTS) return;
  int b = blockIdx.y;
  int gi = b*NPTS+i;
  int mode = misc[0];
  bool m;
  if (mode==0)      m = ((const int*)maskp)[gi]!=0;
  else if (mode==1) m = ((const unsigned char*)maskp)[gi]!=0;
  else              m = ((const float*)maskp)[gi]!=0.f;
  int cell = -1;
  if (m){
    float x = pts[(size_t)gi*5+0], y = pts[(size_t)gi*5+1];
    int ix = (int)((x - (-32.0f)) / 0.25f);
    ix = ix<0?0:(ix>255?255:ix);
    int iy = (int)((y - (-32.0f)) / 0.25f);
    iy = iy<0?0:(iy>255?255:iy);
    cell = iy*NXG + ix;
    atomicAdd(&ccnt[b*NCELL+cell], 1);
  }
  pid[gi] = cell;
}

// ---------------- parallel occupancy scan ----------------
__global__ __launch_bounds__(256) void scan_a(const int* __restrict__ ccnt,
                                              int2* __restrict__ bpart){
  int b = blockIdx.y, blk = blockIdx.x, t = threadIdx.x;
  int4 v = *(const int4*)&ccnt[b*NCELL + blk*1024 + t*4];
  int occ = (v.x>0)+(v.y>0)+(v.z>0)+(v.w>0);
  int cnt = v.x+v.y+v.z+v.w;
  #pragma unroll
  for (int off=32; off>0; off>>=1){
    occ += __shfl_xor(occ, off, 64);
    cnt += __shfl_xor(cnt, off, 64);
  }
  __shared__ int so[4], sc[4];
  int wv = t>>6, lane = t&63;
  if (lane==0){ so[wv]=occ; sc[wv]=cnt; }
  __syncthreads();
  if (t==0) bpart[b*64+blk] = make_int2(so[0]+so[1]+so[2]+so[3], sc[0]+sc[1]+sc[2]+sc[3]);
}

__global__ __launch_bounds__(256) void scan_b(const int* __restrict__ ccnt,
    const int2* __restrict__ bpart,
    int* __restrict__ crank, int* __restrict__ cstart, int* __restrict__ pcell,
    int* __restrict__ misc, int* __restrict__ heavy){
  __shared__ int swo[4], swc[4], sk[4];
  __shared__ int bo_, bc_;
  int b = blockIdx.y, blk = blockIdx.x, t = threadIdx.x;
  int wv = t>>6, lane = t&63;
  if (t < 64){
    int2 p = bpart[b*64+t];
    int po = (t<blk)? p.x : 0;
    int pc = (t<blk)? p.y : 0;
    int to = p.x;
    int tc = p.y;
    #pragma unroll
    for (int off=32; off>0; off>>=1){
      po += __shfl_xor(po, off, 64);
      pc += __shfl_xor(pc, off, 64);
      to += __shfl_xor(to, off, 64);
      tc += __shfl_xor(tc, off, 64);
    }
    if (t==0){
      bo_ = po; bc_ = pc;
      if (blk==0){
        misc[1+b] = (to < MAXP) ? to : MAXP;
        misc[5+b] = tc;               // total masked points
      }
    }
  }
  int4 v = *(const int4*)&ccnt[b*NCELL + blk*1024 + t*4];
  int occ = (v.x>0)+(v.y>0)+(v.z>0)+(v.w>0);
  int cnt = v.x+v.y+v.z+v.w;
  int io = occ, ic = cnt;
  #pragma unroll
  for (int off=1; off<64; off<<=1){
    int ao = __shfl_up(io, off, 64);
    int ac = __shfl_up(ic, off, 64);
    if (lane >= off){ io += ao; ic += ac; }
  }
  if (lane==63){ swo[wv]=io; swc[wv]=ic; }
  __syncthreads();
  int wvo=0, wvc=0;
  #pragma unroll
  for (int w2=0; w2<4; w2++){
    if (w2<wv){ wvo += swo[w2]; wvc += swc[w2]; }
  }
  int eo = bo_ + wvo + io - occ;
  int ec = bc_ + wvc + ic - cnt;
  int kept = 0;
  int cellb = blk*1024 + t*4;
  int vv[4] = {v.x,v.y,v.z,v.w};
  #pragma unroll
  for (int j=0;j<4;j++){
    int c = cellb+j; int val = vv[j];
    if (val>0){
      crank[b*NCELL+c]=eo; cstart[b*NCELL+c]=ec;
      if (eo<MAXP){
        pcell[b*MAXP+eo]=c;
        kept += (val<MAXPP)? val : MAXPP;
        if (val>MAXPP){
          int hi = atomicAdd(&heavy[b],1);
          if (hi<64) heavy[2 + b*64 + hi] = c;
        }
      }
      eo++; ec+=val;
    }
  }
  #pragma unroll
  for (int off=32; off>0; off>>=1) kept += __shfl_xor(kept, off, 64);
  if (lane==0) sk[wv]=kept;
  __syncthreads();
  if (t==0) atomicAdd(&misc[3+b], sk[0]+sk[1]+sk[2]+sk[3]);
}

__global__ void scatter_points(const int* __restrict__ pid, const int* __restrict__ ccnt,
    const int* __restrict__ crank, const int* __restrict__ cstart,
    int* __restrict__ ctmp, int* __restrict__ plist, int* __restrict__ pptr){
  int i = blockIdx.x*blockDim.x + threadIdx.x;
  if (i>=NPTS) return;
  int b = blockIdx.y;
  int gi = b*NPTS+i;
  int cell = pid[gi];
  if (cell<0) return;
  int bc = b*NCELL+cell;
  int pos = cstart[bc] + atomicAdd(&ctmp[bc],1);
  plist[b*NPTS+pos] = i;
  int r = crank[bc];
  if (r>=0 && r<MAXP && ccnt[bc]<=MAXPP) pptr[gi] = r;
}

__global__ void heavy_select(const int* __restrict__ ccnt, const int* __restrict__ crank,
    const int* __restrict__ cstart, const int* __restrict__ plist,
    const int* __restrict__ heavy, int* __restrict__ pptr){
  int b = blockIdx.y;
  int hn = heavy[b]; if (hn>64) hn=64;
  if ((int)blockIdx.x >= hn) return;
  int cell = heavy[2 + b*64 + blockIdx.x];
  int bc = b*NCELL+cell;
  int cnt = ccnt[bc], start = cstart[bc], pr = crank[bc];
  for (int e=threadIdx.x; e<cnt; e+=blockDim.x){
    int pe = plist[b*NPTS+start+e];
    int rank=0;
    for (int k=0;k<cnt;k++) rank += (plist[b*NPTS+start+k] < pe);
    if (rank<MAXPP) pptr[b*NPTS+pe] = pr;
  }
}

// ---------------- compact pillar-ordered point tensor + centroid atomics ----------------
__global__ __launch_bounds__(256) void gather_cpts(const float* __restrict__ pts,
    const int* __restrict__ pid, const int* __restrict__ pptr,
    const int* __restrict__ plist, const int* __restrict__ misc,
    float* __restrict__ cpts, float* __restrict__ psum){
  int pos = blockIdx.x*256 + threadIdx.x;
  int b = blockIdx.y;
  if (pos >= misc[5+b]) return;
  int i = plist[b*NPTS+pos];
  int gi = b*NPTS+i;
  const float* qp = &pts[(size_t)gi*5];
  float x=qp[0], y=qp[1], z=qp[2], i1=qp[3], i2=qp[4];
  int cell = pid[gi];
  int rid = pptr[gi];
  float gx = -32.0f + ((float)(cell&255)+0.5f)*0.25f;
  float gy = -32.0f + ((float)(cell>>8)+0.5f)*0.25f;
  float4* cp = (float4*)&cpts[(size_t)(b*NPTS+pos)*8];
  cp[0] = make_float4(x,y,z,i1);
  cp[1] = make_float4(i2,gx,gy,__int_as_float(rid));
  if (rid>=0){
    float* s = &psum[(size_t)(b*MAXP+rid)*4];
    atomicAdd(s+0,x); atomicAdd(s+1,y); atomicAdd(s+2,z); atomicAdd(s+3,1.f);
  }
}

__global__ void centroid_fin(float* __restrict__ psum){
  int i = blockIdx.x*blockDim.x + threadIdx.x;
  if (i>=2*MAXP) return;
  float* s = &psum[(size_t)i*4];
  float inv = 1.0f / fmaxf(s[3],1.0f);
  s[0]*=inv; s[1]*=inv; s[2]*=inv;
}

// ---------------- global aug moments (65 register accumulators) ----------------
#define MM_ACC(K,V) { if ((K)<32) m0[(K)&31]+=(V); else if ((K)<64) m1[((K)-32)&31]+=(V); else m2+=(V); }
__global__ __launch_bounds__(256) void moments(const float* __restrict__ cpts,
    const float* __restrict__ psum, const int* __restrict__ misc,
    float* __restrict__ lstat){
  int b = blockIdx.y;
  int n = misc[5+b];
  f32x32 m0, m1; float m2 = 0.f;
  #pragma unroll
  for (int j=0;j<32;j++){ m0[j]=0.f; m1[j]=0.f; }
  for (int pos = blockIdx.x*256+threadIdx.x; pos<n; pos += gridDim.x*256){
    const float4* cp = (const float4*)&cpts[(size_t)(b*NPTS+pos)*8];
    float4 f1 = cp[0], f2 = cp[1];
    int rid = __float_as_int(f2.w);
    if (rid<0) continue;
    float4 mc = *(const float4*)&psum[(size_t)(b*MAXP+rid)*4];
    float aug[10] = {f1.x,f1.y,f1.z,f1.w,f2.x,
                     f1.x-mc.x, f1.y-mc.y, f1.z-mc.z, f2.y, f2.z};
    #pragma unroll
    for (int d=0; d<10; d++){
      #pragma unroll
      for (int e=d; e<10; e++){
        const int k = d*10 - d*(d-1)/2 + (e-d);
        MM_ACC(k, aug[d]*aug[e]);
      }
      const int kl = 55+d;
      MM_ACC(kl, aug[d]);
    }
  }
  int lane = threadIdx.x & 63;
  int rep = ((blockIdx.x*256+threadIdx.x)>>6) & 15;
  float* dst = &lstat[(size_t)(rep*2+b)*65];
  #pragma unroll
  for (int j=0;j<32;j++){
    float v = m0[j];
    #pragma unroll
    for (int off=32; off>0; off>>=1) v += __shfl_xor(v, off, 64);
    if (lane==0) atomicAdd(&dst[j], v);
  }
  #pragma unroll
  for (int j=0;j<32;j++){
    float v = m1[j];
    #pragma unroll
    for (int off=32; off>0; off>>=1) v += __shfl_xor(v, off, 64);
    if (lane==0) atomicAdd(&dst[32+j], v);
  }
  {
    float v = m2;
    #pragma unroll
    for (int off=32; off>0; off>>=1) v += __shfl_xor(v, off, 64);
    if (lane==0) atomicAdd(&dst[64], v);
  }
}

__global__ void stats_fin1(const float* __restrict__ w1, const float* __restrict__ b1,
    const float* __restrict__ g1, const float* __restrict__ be1,
    const float* __restrict__ w2, const float* __restrict__ b2,
    const float* __restrict__ lstat, float* __restrict__ stats,
    const int* __restrict__ misc){
  __shared__ float M[65];
  __shared__ float z0s[64];
  int b = blockIdx.x, c = threadIdx.x;
  for (int e=c; e<65; e+=64){
    float s=0.f;
    for (int r=0;r<16;r++) s += lstat[(size_t)(r*2+b)*65+e];
    M[e]=s;
  }
  __syncthreads();
  float* S = &stats[(size_t)b*512];
  float wcol[10];
  #pragma unroll
  for (int d=0;d<10;d++) wcol[d] = w1[d*64+c];
  float b1c = b1[c];
  float nk = (float)misc[3+b];
  const float N = (float)NROWS;
  float pad = N - nk;
  float lw = 0.f;
  #pragma unroll
  for (int d=0;d<10;d++) lw += M[55+d]*wcol[d];
  float s = nk*b1c + lw;
  float qq = nk*b1c*b1c + 2.f*b1c*lw;
  #pragma unroll
  for (int d=0; d<10; d++){
    #pragma unroll
    for (int e=d; e<10; e++){
      float m = M[d*10 - d*(d-1)/2 + (e-d)];
      qq += ((d==e)?1.f:2.f)*m*wcol[d]*wcol[e];
    }
  }
  float St = s + pad*b1c;
  float Qt = qq + pad*b1c*b1c;
  float mu = St/N;
  float var = fmaxf(Qt/N - mu*mu, 0.f);
  float sc = g1[c]*rsqrtf(var+1e-5f);
  float sh = be1[c]-mu*sc;
  S[256+c]=sc; S[320+c]=sh;
  float z0 = fmaxf(b1c*sc+sh, 0.f);
  z0s[c]=z0;
  __syncthreads();
  float t0 = b2[c];
  for (int i2=0;i2<64;i2++) t0 += z0s[i2]*w2[(size_t)i2*64+c];
  S[128+c]=pad*t0; S[192+c]=pad*t0*t0;
}

// ---------------- pillar-centric MLP + in-register max/min ----------------
__global__ __launch_bounds__(256) void pillar_mlp(const float* __restrict__ cpts,
    const int* __restrict__ pcell, const int* __restrict__ cstart,
    const int* __restrict__ ccnt, const float* __restrict__ psum,
    const int* __restrict__ misc,
    const float* __restrict__ w1, const float* __restrict__ b1,
    const float* __restrict__ w2, const float* __restrict__ b2,
    const float* __restrict__ stats, float* __restrict__ l2stat,
    float* __restrict__ fmx, float* __restrict__ fmn){
  const int lane = threadIdx.x & 63;
  float w1c[10];
  #pragma unroll
  for (int d=0;d<10;d++) w1c[d] = w1[d*64+lane];
  f32x32 w2lo, w2hi;
  #pragma unroll
  for (int c=0;c<32;c++) w2lo[c] = w2[(size_t)c*64+lane];
  #pragma unroll
  for (int c=0;c<32;c++) w2hi[c] = w2[(size_t)(c+32)*64+lane];
  const float b1c = b1[lane], b2c = b2[lane];
  const float sc1_0 = stats[256+lane], sh1_0 = stats[320+lane];
  const float sc1_1 = stats[512+256+lane], sh1_1 = stats[512+320+lane];
  const int npil0 = misc[1], npil1 = misc[2];
  float s2_0=0.f, q2_0=0.f, s2_1=0.f, q2_1=0.f;

  const int wglobal = (blockIdx.x*256 + threadIdx.x) >> 6;
  const int nwaves = (gridDim.x*256) >> 6;
  for (int qq = wglobal; qq < 2*MAXP; qq += nwaves){
    int b = (qq >= MAXP) ? 1 : 0;
    int p = qq - b*MAXP;
    int npil = b ? npil1 : npil0;
    if (p >= npil) continue;
    int cell = pcell[b*MAXP+p];
    int bc = b*NCELL+cell;
    int cnt = ccnt[bc], start = cstart[bc];
    const float* mc = &psum[(size_t)(b*MAXP+p)*4];
    float mx = mc[0], my = mc[1], mz = mc[2];
    float gx = -32.0f + ((float)(cell&255)+0.5f)*0.25f;
    float gy = -32.0f + ((float)(cell>>8)+0.5f)*0.25f;
    float sc1 = b ? sc1_1 : sc1_0;
    float sh1 = b ? sh1_1 : sh1_0;
    float tmax = -1e30f, tmin = 1e30f;
    float s2 = 0.f, q2 = 0.f;
    for (int k=0; k<cnt; k++){
      const float4* cp = (const float4*)&cpts[(size_t)(b*NPTS+start+k)*8];
      float4 f1 = cp[0], f2 = cp[1];
      int rid = __float_as_int(f2.w);
      if (rid != p) continue;
      float x=f1.x, y=f1.y, z=f1.z, i1=f1.w, i2=f2.x;
      float acc = b1c;
      acc = fmaf(x, w1c[0], acc);
      acc = fmaf(y, w1c[1], acc);
      acc = fmaf(z, w1c[2], acc);
      acc = fmaf(i1, w1c[3], acc);
      acc = fmaf(i2, w1c[4], acc);
      acc = fmaf(x-mx, w1c[5], acc);
      acc = fmaf(y-my, w1c[6], acc);
      acc = fmaf(z-mz, w1c[7], acc);
      acc = fmaf(gx, w1c[8], acc);
      acc = fmaf(gy, w1c[9], acc);
      float zz = fmaxf(acc*sc1+sh1, 0.f);
      float t = b2c;
      #pragma unroll
      for (int c=0;c<32;c++){
        float zc = __int_as_float(__builtin_amdgcn_readlane(__float_as_int(zz), c));
        t = fmaf(zc, w2lo[c], t);
      }
      #pragma unroll
      for (int c=0;c<32;c++){
        float zc = __int_as_float(__builtin_amdgcn_readlane(__float_as_int(zz), c+32));
        t = fmaf(zc, w2hi[c], t);
      }
      tmax = fmaxf(tmax, t);
      tmin = fminf(tmin, t);
      s2 += t; q2 += t*t;
    }
    fmx[(size_t)(b*MAXP+p)*64 + lane] = tmax;
    fmn[(size_t)(b*MAXP+p)*64 + lane] = tmin;
    if (b){ s2_1 += s2; q2_1 += q2; } else { s2_0 += s2; q2_0 += q2; }
  }
  int rep = wglobal & 15;
  atomicAdd(&l2stat[((rep*2+0)*2+0)*64+lane], s2_0);
  atomicAdd(&l2stat[((rep*2+0)*2+1)*64+lane], q2_0);
  atomicAdd(&l2stat[((rep*2+1)*2+0)*64+lane], s2_1);
  atomicAdd(&l2stat[((rep*2+1)*2+1)*64+lane], q2_1);
}

__global__ void stats_fin2(const float* __restrict__ g2,const float* __restrict__ be2,
                           const float* __restrict__ l2stat, float* __restrict__ stats){
  int b = blockIdx.x, c = threadIdx.x;
  float* S = &stats[(size_t)b*512];
  float s = S[128+c], q = S[192+c];
  for (int r=0;r<16;r++){
    s += l2stat[((r*2+b)*2+0)*64+c];
    q += l2stat[((r*2+b)*2+1)*64+c];
  }
  const float N = (float)NROWS;
  float m = s/N;
  float v = fmaxf(q/N - m*m, 0.f);
  float sc = g2[c]*rsqrtf(v+1e-5f);
  S[384+c]=sc; S[448+c]=be2[c]-m*sc;
}

// BN2+relu on pillar max/min, scatter to bf16 pixel-major BEV [y][x][ch]
__global__ void scatter_bev(const float* __restrict__ fmx, const float* __restrict__ fmn,
                            const int* __restrict__ pcell, const int* __restrict__ misc,
                            const float* __restrict__ stats, short* __restrict__ bevh){
  int tid = blockIdx.x*256+threadIdx.x;
  if (tid >= 2*64*MAXP) return;
  int c = tid & 63;
  int bp = tid >> 6;
  int b = bp / MAXP;
  int p = bp - b*MAXP;
  if (p >= misc[1+b]) return;
  float sc2 = stats[(size_t)b*512+384+c], sh2 = stats[(size_t)b*512+448+c];
  float t = (sc2 >= 0.f) ? fmx[tid] : fmn[tid];
  float v = fmaxf(sc2*t+sh2, 0.f);
  int cell = pcell[b*MAXP+p];
  bevh[((size_t)((b<<16) + cell))*64 + c] = to_bf16(v);
}

// ---------------- weights fp32 [oc][ic][tap] -> bf16 [layer][tap][oc][ic] ----------------
__global__ void wcvt3(const float* __restrict__ w0, const float* __restrict__ w1,
                      const float* __restrict__ w2, short* __restrict__ wh){
  int t = blockIdx.x*256 + threadIdx.x;
  if (t >= 3*36864) return;
  int l = t / 36864, r = t - l*36864;
  const float* w = (l==0)? w0 : ((l==1)? w1 : w2);
  int ic = r & 63, oc = (r>>6)&63, tap = r>>12;
  wh[t] = to_bf16(w[(oc*64+ic)*9 + tap]);
}

// ---------------- fused MFMA conv3x3 ----------------
// in: bf16 px-major (optionally BN+relu applied during staging via ibn=[sc64|sh64])
// out: outh (bf16 px-major raw) OR outf (fp32 [oc][y][x]); fused BN-stats -> stat[s64|q64]
#define MFMA16(A,B,C) __builtin_amdgcn_mfma_f32_16x16x32_bf16(A,B,C,0,0,0)

__global__ __launch_bounds__(256,2) void conv_mfma(const short* __restrict__ xh,
    const short* __restrict__ wh, const float* __restrict__ bias,
    const float* __restrict__ ibn,
    short* __restrict__ outh, float* __restrict__ outf,
    float* __restrict__ stat){
  __shared__ short sX[18*18*40];
  __shared__ short sW[576*40];
  __shared__ float sBN[128];
  __shared__ float ss[64], sq[64];
  const int tX = blockIdx.x*16, tY = blockIdx.y*16, b = blockIdx.z;
  const int t = threadIdx.x;
  const int lane = t & 63, wv = t >> 6;
  const int colx = lane & 15;
  const int kb = (lane >> 4) * 8;
  if (t < 64){ ss[t]=0.f; sq[t]=0.f; }
  if (ibn && t >= 128 && t < 256) sBN[t-128] = ibn[t-128];

  f32x4 a00={0.f,0.f,0.f,0.f}, a01=a00, a02=a00, a03=a00;
  f32x4 a10=a00, a11=a00, a12=a00, a13=a00;
  f32x4 a20=a00, a21=a00, a22=a00, a23=a00;
  f32x4 a30=a00, a31=a00, a32=a00, a33=a00;

  for (int h=0; h<2; ++h){
    __syncthreads();
    for (int e=t; e<1296; e+=256){
      int px = e>>2, j = e&3;
      int yy = px/18, xx = px - yy*18;
      int gy = tY+yy-1, gx = tX+xx-1;
      uint4 v = make_uint4(0,0,0,0);
      if ((unsigned)gy<256u && (unsigned)gx<256u){
        v = *(const uint4*)&xh[((size_t)((b<<16) + (gy<<8) + gx))*64 + h*32 + j*8];
        if (ibn){
          unsigned arr[4] = {v.x, v.y, v.z, v.w};
          #pragma unroll
          for (int j2=0;j2<4;j2++){
            unsigned wrd = arr[j2];
            int ch = h*32 + j*8 + j2*2;
            float lo = __uint_as_float(wrd<<16);
            float hi = __uint_as_float(wrd & 0xffff0000u);
            lo = fmaxf(lo*sBN[ch]+sBN[64+ch], 0.f);
            hi = fmaxf(hi*sBN[ch+1]+sBN[64+ch+1], 0.f);
            arr[j2] = (unsigned)(unsigned short)to_bf16(lo) |
                      (((unsigned)(unsigned short)to_bf16(hi))<<16);
          }
          v = make_uint4(arr[0],arr[1],arr[2],arr[3]);
        }
      }
      *(uint4*)&sX[px*40 + j*8] = v;
    }
    for (int e=t; e<2304; e+=256){
      int row = e>>2, j = e&3;
      uint4 v = *(const uint4*)&wh[(size_t)row*64 + h*32 + j*8];
      *(uint4*)&sW[row*40 + j*8] = v;
    }
    __syncthreads();
    #pragma unroll
    for (int tap=0; tap<9; ++tap){
      const int dy = tap/3, dx = tap - dy*3;
      s16x8 wA = *(const s16x8*)&sW[(tap*64 +  0 + colx)*40 + kb];
      s16x8 wB = *(const s16x8*)&sW[(tap*64 + 16 + colx)*40 + kb];
      s16x8 wC = *(const s16x8*)&sW[(tap*64 + 32 + colx)*40 + kb];
      s16x8 wD = *(const s16x8*)&sW[(tap*64 + 48 + colx)*40 + kb];
      s16x8 x0 = *(const s16x8*)&sX[((wv*4+0+dy)*18 + colx+dx)*40 + kb];
      s16x8 x1 = *(const s16x8*)&sX[((wv*4+1+dy)*18 + colx+dx)*40 + kb];
      s16x8 x2 = *(const s16x8*)&sX[((wv*4+2+dy)*18 + colx+dx)*40 + kb];
      s16x8 x3 = *(const s16x8*)&sX[((wv*4+3+dy)*18 + colx+dx)*40 + kb];
      a00 = MFMA16(wA,x0,a00); a01 = MFMA16(wA,x1,a01);
      a02 = MFMA16(wA,x2,a02); a03 = MFMA16(wA,x3,a03);
      a10 = MFMA16(wB,x0,a10); a11 = MFMA16(wB,x1,a11);
      a12 = MFMA16(wB,x2,a12); a13 = MFMA16(wB,x3,a13);
      a20 = MFMA16(wC,x0,a20); a21 = MFMA16(wC,x1,a21);
      a22 = MFMA16(wC,x2,a22); a23 = MFMA16(wC,x3,a23);
      a30 = MFMA16(wD,x0,a30); a31 = MFMA16(wD,x1,a31);
      a32 = MFMA16(wD,x2,a32); a33 = MFMA16(wD,x3,a33);
    }
  }
  const int ocl = (lane>>4)*4;
  // per group G: outputs v{R}{m}, stats reduce over colx, then writes
  #define DOG(G, A0,A1,A2,A3) { \
    const int oc0g = G*16 + ocl; \
    float bj0=bias[oc0g], bj1=bias[oc0g+1], bj2=bias[oc0g+2], bj3=bias[oc0g+3]; \
    float v00=A0[0]+bj0, v01=A0[1]+bj1, v02=A0[2]+bj2, v03=A0[3]+bj3; \
    float v10=A1[0]+bj0, v11=A1[1]+bj1, v12=A1[2]+bj2, v13=A1[3]+bj3; \
    float v20=A2[0]+bj0, v21=A2[1]+bj1, v22=A2[2]+bj2, v23=A2[3]+bj3; \
    float v30=A3[0]+bj0, v31=A3[1]+bj1, v32=A3[2]+bj2, v33=A3[3]+bj3; \
    float s0=v00+v10+v20+v30, q0=v00*v00+v10*v10+v20*v20+v30*v30; \
    float s1=v01+v11+v21+v31, q1=v01*v01+v11*v11+v21*v21+v31*v31; \
    float s2=v02+v12+v22+v32, q2=v02*v02+v12*v12+v22*v22+v32*v32; \
    float s3=v03+v13+v23+v33, q3=v03*v03+v13*v13+v23*v23+v33*v33; \
    s0+=__shfl_xor(s0,1,64); s0+=__shfl_xor(s0,2,64); s0+=__shfl_xor(s0,4,64); s0+=__shfl_xor(s0,8,64); \
    q0+=__shfl_xor(q0,1,64); q0+=__shfl_xor(q0,2,64); q0+=__shfl_xor(q0,4,64); q0+=__shfl_xor(q0,8,64); \
    s1+=__shfl_xor(s1,1,64); s1+=__shfl_xor(s1,2,64); s1+=__shfl_xor(s1,4,64); s1+=__shfl_xor(s1,8,64); \
    q1+=__shfl_xor(q1,1,64); q1+=__shfl_xor(q1,2,64); q1+=__shfl_xor(q1,4,64); q1+=__shfl_xor(q1,8,64); \
    s2+=__shfl_xor(s2,1,64); s2+=__shfl_xor(s2,2,64); s2+=__shfl_xor(s2,4,64); s2+=__shfl_xor(s2,8,64); \
    q2+=__shfl_xor(q2,1,64); q2+=__shfl_xor(q2,2,64); q2+=__shfl_xor(q2,4,64); q2+=__shfl_xor(q2,8,64); \
    s3+=__shfl_xor(s3,1,64); s3+=__shfl_xor(s3,2,64); s3+=__shfl_xor(s3,4,64); s3+=__shfl_xor(s3,8,64); \
    q3+=__shfl_xor(q3,1,64); q3+=__shfl_xor(q3,2,64); q3+=__shfl_xor(q3,4,64); q3+=__shfl_xor(q3,8,64); \
    if (colx==0){ \
      atomicAdd(&ss[oc0g],s0);   atomicAdd(&sq[oc0g],q0); \
      atomicAdd(&ss[oc0g+1],s1); atomicAdd(&sq[oc0g+1],q1); \
      atomicAdd(&ss[oc0g+2],s2); atomicAdd(&sq[oc0g+2],q2); \
      atomicAdd(&ss[oc0g+3],s3); atomicAdd(&sq[oc0g+3],q3); \
    } \
    if (outh){ \
      size_t pb = (size_t)((b<<16) + tX + colx); \
      *(short4*)&outh[(pb + ((tY+wv*4+0)<<8))*64 + oc0g] = make_short4(to_bf16(v00),to_bf16(v01),to_bf16(v02),to_bf16(v03)); \
      *(short4*)&outh[(pb + ((tY+wv*4+1)<<8))*64 + oc0g] = make_short4(to_bf16(v10),to_bf16(v11),to_bf16(v12),to_bf16(v13)); \
      *(short4*)&outh[(pb + ((tY+wv*4+2)<<8))*64 + oc0g] = make_short4(to_bf16(v20),to_bf16(v21),to_bf16(v22),to_bf16(v23)); \
      *(short4*)&outh[(pb + ((tY+wv*4+3)<<8))*64 + oc0g] = make_short4(to_bf16(v30),to_bf16(v31),to_bf16(v32),to_bf16(v33)); \
    } else { \
      size_t cb0 = (((size_t)(b*64+oc0g))<<16) + ((tY+wv*4)<<8) + tX + colx; \
      outf[cb0          ] = v00; outf[cb0+(1<<16)      ] = v01; outf[cb0+(2<<16)      ] = v02; outf[cb0+(3<<16)      ] = v03; \
      outf[cb0+256      ] = v10; outf[cb0+(1<<16)+256  ] = v11; outf[cb0+(2<<16)+256  ] = v12; outf[cb0+(3<<16)+256  ] = v13; \
      outf[cb0+512      ] = v20; outf[cb0+(1<<16)+512  ] = v21; outf[cb0+(2<<16)+512  ] = v22; outf[cb0+(3<<16)+512  ] = v23; \
      outf[cb0+768      ] = v30; outf[cb0+(1<<16)+768  ] = v31; outf[cb0+(2<<16)+768  ] = v32; outf[cb0+(3<<16)+768  ] = v33; \
    } \
  }
  DOG(0, a00,a01,a02,a03)
  DOG(1, a10,a11,a12,a13)
  DOG(2, a20,a21,a22,a23)
  DOG(3, a30,a31,a32,a33)
  #undef DOG
  __syncthreads();
  if (t < 64){
    atomicAdd(&stat[t],    ss[t]);
    atomicAdd(&stat[64+t], sq[t]);
  }
}

__global__ void bn_fin(float* __restrict__ bnst, const float* __restrict__ g, const float* __restrict__ be){
  int c = threadIdx.x;
  const float n = 131072.f;
  float m = bnst[c]/n;
  float v = fmaxf(bnst[64+c]/n - m*m, 0.f);
  float sc = g[c]*rsqrtf(v+1e-5f);
  bnst[128+c]=sc; bnst[192+c]=be[c]-m*sc;
}

__global__ __launch_bounds__(256) void bn_apply(float* __restrict__ x, const float* __restrict__ bnst){
  size_t idx = (size_t)blockIdx.x*256 + threadIdx.x;
  size_t stride = (size_t)gridDim.x*256;
  float4* p = (float4*)x;
  for (size_t k=idx; k<2097152ULL; k+=stride){
    int c = (int)((k>>14)&63);
    float sc = bnst[128+c], sh = bnst[192+c];
    float4 v = p[k];
    v.x=fmaxf(v.x*sc+sh,0.f); v.y=fmaxf(v.y*sc+sh,0.f);
    v.z=fmaxf(v.z*sc+sh,0.f); v.w=fmaxf(v.w*sc+sh,0.f);
    p[k]=v;
  }
}

// ---------------- launch ----------------
extern "C" void kernel_launch(void* const* d_in, const int* in_sizes, int n_in,
                              void* d_out, int out_size, void* d_ws, size_t ws_size,
                              hipStream_t stream){
  const float* pts  = (const float*)d_in[0];
  const void*  mask = d_in[1];
  const float* w1 = (const float*)d_in[2];
  const float* b1 = (const float*)d_in[3];
  const float* g1 = (const float*)d_in[4];
  const float* be1= (const float*)d_in[5];
  const float* w2 = (const float*)d_in[6];
  const float* b2 = (const float*)d_in[7];
  const float* g2 = (const float*)d_in[8];
  const float* be2= (const float*)d_in[9];
  const float* cw[3]  = {(const float*)d_in[10],(const float*)d_in[14],(const float*)d_in[18]};
  const float* cb[3]  = {(const float*)d_in[11],(const float*)d_in[15],(const float*)d_in[19]};
  const float* cg[3]  = {(const float*)d_in[12],(const float*)d_in[16],(const float*)d_in[20]};
  const float* cbe[3] = {(const float*)d_in[13],(const float*)d_in[17],(const float*)d_in[21]};
  float* out = (float*)d_out;

  char* W = (char*)d_ws;
  size_t off = 0;
  auto A = [&](size_t n){ size_t r = off; off = (off + n + 255) & ~(size_t)255; return r; };
  short*    BIGH  = (short*)   (W + A((size_t)2*NCELL*64*2));
  short*    OUT1H = (short*)   (W + A((size_t)2*NCELL*64*2));
  int*      PID   = (int*)     (W + A((size_t)2*NPTS*4));
  int*      CRANK = (int*)     (W + A((size_t)2*NCELL*4));
  int*      CSTART= (int*)     (W + A((size_t)2*NCELL*4));
  int*      PLIST = (int*)     (W + A((size_t)2*NPTS*4));
  int*      PPTR  = (int*)     (W + A((size_t)2*NPTS*4));
  int*      PCELL = (int*)     (W + A((size_t)2*MAXP*4));
  float*    CPTS  = (float*)   (W + A((size_t)2*NPTS*8*4));
  float*    FMX   = (float*)   (W + A((size_t)2*MAXP*64*4));
  float*    FMN   = (float*)   (W + A((size_t)2*MAXP*64*4));
  short*    WH    = (short*)   (W + A((size_t)3*36864*2));
  int2*     BPART = (int2*)    (W + A((size_t)2*64*8));
  // ---- zero block (single memset) ----
  size_t zbeg = off;
  int*      CCNT  = (int*)     (W + A((size_t)2*NCELL*4));
  int*      CTMP  = (int*)     (W + A((size_t)2*NCELL*4));
  float*    PSUM  = (float*)   (W + A((size_t)2*MAXP*16));
  float*    STATS = (float*)   (W + A((size_t)2*512*4));
  float*    LSTAT = (float*)   (W + A((size_t)16*2*65*4));
  float*    L2STAT= (float*)   (W + A((size_t)16*2*2*64*4));
  float*    BNST  = (float*)   (W + A((size_t)3*256*4));
  int*      HEAVY = (int*)     (W + A((size_t)(2+2*64)*4));
  int*      MISC  = (int*)     (W + A(256));
  size_t zend = off;

  hipMemsetAsync(BIGH, 0, (size_t)2*NCELL*64*2, stream);
  hipMemsetAsync(PPTR, 0xFF, (size_t)2*NPTS*4, stream);
  hipMemsetAsync(W+zbeg, 0, zend-zbeg, stream);

  dim3 perPt((NPTS+255)/256, 2);

  probe_mask<<<1,256,0,stream>>>((const unsigned*)mask, MISC);
  compute_pid<<<perPt,256,0,stream>>>(pts, mask, MISC, PID, CCNT);
  wcvt3<<<432,256,0,stream>>>(cw[0], cw[1], cw[2], WH);
  scan_a<<<dim3(64,2),256,0,stream>>>(CCNT, BPART);
  scan_b<<<dim3(64,2),256,0,stream>>>(CCNT, BPART, CRANK, CSTART, PCELL, MISC, HEAVY);
  scatter_points<<<perPt,256,0,stream>>>(PID, CCNT, CRANK, CSTART, CTMP, PLIST, PPTR);
  heavy_select<<<dim3(64,2),64,0,stream>>>(CCNT, CRANK, CSTART, PLIST, HEAVY, PPTR);
  gather_cpts<<<perPt,256,0,stream>>>(pts, PID, PPTR, PLIST, MISC, CPTS, PSUM);
  centroid_fin<<<(2*MAXP+255)/256,256,0,stream>>>(PSUM);
  moments<<<dim3(120,2),256,0,stream>>>(CPTS, PSUM, MISC, LSTAT);
  stats_fin1<<<2,64,0,stream>>>(w1, b1, g1, be1, w2, b2, LSTAT, STATS, MISC);
  pillar_mlp<<<2048,256,0,stream>>>(CPTS, PCELL, CSTART, CCNT, PSUM, MISC,
                                    w1, b1, w2, b2, STATS, L2STAT, FMX, FMN);
  stats_fin2<<<2,64,0,stream>>>(g2, be2, L2STAT, STATS);
  scatter_bev<<<(2*64*MAXP+255)/256,256,0,stream>>>(FMX, FMN, PCELL, MISC, STATS, BIGH);

  // conv1: BIGH -> OUT1H (bf16, raw) + stats BNST0
  conv_mfma<<<dim3(16,16,2),256,0,stream>>>(BIGH, WH, cb[0], nullptr, OUT1H, nullptr, BNST);
  bn_fin<<<1,64,0,stream>>>(BNST, cg[0], cbe[0]);
  // conv2: OUT1H (bn1+relu on stage) -> BIGH (bf16, raw) + stats BNST1
  conv_mfma<<<dim3(16,16,2),256,0,stream>>>(OUT1H, WH+36864, cb[1], BNST+128, BIGH, nullptr, BNST+256);
  bn_fin<<<1,64,0,stream>>>(BNST+256, cg[1], cbe[1]);
  // conv3: BIGH (bn2+relu on stage) -> d_out (fp32) + stats BNST2
  conv_mfma<<<dim3(16,16,2),256,0,stream>>>(BIGH, WH+2*36864, cb[2], BNST+256+128, nullptr, out, BNST+512);
  bn_fin<<<1,64,0,stream>>>(BNST+512, cg[2], cbe[2]);
  bn_apply<<<2048,256,0,stream>>>(out, BNST+512);
}